// Round 5
// baseline (646.195 us; speedup 1.0000x reference)
//
#include <hip/hip_runtime.h>
#include <hip/hip_bf16.h>

#define N_NODES 30000
#define N_EDGES 240000
#define ETOT    (N_EDGES + N_NODES)   // 270000 (self loops appended)
#define NGRAPH  128

typedef __attribute__((ext_vector_type(8))) short bf16x8;
typedef __attribute__((ext_vector_type(4))) short bf16x4;
typedef __attribute__((ext_vector_type(4))) float f32x4;

__device__ __forceinline__ unsigned short f2bf(float f) {
    unsigned u = __float_as_uint(f);
    u += 0x7fff + ((u >> 16) & 1);        // round-to-nearest-even
    return (unsigned short)(u >> 16);
}
__device__ __forceinline__ float bf2f(unsigned short h) {
    return __uint_as_float(((unsigned)h) << 16);
}

// ---------- weight transpose + hi/lo bf16 split (once per call) ----------
__global__ __launch_bounds__(256) void conv_weights(const float* __restrict__ W,
                                                    const float* __restrict__ Win,
                                                    const float* __restrict__ Wout,
                                                    short* __restrict__ wt_hi, short* __restrict__ wt_lo,
                                                    short* __restrict__ wint_hi, short* __restrict__ wint_lo,
                                                    short* __restrict__ woutt_hi, short* __restrict__ woutt_lo) {
    int i = blockIdx.x * 256 + threadIdx.x;
    float v; short* dh; short* dl; int di;
    if (i < 196608) {                       // 3*512*128
        int l = i >> 16, r = i & 65535;
        int n = r >> 7, k = r & 127;
        v = W[(size_t)l * 65536 + k * 512 + n];
        dh = wt_hi; dl = wt_lo; di = i;
    } else if (i < 245760) {                // + 3*128*128
        int j = i - 196608;
        int l = j >> 14, r = j & 16383;
        int n = r >> 7, k = r & 127;
        v = Win[(size_t)l * 16384 + k * 128 + n];
        dh = wint_hi; dl = wint_lo; di = j;
    } else if (i < 294912) {
        int j = i - 245760;
        int l = j >> 14, r = j & 16383;
        int n = r >> 7, k = r & 127;
        v = Wout[(size_t)l * 16384 + k * 128 + n];
        dh = woutt_hi; dl = woutt_lo; di = j;
    } else return;
    unsigned short hi = f2bf(v);
    unsigned short lo = f2bf(v - bf2f(hi));
    dh[di] = (short)hi; dl[di] = (short)lo;
}

// ---------- activation split: fp32 [N,128] -> bf16 hi/lo (only for x, once) ----------
__global__ __launch_bounds__(256) void split_act(const float* __restrict__ A,
                                                 short* __restrict__ Ah,
                                                 short* __restrict__ Al) {
    int i = blockIdx.x * 256 + threadIdx.x;       // covers 8 floats each
    if (i >= N_NODES * 16) return;
    const float4* p = (const float4*)A + (size_t)i * 2;
    float4 v0 = p[0], v1 = p[1];
    float f[8] = {v0.x, v0.y, v0.z, v0.w, v1.x, v1.y, v1.z, v1.w};
    bf16x8 h, l;
#pragma unroll
    for (int j = 0; j < 8; j++) {
        unsigned short hh = f2bf(f[j]);
        h[j] = (short)hh;
        l[j] = (short)f2bf(f[j] - bf2f(hh));
    }
    *(bf16x8*)(Ah + (size_t)i * 8) = h;
    *(bf16x8*)(Al + (size_t)i * 8) = l;
}

// ---------- conv GEMM + fused attention-logit epilogue ----------
// block: 64 rows x 128 cols (one head); computes hfullb tile AND als/ald for that head
__global__ __launch_bounds__(256) void gemm_conv(const short* __restrict__ Ah,
                                                 const short* __restrict__ Al,
                                                 const short* __restrict__ Bth,
                                                 const short* __restrict__ Btl,
                                                 const float* __restrict__ att_s,
                                                 const float* __restrict__ att_d,
                                                 unsigned short* __restrict__ hfullb,
                                                 float* __restrict__ als,
                                                 float* __restrict__ ald) {
    __shared__ short As_h[64 * 136];
    __shared__ short As_l[64 * 136];
    __shared__ float red_s[2][64], red_d[2][64];
    const int bm = blockIdx.x * 64;
    const int hd = blockIdx.y;            // head = column block
    const int bn = hd * 128;
    const int t  = threadIdx.x;
#pragma unroll
    for (int i = 0; i < 4; i++) {
        int idx8 = t + i * 256;              // 1024 ushort8 slots
        int row = idx8 >> 4, c8 = (idx8 & 15) << 3;
        bf16x8 vh = {}, vl = {};
        if (bm + row < N_NODES) {
            vh = *(const bf16x8*)(Ah + (size_t)(bm + row) * 128 + c8);
            vl = *(const bf16x8*)(Al + (size_t)(bm + row) * 128 + c8);
        }
        *(bf16x8*)(As_h + row * 136 + c8) = vh;
        *(bf16x8*)(As_l + row * 136 + c8) = vl;
    }
    __syncthreads();

    const int w = t >> 6, lane = t & 63;
    const int wr = w >> 1, wc = w & 1;
    const int lr = lane & 15, lg = lane >> 4;
    f32x4 acc[2][4] = {};
    const size_t bofs0 = (size_t)(bn + wc * 64 + lr) * 128 + lg * 8;
#pragma unroll
    for (int kk = 0; kk < 4; kk++) {
        bf16x8 ah[2], al[2], bh[4], bl[4];
#pragma unroll
        for (int ni = 0; ni < 4; ni++) {
            size_t o = bofs0 + (size_t)ni * 16 * 128 + kk * 32;
            bh[ni] = *(const bf16x8*)(Bth + o);
            bl[ni] = *(const bf16x8*)(Btl + o);
        }
        int ko = kk * 32 + lg * 8;
#pragma unroll
        for (int mi = 0; mi < 2; mi++) {
            int r = wr * 32 + mi * 16 + lr;
            ah[mi] = *(const bf16x8*)(As_h + r * 136 + ko);
            al[mi] = *(const bf16x8*)(As_l + r * 136 + ko);
        }
#pragma unroll
        for (int mi = 0; mi < 2; mi++)
#pragma unroll
            for (int ni = 0; ni < 4; ni++) {
                acc[mi][ni] = __builtin_amdgcn_mfma_f32_16x16x32_bf16(ah[mi], bh[ni], acc[mi][ni], 0, 0, 0);
                acc[mi][ni] = __builtin_amdgcn_mfma_f32_16x16x32_bf16(al[mi], bh[ni], acc[mi][ni], 0, 0, 0);
                acc[mi][ni] = __builtin_amdgcn_mfma_f32_16x16x32_bf16(ah[mi], bl[ni], acc[mi][ni], 0, 0, 0);
            }
    }
    // store hfullb tile (bf16)
#pragma unroll
    for (int mi = 0; mi < 2; mi++) {
        int m0 = bm + wr * 32 + mi * 16 + lg * 4;
#pragma unroll
        for (int ni = 0; ni < 4; ni++) {
            int n = bn + wc * 64 + ni * 16 + lr;
#pragma unroll
            for (int r = 0; r < 4; r++) {
                int m = m0 + r;
                if (m < N_NODES) hfullb[(size_t)m * 512 + n] = f2bf(acc[mi][ni][r]);
            }
        }
    }
    // fused attention logits: als[m,hd] = sum_c h[m,c]*att_s[hd,c]  (fp32-exact)
    float as_c[4], ad_c[4];
#pragma unroll
    for (int ni = 0; ni < 4; ni++) {
        int cc = wc * 64 + ni * 16 + lr;
        as_c[ni] = att_s[hd * 128 + cc];
        ad_c[ni] = att_d[hd * 128 + cc];
    }
#pragma unroll
    for (int mi = 0; mi < 2; mi++) {
#pragma unroll
        for (int r = 0; r < 4; r++) {
            float ps = 0.f, pd = 0.f;
#pragma unroll
            for (int ni = 0; ni < 4; ni++) {
                ps = fmaf(acc[mi][ni][r], as_c[ni], ps);
                pd = fmaf(acc[mi][ni][r], ad_c[ni], pd);
            }
#pragma unroll
            for (int off = 1; off < 16; off <<= 1) {
                ps += __shfl_xor(ps, off);
                pd += __shfl_xor(pd, off);
            }
            if (lr == 0) {
                int row = wr * 32 + mi * 16 + lg * 4 + r;
                red_s[wc][row] = ps;
                red_d[wc][row] = pd;
            }
        }
    }
    __syncthreads();
    if (t < 64) {
        int m = bm + t;
        if (m < N_NODES) als[m * 4 + hd] = red_s[0][t] + red_s[1][t];
    } else if (t < 128) {
        int tt = t - 64;
        int m = bm + tt;
        if (m < N_NODES) ald[m * 4 + hd] = red_d[0][tt] + red_d[1][tt];
    }
}

// ---------- fused skip: P = hin@Win + bn(g)@Wout ; gate+relu epilogue; split next-layer bf16 ----
__global__ __launch_bounds__(256) void skip_gate(const float* __restrict__ hin,
                                                 const short* __restrict__ hinh,
                                                 const short* __restrict__ hinl,
                                                 const float* __restrict__ g,
                                                 const float* __restrict__ bnsum,   // [0:128)=sum,[128:256)=sumsq
                                                 const float* __restrict__ gamma,
                                                 const float* __restrict__ beta,
                                                 const short* __restrict__ w1h, const short* __restrict__ w1l,
                                                 const short* __restrict__ w2h, const short* __restrict__ w2l,
                                                 const float* __restrict__ bin, const float* __restrict__ bout,
                                                 float* __restrict__ hout,
                                                 short* __restrict__ houth,
                                                 short* __restrict__ houtl) {
    __shared__ short A1h[64 * 136], A1l[64 * 136], A2h[64 * 136], A2l[64 * 136];
    __shared__ float bnp_s[256];
    const int bm = blockIdx.x * 64;
    const int bn = blockIdx.y * 64;
    const int t  = threadIdx.x;
    if (t < 128) {
        float inv = 1.f / (float)N_NODES;
        float mu  = bnsum[t] * inv;
        float var = bnsum[128 + t] * inv - mu * mu;
        float rs  = rsqrtf(var + 1e-5f);
        float sc  = gamma[t] * rs;
        bnp_s[t]       = sc;
        bnp_s[128 + t] = beta[t] - mu * sc;
    }
    __syncthreads();
    // A1: copy pre-split hin tiles
#pragma unroll
    for (int i = 0; i < 4; i++) {
        int idx8 = t + i * 256;
        int row = idx8 >> 4, c8 = (idx8 & 15) << 3;
        bf16x8 vh = {}, vl = {};
        if (bm + row < N_NODES) {
            vh = *(const bf16x8*)(hinh + (size_t)(bm + row) * 128 + c8);
            vl = *(const bf16x8*)(hinl + (size_t)(bm + row) * 128 + c8);
        }
        *(bf16x8*)(A1h + row * 136 + c8) = vh;
        *(bf16x8*)(A1l + row * 136 + c8) = vl;
    }
    // A2: bn(g) + split
#pragma unroll
    for (int i = 0; i < 8; i++) {
        int idx4 = t + i * 256;
        int row = idx4 >> 5, c4 = (idx4 & 31) << 2;
        float4 v2 = make_float4(0.f, 0.f, 0.f, 0.f);
        if (bm + row < N_NODES) {
            float4 gv = *(const float4*)(g + (size_t)(bm + row) * 128 + c4);
            v2.x = fmaf(bnp_s[c4 + 0], gv.x, bnp_s[128 + c4 + 0]);
            v2.y = fmaf(bnp_s[c4 + 1], gv.y, bnp_s[128 + c4 + 1]);
            v2.z = fmaf(bnp_s[c4 + 2], gv.z, bnp_s[128 + c4 + 2]);
            v2.w = fmaf(bnp_s[c4 + 3], gv.w, bnp_s[128 + c4 + 3]);
        }
        unsigned short b0 = f2bf(v2.x), b1 = f2bf(v2.y), b2 = f2bf(v2.z), b3 = f2bf(v2.w);
        *(bf16x4*)(A2h + row * 136 + c4) = (bf16x4){(short)b0, (short)b1, (short)b2, (short)b3};
        *(bf16x4*)(A2l + row * 136 + c4) = (bf16x4){(short)f2bf(v2.x - bf2f(b0)), (short)f2bf(v2.y - bf2f(b1)),
                                                    (short)f2bf(v2.z - bf2f(b2)), (short)f2bf(v2.w - bf2f(b3))};
    }
    __syncthreads();

    const int w = t >> 6, lane = t & 63;
    const int wr = w >> 1, wc = w & 1;
    const int lr = lane & 15, lg = lane >> 4;
    f32x4 acc[2][2] = {};
    const size_t bofs0 = (size_t)(bn + wc * 32 + lr) * 128 + lg * 8;
#pragma unroll
    for (int kk = 0; kk < 4; kk++) {
        bf16x8 a1f[2], a1g[2], a2f[2], a2g[2], b1h[2], b1l[2], b2h[2], b2l[2];
#pragma unroll
        for (int ni = 0; ni < 2; ni++) {
            size_t o = bofs0 + (size_t)ni * 16 * 128 + kk * 32;
            b1h[ni] = *(const bf16x8*)(w1h + o);
            b1l[ni] = *(const bf16x8*)(w1l + o);
            b2h[ni] = *(const bf16x8*)(w2h + o);
            b2l[ni] = *(const bf16x8*)(w2l + o);
        }
        int ko = kk * 32 + lg * 8;
#pragma unroll
        for (int mi = 0; mi < 2; mi++) {
            int r = wr * 32 + mi * 16 + lr;
            a1f[mi] = *(const bf16x8*)(A1h + r * 136 + ko);
            a1g[mi] = *(const bf16x8*)(A1l + r * 136 + ko);
            a2f[mi] = *(const bf16x8*)(A2h + r * 136 + ko);
            a2g[mi] = *(const bf16x8*)(A2l + r * 136 + ko);
        }
#pragma unroll
        for (int mi = 0; mi < 2; mi++)
#pragma unroll
            for (int ni = 0; ni < 2; ni++) {
                acc[mi][ni] = __builtin_amdgcn_mfma_f32_16x16x32_bf16(a1f[mi], b1h[ni], acc[mi][ni], 0, 0, 0);
                acc[mi][ni] = __builtin_amdgcn_mfma_f32_16x16x32_bf16(a1g[mi], b1h[ni], acc[mi][ni], 0, 0, 0);
                acc[mi][ni] = __builtin_amdgcn_mfma_f32_16x16x32_bf16(a1f[mi], b1l[ni], acc[mi][ni], 0, 0, 0);
                acc[mi][ni] = __builtin_amdgcn_mfma_f32_16x16x32_bf16(a2f[mi], b2h[ni], acc[mi][ni], 0, 0, 0);
                acc[mi][ni] = __builtin_amdgcn_mfma_f32_16x16x32_bf16(a2g[mi], b2h[ni], acc[mi][ni], 0, 0, 0);
                acc[mi][ni] = __builtin_amdgcn_mfma_f32_16x16x32_bf16(a2f[mi], b2l[ni], acc[mi][ni], 0, 0, 0);
            }
    }
#pragma unroll
    for (int mi = 0; mi < 2; mi++) {
        int m0 = bm + wr * 32 + mi * 16 + lg * 4;
#pragma unroll
        for (int ni = 0; ni < 2; ni++) {
            int n = bn + wc * 32 + ni * 16 + lr;
            float bsum = bin[n] + bout[n];
            float sc = bnp_s[n], sh = bnp_s[128 + n];
#pragma unroll
            for (int r = 0; r < 4; r++) {
                int m = m0 + r;
                if (m < N_NODES) {
                    float gv   = g[(size_t)m * 128 + n];
                    float hbnv = fmaf(sc, gv, sh);
                    float hv   = hin[(size_t)m * 128 + n];
                    float gt   = 1.f / (1.f + __expf(-(acc[mi][ni][r] + bsum)));
                    float ov   = fmaxf(gt * hbnv + (1.f - gt) * hv, 0.f);
                    hout[(size_t)m * 128 + n] = ov;
                    unsigned short oh = f2bf(ov);
                    houth[(size_t)m * 128 + n] = (short)oh;
                    houtl[(size_t)m * 128 + n] = (short)f2bf(ov - bf2f(oh));
                }
            }
        }
    }
}

// ---------------- CSR build ----------------
__global__ __launch_bounds__(256) void deg_kernel(const int* __restrict__ ei1,
                                                  int* __restrict__ deg) {
    int e = blockIdx.x * 256 + threadIdx.x;
    if (e >= ETOT) return;
    int d = (e < N_EDGES) ? ei1[e] : (e - N_EDGES);
    atomicAdd(&deg[d], 1);
}

__global__ __launch_bounds__(1024) void scan_kernel(const int* __restrict__ deg,
                                                    int* __restrict__ rowptr,
                                                    int* __restrict__ wofs) {
    const int CH = 30;
    int t = threadIdx.x;
    int base = t * CH;
    int s = 0;
    for (int j = 0; j < CH; j++) { int idx = base + j; if (idx < N_NODES) s += deg[idx]; }
    __shared__ int sums[1024];
    sums[t] = s;
    __syncthreads();
    for (int off = 1; off < 1024; off <<= 1) {
        int v = (t >= off) ? sums[t - off] : 0;
        __syncthreads();
        sums[t] += v;
        __syncthreads();
    }
    int run = sums[t] - s;
    for (int j = 0; j < CH; j++) {
        int idx = base + j;
        if (idx < N_NODES) { rowptr[idx] = run; wofs[idx] = run; run += deg[idx]; }
        else if (idx == N_NODES) { rowptr[N_NODES] = run; }
    }
}

__global__ __launch_bounds__(256) void scatter_kernel(const int* __restrict__ ei0,
                                                      const int* __restrict__ ei1,
                                                      int* __restrict__ wofs,
                                                      int* __restrict__ csr_src) {
    int e = blockIdx.x * 256 + threadIdx.x;
    if (e >= ETOT) return;
    int s = (e < N_EDGES) ? ei0[e] : (e - N_EDGES);
    int d = (e < N_EDGES) ? ei1[e] : (e - N_EDGES);
    int pos = atomicAdd(&wofs[d], 1);
    csr_src[pos] = s;
}

// ---------------- fused gather (bf16 messages, 4-edge unroll) ----------------
__global__ __launch_bounds__(256) void gat_gather(const int* __restrict__ rowptr,
                                                  const int* __restrict__ csr_src,
                                                  const float* __restrict__ al_s,
                                                  const float* __restrict__ al_d,
                                                  const unsigned short* __restrict__ hfullb,
                                                  const float* __restrict__ conv_b,
                                                  float* __restrict__ g,
                                                  float* __restrict__ bnsum,
                                                  float* __restrict__ bnsum2) {
    const int lane = threadIdx.x & 63;
    const int wib  = threadIdx.x >> 6;
    const int gwid = blockIdx.x * 4 + wib;
    const int nw   = gridDim.x * 4;
    const int h    = lane >> 4;
    const int sub  = lane & 15;
    float s1[8] = {}, s2[8] = {};

    for (int n = gwid; n < N_NODES; n += nw) {
        const int e0 = rowptr[n], e1 = rowptr[n + 1];
        const float ald_h = al_d[n * 4 + h];

        float mx = -1e30f;
        for (int i = e0 + sub; i < e1; i += 16) {
            int s = csr_src[i];
            float v = al_s[s * 4 + h] + ald_h;
            v = (v > 0.f) ? v : 0.2f * v;
            mx = fmaxf(mx, v);
        }
        mx = fmaxf(mx, __shfl_xor(mx, 1));
        mx = fmaxf(mx, __shfl_xor(mx, 2));
        mx = fmaxf(mx, __shfl_xor(mx, 4));
        mx = fmaxf(mx, __shfl_xor(mx, 8));

        float acc[8] = {};
        float zs = 0.f;
        int i = e0;
        for (; i + 3 < e1; i += 4) {
            int sA = csr_src[i], sB = csr_src[i + 1], sC = csr_src[i + 2], sD = csr_src[i + 3];
            bf16x8 ha = *(const bf16x8*)(hfullb + (size_t)sA * 512 + lane * 8);
            bf16x8 hb = *(const bf16x8*)(hfullb + (size_t)sB * 512 + lane * 8);
            bf16x8 hc = *(const bf16x8*)(hfullb + (size_t)sC * 512 + lane * 8);
            bf16x8 hd = *(const bf16x8*)(hfullb + (size_t)sD * 512 + lane * 8);
            float vA = al_s[sA * 4 + h] + ald_h; vA = (vA > 0.f) ? vA : 0.2f * vA;
            float vB = al_s[sB * 4 + h] + ald_h; vB = (vB > 0.f) ? vB : 0.2f * vB;
            float vC = al_s[sC * 4 + h] + ald_h; vC = (vC > 0.f) ? vC : 0.2f * vC;
            float vD = al_s[sD * 4 + h] + ald_h; vD = (vD > 0.f) ? vD : 0.2f * vD;
            float exA = __expf(vA - mx), exB = __expf(vB - mx);
            float exC = __expf(vC - mx), exD = __expf(vD - mx);
            zs += (exA + exB) + (exC + exD);
#pragma unroll
            for (int j = 0; j < 8; j++) {
                float a = fmaf(exA, bf2f((unsigned short)ha[j]), acc[j]);
                a = fmaf(exB, bf2f((unsigned short)hb[j]), a);
                a = fmaf(exC, bf2f((unsigned short)hc[j]), a);
                acc[j] = fmaf(exD, bf2f((unsigned short)hd[j]), a);
            }
        }
        for (; i < e1; i++) {
            int sA = csr_src[i];
            float vA = al_s[sA * 4 + h] + ald_h; vA = (vA > 0.f) ? vA : 0.2f * vA;
            bf16x8 ha = *(const bf16x8*)(hfullb + (size_t)sA * 512 + lane * 8);
            float exA = __expf(vA - mx);
            zs += exA;
#pragma unroll
            for (int j = 0; j < 8; j++)
                acc[j] = fmaf(exA, bf2f((unsigned short)ha[j]), acc[j]);
        }

        float inv = 0.25f / (zs + 1e-16f);
#pragma unroll
        for (int j = 0; j < 8; j++) {
            float a = acc[j] * inv;
            a += __shfl_xor(a, 16);
            a += __shfl_xor(a, 32);
            acc[j] = a;
        }
        if (lane < 16) {
            float o[8];
#pragma unroll
            for (int j = 0; j < 8; j++) {
                float tv = acc[j] + conv_b[sub * 8 + j];
                o[j] = tv;
                s1[j] += tv;
                s2[j] = fmaf(tv, tv, s2[j]);
            }
            float* gp = g + (size_t)n * 128 + sub * 8;
            *(float4*)gp       = make_float4(o[0], o[1], o[2], o[3]);
            *(float4*)(gp + 4) = make_float4(o[4], o[5], o[6], o[7]);
        }
    }

    __shared__ float redA[4][128], redB[4][128];
    if (lane < 16) {
#pragma unroll
        for (int j = 0; j < 8; j++) {
            redA[wib][sub * 8 + j] = s1[j];
            redB[wib][sub * 8 + j] = s2[j];
        }
    }
    __syncthreads();
    int t = threadIdx.x;
    if (t < 128) {
        atomicAdd(&bnsum[t], redA[0][t] + redA[1][t] + redA[2][t] + redA[3][t]);
    } else {
        int c = t - 128;
        atomicAdd(&bnsum2[c], redB[0][c] + redB[1][c] + redB[2][c] + redB[3][c]);
    }
}

// ---------------- pooling: sorted batch -> segment sums, no atomics ----------------
__global__ void bounds_kernel(const int* __restrict__ batch, int* __restrict__ gstart) {
    int t = threadIdx.x;
    if (t > NGRAPH) return;
    int lo = 0, hi = N_NODES;
    while (lo < hi) { int mid = (lo + hi) >> 1; if (batch[mid] < t) lo = mid + 1; else hi = mid; }
    gstart[t] = lo;
}

__global__ __launch_bounds__(256) void pool2_kernel(const float* __restrict__ h,
                                                    const int* __restrict__ gstart,
                                                    float* __restrict__ pooled) {
    int gid = blockIdx.x;
    int lo = gstart[gid], hi = gstart[gid + 1];
    int c = threadIdx.x & 127, half = threadIdx.x >> 7;
    float s = 0.f;
    for (int n = lo + half; n < hi; n += 2) s += h[(size_t)n * 128 + c];
    __shared__ float sh[256];
    sh[threadIdx.x] = s;
    __syncthreads();
    if (half == 0) {
        float cc = (float)(hi - lo);
        cc = fmaxf(cc, 1.f);
        pooled[gid * 128 + c] = (sh[c] + sh[c + 128]) / cc;
    }
}

__global__ __launch_bounds__(128) void head_kernel(const float* __restrict__ pooled,
                                                   const float* __restrict__ fc1W,
                                                   const float* __restrict__ fc1b,
                                                   const float* __restrict__ fc3W,
                                                   const float* __restrict__ fc3b,
                                                   float* __restrict__ out) {
    int gid = blockIdx.x, t = threadIdx.x;
    __shared__ float hg[128];
    __shared__ float a1[128];
    hg[t] = pooled[gid * 128 + t];
    __syncthreads();
    float s = fc1b[t];
    for (int c = 0; c < 128; c++) s = fmaf(hg[c], fc1W[c * 128 + t], s);
    a1[t] = fmaxf(s, 0.f);
    __syncthreads();
    if (t < 16) {
        float o = fc3b[t];
        for (int j = 0; j < 128; j++) o = fmaf(a1[j], fc3W[j * 16 + t], o);
        out[gid * 16 + t] = o;
    }
}

extern "C" void kernel_launch(void* const* d_in, const int* in_sizes, int n_in,
                              void* d_out, int out_size, void* d_ws, size_t ws_size,
                              hipStream_t stream) {
    const float* x       = (const float*)d_in[0];
    const int*   ei      = (const int*)d_in[1];
    const int*   batch   = (const int*)d_in[2];
    const float* W       = (const float*)d_in[3];
    const float* att_src = (const float*)d_in[4];
    const float* att_dst = (const float*)d_in[5];
    const float* conv_b  = (const float*)d_in[6];
    const float* gamma   = (const float*)d_in[7];
    const float* beta    = (const float*)d_in[8];
    const float* sk_Win  = (const float*)d_in[9];
    const float* sk_bin  = (const float*)d_in[10];
    const float* sk_Wout = (const float*)d_in[11];
    const float* sk_bout = (const float*)d_in[12];
    const float* fc1_W   = (const float*)d_in[13];
    const float* fc1_b   = (const float*)d_in[14];
    const float* fc3_W   = (const float*)d_in[15];
    const float* fc3_b   = (const float*)d_in[16];
    float* out = (float*)d_out;
    const int* ei0 = ei;
    const int* ei1 = ei + N_EDGES;

    float* ws = (float*)d_ws;
    size_t o = 0;
    unsigned short* hfullb = (unsigned short*)(ws + o); o += (size_t)N_NODES * 256;  // bf16 [N,512]
    float* gbuf   = ws + o; o += (size_t)N_NODES * 128;
    float* hA     = ws + o; o += (size_t)N_NODES * 128;
    float* hB     = ws + o; o += (size_t)N_NODES * 128;
    short* spAh   = (short*)(ws + o); o += (size_t)N_NODES * 64;   // bf16 [N,128] ping
    short* spAl   = (short*)(ws + o); o += (size_t)N_NODES * 64;
    short* spBh   = (short*)(ws + o); o += (size_t)N_NODES * 64;   // pong
    short* spBl   = (short*)(ws + o); o += (size_t)N_NODES * 64;
    float* als    = ws + o; o += N_NODES * 4;
    float* ald    = ws + o; o += N_NODES * 4;
    float* bnsum  = ws + o; o += 768;      // 3 layers x (128 sum + 128 sumsq)
    float* pooled = ws + o; o += NGRAPH * 128;
    short* wt_hi   = (short*)(ws + o); o += 98304;   // 3*512*128 shorts
    short* wt_lo   = (short*)(ws + o); o += 98304;
    short* wint_hi = (short*)(ws + o); o += 24576;   // 3*128*128 shorts
    short* wint_lo = (short*)(ws + o); o += 24576;
    short* woutt_hi = (short*)(ws + o); o += 24576;
    short* woutt_lo = (short*)(ws + o); o += 24576;
    int* gstart   = (int*)(ws + o); o += 132;
    int* deg      = (int*)(ws + o); o += N_NODES;
    int* rowptr   = (int*)(ws + o); o += N_NODES + 4;
    int* wofs     = (int*)(ws + o); o += N_NODES;
    int* csr_src  = (int*)(ws + o); o += ETOT;

    conv_weights<<<1152, 256, 0, stream>>>(W, sk_Win, sk_Wout,
                                           wt_hi, wt_lo, wint_hi, wint_lo, woutt_hi, woutt_lo);

    hipMemsetAsync(deg, 0, N_NODES * 4, stream);
    hipMemsetAsync(bnsum, 0, 768 * 4, stream);
    deg_kernel<<<(ETOT + 255) / 256, 256, 0, stream>>>(ei1, deg);
    scan_kernel<<<1, 1024, 0, stream>>>(deg, rowptr, wofs);
    scatter_kernel<<<(ETOT + 255) / 256, 256, 0, stream>>>(ei0, ei1, wofs, csr_src);
    bounds_kernel<<<1, 256, 0, stream>>>(batch, gstart);
    split_act<<<1875, 256, 0, stream>>>(x, spAh, spAl);

    const float* hin = x;
    float* hout = hA;
    short* sh_in_h = spAh; short* sh_in_l = spAl;
    short* sh_out_h = spBh; short* sh_out_l = spBl;
    for (int l = 0; l < 3; l++) {
        gemm_conv<<<dim3(469, 4), 256, 0, stream>>>(sh_in_h, sh_in_l,
                                                    wt_hi + (size_t)l * 65536, wt_lo + (size_t)l * 65536,
                                                    att_src + l * 512, att_dst + l * 512,
                                                    hfullb, als, ald);
        gat_gather<<<2048, 256, 0, stream>>>(rowptr, csr_src, als, ald, hfullb,
                                             conv_b + l * 128, gbuf,
                                             bnsum + l * 256, bnsum + l * 256 + 128);
        skip_gate<<<dim3(469, 2), 256, 0, stream>>>(hin, sh_in_h, sh_in_l, gbuf,
                                                    bnsum + l * 256, gamma + l * 128, beta + l * 128,
                                                    wint_hi + (size_t)l * 16384, wint_lo + (size_t)l * 16384,
                                                    woutt_hi + (size_t)l * 16384, woutt_lo + (size_t)l * 16384,
                                                    sk_bin + l * 128, sk_bout + l * 128,
                                                    hout, sh_out_h, sh_out_l);
        hin = hout;
        hout = (hout == hA) ? hB : hA;
        short* th = sh_in_h; short* tl = sh_in_l;
        sh_in_h = sh_out_h; sh_in_l = sh_out_l;
        sh_out_h = th; sh_out_l = tl;
    }

    pool2_kernel<<<NGRAPH, 256, 0, stream>>>(hin, gstart, pooled);
    head_kernel<<<NGRAPH, 128, 0, stream>>>(pooled, gstart ? fc1_W : fc1_W, fc1_b, fc3_W, fc3_b, out);
}

// Round 6
// 585.491 us; speedup vs baseline: 1.1037x; 1.1037x over previous
//
#include <hip/hip_runtime.h>
#include <hip/hip_bf16.h>

#define N_NODES 30000
#define N_EDGES 240000
#define ETOT    (N_EDGES + N_NODES)   // 270000 (self loops appended)
#define NGRAPH  128

typedef __attribute__((ext_vector_type(8))) short bf16x8;
typedef __attribute__((ext_vector_type(4))) short bf16x4;
typedef __attribute__((ext_vector_type(4))) float f32x4;

__device__ __forceinline__ unsigned short f2bf(float f) {
    unsigned u = __float_as_uint(f);
    u += 0x7fff + ((u >> 16) & 1);        // round-to-nearest-even
    return (unsigned short)(u >> 16);
}
__device__ __forceinline__ float bf2f(unsigned short h) {
    return __uint_as_float(((unsigned)h) << 16);
}

// ---------- weight transpose + hi/lo bf16 split (once per call) ----------
__global__ __launch_bounds__(256) void conv_weights(const float* __restrict__ W,
                                                    const float* __restrict__ Win,
                                                    const float* __restrict__ Wout,
                                                    short* __restrict__ wt_hi, short* __restrict__ wt_lo,
                                                    short* __restrict__ wint_hi, short* __restrict__ wint_lo,
                                                    short* __restrict__ woutt_hi, short* __restrict__ woutt_lo) {
    int i = blockIdx.x * 256 + threadIdx.x;
    float v; short* dh; short* dl; int di;
    if (i < 196608) {                       // 3*512*128
        int l = i >> 16, r = i & 65535;
        int n = r >> 7, k = r & 127;
        v = W[(size_t)l * 65536 + k * 512 + n];
        dh = wt_hi; dl = wt_lo; di = i;
    } else if (i < 245760) {                // + 3*128*128
        int j = i - 196608;
        int l = j >> 14, r = j & 16383;
        int n = r >> 7, k = r & 127;
        v = Win[(size_t)l * 16384 + k * 128 + n];
        dh = wint_hi; dl = wint_lo; di = j;
    } else if (i < 294912) {
        int j = i - 245760;
        int l = j >> 14, r = j & 16383;
        int n = r >> 7, k = r & 127;
        v = Wout[(size_t)l * 16384 + k * 128 + n];
        dh = woutt_hi; dl = woutt_lo; di = j;
    } else return;
    unsigned short hi = f2bf(v);
    unsigned short lo = f2bf(v - bf2f(hi));
    dh[di] = (short)hi; dl[di] = (short)lo;
}

// ---------- activation split: fp32 [N,128] -> bf16 hi/lo (only for x, once) ----------
__global__ __launch_bounds__(256) void split_act(const float* __restrict__ A,
                                                 short* __restrict__ Ah,
                                                 short* __restrict__ Al) {
    int i = blockIdx.x * 256 + threadIdx.x;       // covers 8 floats each
    if (i >= N_NODES * 16) return;
    const float4* p = (const float4*)A + (size_t)i * 2;
    float4 v0 = p[0], v1 = p[1];
    float f[8] = {v0.x, v0.y, v0.z, v0.w, v1.x, v1.y, v1.z, v1.w};
    bf16x8 h, l;
#pragma unroll
    for (int j = 0; j < 8; j++) {
        unsigned short hh = f2bf(f[j]);
        h[j] = (short)hh;
        l[j] = (short)f2bf(f[j] - bf2f(hh));
    }
    *(bf16x8*)(Ah + (size_t)i * 8) = h;
    *(bf16x8*)(Al + (size_t)i * 8) = l;
}

// ---------- conv GEMM + fused attention-logit epilogue ----------
// block: 64 rows x 128 cols (one head); computes hfullb tile AND als/ald for that head
__global__ __launch_bounds__(256) void gemm_conv(const short* __restrict__ Ah,
                                                 const short* __restrict__ Al,
                                                 const short* __restrict__ Bth,
                                                 const short* __restrict__ Btl,
                                                 const float* __restrict__ att_s,
                                                 const float* __restrict__ att_d,
                                                 unsigned short* __restrict__ hfullb,
                                                 float* __restrict__ als,
                                                 float* __restrict__ ald) {
    __shared__ short As_h[64 * 136];
    __shared__ short As_l[64 * 136];
    __shared__ float red_s[2][64], red_d[2][64];
    const int bm = blockIdx.x * 64;
    const int hd = blockIdx.y;            // head = column block
    const int bn = hd * 128;
    const int t  = threadIdx.x;
#pragma unroll
    for (int i = 0; i < 4; i++) {
        int idx8 = t + i * 256;              // 1024 ushort8 slots
        int row = idx8 >> 4, c8 = (idx8 & 15) << 3;
        bf16x8 vh = {}, vl = {};
        if (bm + row < N_NODES) {
            vh = *(const bf16x8*)(Ah + (size_t)(bm + row) * 128 + c8);
            vl = *(const bf16x8*)(Al + (size_t)(bm + row) * 128 + c8);
        }
        *(bf16x8*)(As_h + row * 136 + c8) = vh;
        *(bf16x8*)(As_l + row * 136 + c8) = vl;
    }
    __syncthreads();

    const int w = t >> 6, lane = t & 63;
    const int wr = w >> 1, wc = w & 1;
    const int lr = lane & 15, lg = lane >> 4;
    f32x4 acc[2][4] = {};
    const size_t bofs0 = (size_t)(bn + wc * 64 + lr) * 128 + lg * 8;
#pragma unroll
    for (int kk = 0; kk < 4; kk++) {
        bf16x8 ah[2], al[2], bh[4], bl[4];
#pragma unroll
        for (int ni = 0; ni < 4; ni++) {
            size_t o = bofs0 + (size_t)ni * 16 * 128 + kk * 32;
            bh[ni] = *(const bf16x8*)(Bth + o);
            bl[ni] = *(const bf16x8*)(Btl + o);
        }
        int ko = kk * 32 + lg * 8;
#pragma unroll
        for (int mi = 0; mi < 2; mi++) {
            int r = wr * 32 + mi * 16 + lr;
            ah[mi] = *(const bf16x8*)(As_h + r * 136 + ko);
            al[mi] = *(const bf16x8*)(As_l + r * 136 + ko);
        }
#pragma unroll
        for (int mi = 0; mi < 2; mi++)
#pragma unroll
            for (int ni = 0; ni < 4; ni++) {
                acc[mi][ni] = __builtin_amdgcn_mfma_f32_16x16x32_bf16(ah[mi], bh[ni], acc[mi][ni], 0, 0, 0);
                acc[mi][ni] = __builtin_amdgcn_mfma_f32_16x16x32_bf16(al[mi], bh[ni], acc[mi][ni], 0, 0, 0);
                acc[mi][ni] = __builtin_amdgcn_mfma_f32_16x16x32_bf16(ah[mi], bl[ni], acc[mi][ni], 0, 0, 0);
            }
    }
    // store hfullb tile (bf16)
#pragma unroll
    for (int mi = 0; mi < 2; mi++) {
        int m0 = bm + wr * 32 + mi * 16 + lg * 4;
#pragma unroll
        for (int ni = 0; ni < 4; ni++) {
            int n = bn + wc * 64 + ni * 16 + lr;
#pragma unroll
            for (int r = 0; r < 4; r++) {
                int m = m0 + r;
                if (m < N_NODES) hfullb[(size_t)m * 512 + n] = f2bf(acc[mi][ni][r]);
            }
        }
    }
    // fused attention logits: als[m,hd] = sum_c h[m,c]*att_s[hd,c]  (fp32-exact)
    float as_c[4], ad_c[4];
#pragma unroll
    for (int ni = 0; ni < 4; ni++) {
        int cc = wc * 64 + ni * 16 + lr;
        as_c[ni] = att_s[hd * 128 + cc];
        ad_c[ni] = att_d[hd * 128 + cc];
    }
#pragma unroll
    for (int mi = 0; mi < 2; mi++) {
#pragma unroll
        for (int r = 0; r < 4; r++) {
            float ps = 0.f, pd = 0.f;
#pragma unroll
            for (int ni = 0; ni < 4; ni++) {
                ps = fmaf(acc[mi][ni][r], as_c[ni], ps);
                pd = fmaf(acc[mi][ni][r], ad_c[ni], pd);
            }
#pragma unroll
            for (int off = 1; off < 16; off <<= 1) {
                ps += __shfl_xor(ps, off);
                pd += __shfl_xor(pd, off);
            }
            if (lr == 0) {
                int row = wr * 32 + mi * 16 + lg * 4 + r;
                red_s[wc][row] = ps;
                red_d[wc][row] = pd;
            }
        }
    }
    __syncthreads();
    if (t < 64) {
        int m = bm + t;
        if (m < N_NODES) als[m * 4 + hd] = red_s[0][t] + red_s[1][t];
    } else if (t < 128) {
        int tt = t - 64;
        int m = bm + tt;
        if (m < N_NODES) ald[m * 4 + hd] = red_d[0][tt] + red_d[1][tt];
    }
}

// ---------- fused skip: P = hin@Win + bn(g)@Wout ; gate+relu epilogue -> bf16 hi/lo ----
__global__ __launch_bounds__(256) void skip_gate(const short* __restrict__ hinh,
                                                 const short* __restrict__ hinl,
                                                 const float* __restrict__ g,
                                                 const float* __restrict__ bnsum,   // [0:128)=sum,[128:256)=sumsq
                                                 const float* __restrict__ gamma,
                                                 const float* __restrict__ beta,
                                                 const short* __restrict__ w1h, const short* __restrict__ w1l,
                                                 const short* __restrict__ w2h, const short* __restrict__ w2l,
                                                 const float* __restrict__ bin, const float* __restrict__ bout,
                                                 short* __restrict__ houth,
                                                 short* __restrict__ houtl) {
    __shared__ short A1h[64 * 136], A1l[64 * 136], A2h[64 * 136], A2l[64 * 136];
    __shared__ float bnp_s[256];
    const int bm = blockIdx.x * 64;
    const int bn = blockIdx.y * 64;
    const int t  = threadIdx.x;
    if (t < 128) {
        float inv = 1.f / (float)N_NODES;
        float mu  = bnsum[t] * inv;
        float var = bnsum[128 + t] * inv - mu * mu;
        float rs  = rsqrtf(var + 1e-5f);
        float sc  = gamma[t] * rs;
        bnp_s[t]       = sc;
        bnp_s[128 + t] = beta[t] - mu * sc;
    }
    __syncthreads();
    // A1: copy pre-split hin tiles
#pragma unroll
    for (int i = 0; i < 4; i++) {
        int idx8 = t + i * 256;
        int row = idx8 >> 4, c8 = (idx8 & 15) << 3;
        bf16x8 vh = {}, vl = {};
        if (bm + row < N_NODES) {
            vh = *(const bf16x8*)(hinh + (size_t)(bm + row) * 128 + c8);
            vl = *(const bf16x8*)(hinl + (size_t)(bm + row) * 128 + c8);
        }
        *(bf16x8*)(A1h + row * 136 + c8) = vh;
        *(bf16x8*)(A1l + row * 136 + c8) = vl;
    }
    // A2: bn(g) + split
#pragma unroll
    for (int i = 0; i < 8; i++) {
        int idx4 = t + i * 256;
        int row = idx4 >> 5, c4 = (idx4 & 31) << 2;
        float4 v2 = make_float4(0.f, 0.f, 0.f, 0.f);
        if (bm + row < N_NODES) {
            float4 gv = *(const float4*)(g + (size_t)(bm + row) * 128 + c4);
            v2.x = fmaf(bnp_s[c4 + 0], gv.x, bnp_s[128 + c4 + 0]);
            v2.y = fmaf(bnp_s[c4 + 1], gv.y, bnp_s[128 + c4 + 1]);
            v2.z = fmaf(bnp_s[c4 + 2], gv.z, bnp_s[128 + c4 + 2]);
            v2.w = fmaf(bnp_s[c4 + 3], gv.w, bnp_s[128 + c4 + 3]);
        }
        unsigned short b0 = f2bf(v2.x), b1 = f2bf(v2.y), b2 = f2bf(v2.z), b3 = f2bf(v2.w);
        *(bf16x4*)(A2h + row * 136 + c4) = (bf16x4){(short)b0, (short)b1, (short)b2, (short)b3};
        *(bf16x4*)(A2l + row * 136 + c4) = (bf16x4){(short)f2bf(v2.x - bf2f(b0)), (short)f2bf(v2.y - bf2f(b1)),
                                                    (short)f2bf(v2.z - bf2f(b2)), (short)f2bf(v2.w - bf2f(b3))};
    }
    __syncthreads();

    const int w = t >> 6, lane = t & 63;
    const int wr = w >> 1, wc = w & 1;
    const int lr = lane & 15, lg = lane >> 4;
    f32x4 acc[2][2] = {};
    const size_t bofs0 = (size_t)(bn + wc * 32 + lr) * 128 + lg * 8;
#pragma unroll
    for (int kk = 0; kk < 4; kk++) {
        bf16x8 a1f[2], a1g[2], a2f[2], a2g[2], b1h[2], b1l[2], b2h[2], b2l[2];
#pragma unroll
        for (int ni = 0; ni < 2; ni++) {
            size_t o = bofs0 + (size_t)ni * 16 * 128 + kk * 32;
            b1h[ni] = *(const bf16x8*)(w1h + o);
            b1l[ni] = *(const bf16x8*)(w1l + o);
            b2h[ni] = *(const bf16x8*)(w2h + o);
            b2l[ni] = *(const bf16x8*)(w2l + o);
        }
        int ko = kk * 32 + lg * 8;
#pragma unroll
        for (int mi = 0; mi < 2; mi++) {
            int r = wr * 32 + mi * 16 + lr;
            a1f[mi] = *(const bf16x8*)(A1h + r * 136 + ko);
            a1g[mi] = *(const bf16x8*)(A1l + r * 136 + ko);
            a2f[mi] = *(const bf16x8*)(A2h + r * 136 + ko);
            a2g[mi] = *(const bf16x8*)(A2l + r * 136 + ko);
        }
#pragma unroll
        for (int mi = 0; mi < 2; mi++)
#pragma unroll
            for (int ni = 0; ni < 2; ni++) {
                acc[mi][ni] = __builtin_amdgcn_mfma_f32_16x16x32_bf16(a1f[mi], b1h[ni], acc[mi][ni], 0, 0, 0);
                acc[mi][ni] = __builtin_amdgcn_mfma_f32_16x16x32_bf16(a1g[mi], b1h[ni], acc[mi][ni], 0, 0, 0);
                acc[mi][ni] = __builtin_amdgcn_mfma_f32_16x16x32_bf16(a1f[mi], b1l[ni], acc[mi][ni], 0, 0, 0);
                acc[mi][ni] = __builtin_amdgcn_mfma_f32_16x16x32_bf16(a2f[mi], b2h[ni], acc[mi][ni], 0, 0, 0);
                acc[mi][ni] = __builtin_amdgcn_mfma_f32_16x16x32_bf16(a2g[mi], b2h[ni], acc[mi][ni], 0, 0, 0);
                acc[mi][ni] = __builtin_amdgcn_mfma_f32_16x16x32_bf16(a2f[mi], b2l[ni], acc[mi][ni], 0, 0, 0);
            }
    }
#pragma unroll
    for (int mi = 0; mi < 2; mi++) {
        int m0 = bm + wr * 32 + mi * 16 + lg * 4;
#pragma unroll
        for (int ni = 0; ni < 2; ni++) {
            int n = bn + wc * 32 + ni * 16 + lr;
            float bsum = bin[n] + bout[n];
#pragma unroll
            for (int r = 0; r < 4; r++) {
                int m = m0 + r;
                if (m < N_NODES) {
                    int lrow = m - bm;
                    float hbnv = bf2f((unsigned short)A2h[lrow * 136 + n]) + bf2f((unsigned short)A2l[lrow * 136 + n]);
                    float hv   = bf2f((unsigned short)A1h[lrow * 136 + n]) + bf2f((unsigned short)A1l[lrow * 136 + n]);
                    float gt   = 1.f / (1.f + __expf(-(acc[mi][ni][r] + bsum)));
                    float ov   = fmaxf(gt * hbnv + (1.f - gt) * hv, 0.f);
                    unsigned short oh = f2bf(ov);
                    houth[(size_t)m * 128 + n] = (short)oh;
                    houtl[(size_t)m * 128 + n] = (short)f2bf(ov - bf2f(oh));
                }
            }
        }
    }
}

// ---------------- CSR build ----------------
__global__ __launch_bounds__(256) void deg_kernel(const int* __restrict__ ei1,
                                                  int* __restrict__ deg) {
    int e = blockIdx.x * 256 + threadIdx.x;
    if (e >= ETOT) return;
    int d = (e < N_EDGES) ? ei1[e] : (e - N_EDGES);
    atomicAdd(&deg[d], 1);
}

__global__ __launch_bounds__(1024) void scan_kernel(const int* __restrict__ deg,
                                                    int* __restrict__ rowptr,
                                                    int* __restrict__ wofs) {
    const int CH = 30;
    int t = threadIdx.x;
    int base = t * CH;
    int s = 0;
    for (int j = 0; j < CH; j++) { int idx = base + j; if (idx < N_NODES) s += deg[idx]; }
    __shared__ int sums[1024];
    sums[t] = s;
    __syncthreads();
    for (int off = 1; off < 1024; off <<= 1) {
        int v = (t >= off) ? sums[t - off] : 0;
        __syncthreads();
        sums[t] += v;
        __syncthreads();
    }
    int run = sums[t] - s;
    for (int j = 0; j < CH; j++) {
        int idx = base + j;
        if (idx < N_NODES) { rowptr[idx] = run; wofs[idx] = run; run += deg[idx]; }
        else if (idx == N_NODES) { rowptr[N_NODES] = run; }
    }
}

__global__ __launch_bounds__(256) void scatter_kernel(const int* __restrict__ ei0,
                                                      const int* __restrict__ ei1,
                                                      int* __restrict__ wofs,
                                                      int* __restrict__ csr_src) {
    int e = blockIdx.x * 256 + threadIdx.x;
    if (e >= ETOT) return;
    int s = (e < N_EDGES) ? ei0[e] : (e - N_EDGES);
    int d = (e < N_EDGES) ? ei1[e] : (e - N_EDGES);
    int pos = atomicAdd(&wofs[d], 1);
    csr_src[pos] = s;
}

// ---------------- fused gather: SINGLE PASS (softmax shift-invariance, no max) ----------
__global__ __launch_bounds__(256) void gat_gather(const int* __restrict__ rowptr,
                                                  const int* __restrict__ csr_src,
                                                  const float* __restrict__ al_s,
                                                  const float* __restrict__ al_d,
                                                  const unsigned short* __restrict__ hfullb,
                                                  const float* __restrict__ conv_b,
                                                  float* __restrict__ g,
                                                  float* __restrict__ bnsum,
                                                  float* __restrict__ bnsum2) {
    const int lane = threadIdx.x & 63;
    const int wib  = threadIdx.x >> 6;
    const int gwid = blockIdx.x * 4 + wib;
    const int nw   = gridDim.x * 4;
    const int h    = lane >> 4;
    const int sub  = lane & 15;
    float s1[8] = {}, s2[8] = {};

    for (int n = gwid; n < N_NODES; n += nw) {
        const int e0 = rowptr[n], e1 = rowptr[n + 1];
        const float ald_h = al_d[n * 4 + h];

        float acc[8] = {};
        float zs = 0.f;
        int i = e0;
        for (; i + 1 < e1; i += 2) {
            int sA = csr_src[i], sB = csr_src[i + 1];
            bf16x8 ha = *(const bf16x8*)(hfullb + (size_t)sA * 512 + lane * 8);
            bf16x8 hb = *(const bf16x8*)(hfullb + (size_t)sB * 512 + lane * 8);
            float vA = al_s[sA * 4 + h] + ald_h; vA = (vA > 0.f) ? vA : 0.2f * vA;
            float vB = al_s[sB * 4 + h] + ald_h; vB = (vB > 0.f) ? vB : 0.2f * vB;
            float exA = __expf(vA), exB = __expf(vB);
            zs += exA + exB;
#pragma unroll
            for (int j = 0; j < 8; j++) {
                float a = fmaf(exA, bf2f((unsigned short)ha[j]), acc[j]);
                acc[j] = fmaf(exB, bf2f((unsigned short)hb[j]), a);
            }
        }
        if (i < e1) {
            int sA = csr_src[i];
            bf16x8 ha = *(const bf16x8*)(hfullb + (size_t)sA * 512 + lane * 8);
            float vA = al_s[sA * 4 + h] + ald_h; vA = (vA > 0.f) ? vA : 0.2f * vA;
            float exA = __expf(vA);
            zs += exA;
#pragma unroll
            for (int j = 0; j < 8; j++)
                acc[j] = fmaf(exA, bf2f((unsigned short)ha[j]), acc[j]);
        }

        float inv = 0.25f / (zs + 1e-16f);
#pragma unroll
        for (int j = 0; j < 8; j++) {
            float a = acc[j] * inv;
            a += __shfl_xor(a, 16);
            a += __shfl_xor(a, 32);
            acc[j] = a;
        }
        if (lane < 16) {
            float o[8];
#pragma unroll
            for (int j = 0; j < 8; j++) {
                float tv = acc[j] + conv_b[sub * 8 + j];
                o[j] = tv;
                s1[j] += tv;
                s2[j] = fmaf(tv, tv, s2[j]);
            }
            float* gp = g + (size_t)n * 128 + sub * 8;
            *(float4*)gp       = make_float4(o[0], o[1], o[2], o[3]);
            *(float4*)(gp + 4) = make_float4(o[4], o[5], o[6], o[7]);
        }
    }

    __shared__ float redA[4][128], redB[4][128];
    if (lane < 16) {
#pragma unroll
        for (int j = 0; j < 8; j++) {
            redA[wib][sub * 8 + j] = s1[j];
            redB[wib][sub * 8 + j] = s2[j];
        }
    }
    __syncthreads();
    int t = threadIdx.x;
    if (t < 128) {
        atomicAdd(&bnsum[t], redA[0][t] + redA[1][t] + redA[2][t] + redA[3][t]);
    } else {
        int c = t - 128;
        atomicAdd(&bnsum2[c], redB[0][c] + redB[1][c] + redB[2][c] + redB[3][c]);
    }
}

// ---------------- pooling + MLP head fused; sorted batch -> segment sums ----------------
__global__ void bounds_kernel(const int* __restrict__ batch, int* __restrict__ gstart) {
    int t = threadIdx.x;
    if (t > NGRAPH) return;
    int lo = 0, hi = N_NODES;
    while (lo < hi) { int mid = (lo + hi) >> 1; if (batch[mid] < t) lo = mid + 1; else hi = mid; }
    gstart[t] = lo;
}

__global__ __launch_bounds__(256) void pool_head(const short* __restrict__ hh,
                                                 const short* __restrict__ hl,
                                                 const int* __restrict__ gstart,
                                                 const float* __restrict__ fc1W,
                                                 const float* __restrict__ fc1b,
                                                 const float* __restrict__ fc3W,
                                                 const float* __restrict__ fc3b,
                                                 float* __restrict__ out) {
    int gid = blockIdx.x, t = threadIdx.x;
    int lo = gstart[gid], hi = gstart[gid + 1];
    int c = t & 127, half = t >> 7;
    float s = 0.f;
    for (int n = lo + half; n < hi; n += 2) {
        size_t idx = (size_t)n * 128 + c;
        s += bf2f((unsigned short)hh[idx]) + bf2f((unsigned short)hl[idx]);
    }
    __shared__ float sh[256];
    __shared__ float hg[128], a1[128];
    sh[t] = s;
    __syncthreads();
    if (half == 0) {
        float cc = fmaxf((float)(hi - lo), 1.f);
        hg[c] = (sh[c] + sh[c + 128]) / cc;
    }
    __syncthreads();
    if (t < 128) {
        float v = fc1b[t];
        for (int c2 = 0; c2 < 128; c2++) v = fmaf(hg[c2], fc1W[c2 * 128 + t], v);
        a1[t] = fmaxf(v, 0.f);
    }
    __syncthreads();
    if (t < 16) {
        float o = fc3b[t];
        for (int j = 0; j < 128; j++) o = fmaf(a1[j], fc3W[j * 16 + t], o);
        out[gid * 16 + t] = o;
    }
}

extern "C" void kernel_launch(void* const* d_in, const int* in_sizes, int n_in,
                              void* d_out, int out_size, void* d_ws, size_t ws_size,
                              hipStream_t stream) {
    const float* x       = (const float*)d_in[0];
    const int*   ei      = (const int*)d_in[1];
    const int*   batch   = (const int*)d_in[2];
    const float* W       = (const float*)d_in[3];
    const float* att_src = (const float*)d_in[4];
    const float* att_dst = (const float*)d_in[5];
    const float* conv_b  = (const float*)d_in[6];
    const float* gamma   = (const float*)d_in[7];
    const float* beta    = (const float*)d_in[8];
    const float* sk_Win  = (const float*)d_in[9];
    const float* sk_bin  = (const float*)d_in[10];
    const float* sk_Wout = (const float*)d_in[11];
    const float* sk_bout = (const float*)d_in[12];
    const float* fc1_W   = (const float*)d_in[13];
    const float* fc1_b   = (const float*)d_in[14];
    const float* fc3_W   = (const float*)d_in[15];
    const float* fc3_b   = (const float*)d_in[16];
    float* out = (float*)d_out;
    const int* ei0 = ei;
    const int* ei1 = ei + N_EDGES;

    float* ws = (float*)d_ws;
    size_t o = 0;
    unsigned short* hfullb = (unsigned short*)(ws + o); o += (size_t)N_NODES * 256;  // bf16 [N,512]
    float* gbuf   = ws + o; o += (size_t)N_NODES * 128;
    short* spAh   = (short*)(ws + o); o += (size_t)N_NODES * 64;   // bf16 [N,128] ping
    short* spAl   = (short*)(ws + o); o += (size_t)N_NODES * 64;
    short* spBh   = (short*)(ws + o); o += (size_t)N_NODES * 64;   // pong
    short* spBl   = (short*)(ws + o); o += (size_t)N_NODES * 64;
    float* als    = ws + o; o += N_NODES * 4;
    float* ald    = ws + o; o += N_NODES * 4;
    float* bnsum  = ws + o; o += 768;      // 3 layers x (128 sum + 128 sumsq)
    short* wt_hi   = (short*)(ws + o); o += 98304;   // 3*512*128 shorts
    short* wt_lo   = (short*)(ws + o); o += 98304;
    short* wint_hi = (short*)(ws + o); o += 24576;   // 3*128*128 shorts
    short* wint_lo = (short*)(ws + o); o += 24576;
    short* woutt_hi = (short*)(ws + o); o += 24576;
    short* woutt_lo = (short*)(ws + o); o += 24576;
    int* gstart   = (int*)(ws + o); o += 132;
    int* deg      = (int*)(ws + o); o += N_NODES;
    int* rowptr   = (int*)(ws + o); o += N_NODES + 4;
    int* wofs     = (int*)(ws + o); o += N_NODES;
    int* csr_src  = (int*)(ws + o); o += ETOT;

    conv_weights<<<1152, 256, 0, stream>>>(W, sk_Win, sk_Wout,
                                           wt_hi, wt_lo, wint_hi, wint_lo, woutt_hi, woutt_lo);

    hipMemsetAsync(deg, 0, N_NODES * 4, stream);
    hipMemsetAsync(bnsum, 0, 768 * 4, stream);
    deg_kernel<<<(ETOT + 255) / 256, 256, 0, stream>>>(ei1, deg);
    scan_kernel<<<1, 1024, 0, stream>>>(deg, rowptr, wofs);
    scatter_kernel<<<(ETOT + 255) / 256, 256, 0, stream>>>(ei0, ei1, wofs, csr_src);
    bounds_kernel<<<1, 256, 0, stream>>>(batch, gstart);
    split_act<<<1875, 256, 0, stream>>>(x, spAh, spAl);

    short* sih = spAh; short* sil = spAl;
    short* soh = spBh; short* sol = spBl;
    for (int l = 0; l < 3; l++) {
        gemm_conv<<<dim3(469, 4), 256, 0, stream>>>(sih, sil,
                                                    wt_hi + (size_t)l * 65536, wt_lo + (size_t)l * 65536,
                                                    att_src + l * 512, att_dst + l * 512,
                                                    hfullb, als, ald);
        gat_gather<<<1024, 256, 0, stream>>>(rowptr, csr_src, als, ald, hfullb,
                                             conv_b + l * 128, gbuf,
                                             bnsum + l * 256, bnsum + l * 256 + 128);
        skip_gate<<<dim3(469, 2), 256, 0, stream>>>(sih, sil, gbuf,
                                                    bnsum + l * 256, gamma + l * 128, beta + l * 128,
                                                    wint_hi + (size_t)l * 16384, wint_lo + (size_t)l * 16384,
                                                    woutt_hi + (size_t)l * 16384, woutt_lo + (size_t)l * 16384,
                                                    sk_bin + l * 128, sk_bout + l * 128,
                                                    soh, sol);
        short* th = sih; short* tl = sil;
        sih = soh; sil = sol;
        soh = th; sol = tl;
    }

    pool_head<<<NGRAPH, 256, 0, stream>>>(sih, sil, gstart, fc1_W, fc1_b, fc3_W, fc3_b, out);
}

// Round 7
// 556.681 us; speedup vs baseline: 1.1608x; 1.0518x over previous
//
#include <hip/hip_runtime.h>
#include <hip/hip_bf16.h>

#define N_NODES 30000
#define N_EDGES 240000
#define ETOT    (N_EDGES + N_NODES)   // 270000 (self loops appended)
#define NGRAPH  128

typedef __attribute__((ext_vector_type(8))) short bf16x8;
typedef __attribute__((ext_vector_type(4))) short bf16x4;
typedef __attribute__((ext_vector_type(4))) float f32x4;

__device__ __forceinline__ unsigned short f2bf(float f) {
    unsigned u = __float_as_uint(f);
    u += 0x7fff + ((u >> 16) & 1);        // round-to-nearest-even
    return (unsigned short)(u >> 16);
}
__device__ __forceinline__ float bf2f(unsigned short h) {
    return __uint_as_float(((unsigned)h) << 16);
}

// ---------- weight transpose + hi/lo bf16 split (once per call) ----------
__global__ __launch_bounds__(256) void conv_weights(const float* __restrict__ W,
                                                    const float* __restrict__ Win,
                                                    const float* __restrict__ Wout,
                                                    short* __restrict__ wt_hi, short* __restrict__ wt_lo,
                                                    short* __restrict__ wint_hi, short* __restrict__ wint_lo,
                                                    short* __restrict__ woutt_hi, short* __restrict__ woutt_lo) {
    int i = blockIdx.x * 256 + threadIdx.x;
    float v; short* dh; short* dl; int di;
    if (i < 196608) {                       // 3*512*128
        int l = i >> 16, r = i & 65535;
        int n = r >> 7, k = r & 127;
        v = W[(size_t)l * 65536 + k * 512 + n];
        dh = wt_hi; dl = wt_lo; di = i;
    } else if (i < 245760) {                // + 3*128*128
        int j = i - 196608;
        int l = j >> 14, r = j & 16383;
        int n = r >> 7, k = r & 127;
        v = Win[(size_t)l * 16384 + k * 128 + n];
        dh = wint_hi; dl = wint_lo; di = j;
    } else if (i < 294912) {
        int j = i - 245760;
        int l = j >> 14, r = j & 16383;
        int n = r >> 7, k = r & 127;
        v = Wout[(size_t)l * 16384 + k * 128 + n];
        dh = woutt_hi; dl = woutt_lo; di = j;
    } else return;
    unsigned short hi = f2bf(v);
    unsigned short lo = f2bf(v - bf2f(hi));
    dh[di] = (short)hi; dl[di] = (short)lo;
}

// ---------- activation split: fp32 [N,128] -> bf16 hi/lo (only for x, once) ----------
__global__ __launch_bounds__(256) void split_act(const float* __restrict__ A,
                                                 short* __restrict__ Ah,
                                                 short* __restrict__ Al) {
    int i = blockIdx.x * 256 + threadIdx.x;       // covers 8 floats each
    if (i >= N_NODES * 16) return;
    const float4* p = (const float4*)A + (size_t)i * 2;
    float4 v0 = p[0], v1 = p[1];
    float f[8] = {v0.x, v0.y, v0.z, v0.w, v1.x, v1.y, v1.z, v1.w};
    bf16x8 h, l;
#pragma unroll
    for (int j = 0; j < 8; j++) {
        unsigned short hh = f2bf(f[j]);
        h[j] = (short)hh;
        l[j] = (short)f2bf(f[j] - bf2f(hh));
    }
    *(bf16x8*)(Ah + (size_t)i * 8) = h;
    *(bf16x8*)(Al + (size_t)i * 8) = l;
}

// ---------- conv GEMM + fused attention-logit epilogue + coalesced bf16 store ----------
// block: 64 rows x 128 cols (one head)
__global__ __launch_bounds__(256) void gemm_conv(const short* __restrict__ Ah,
                                                 const short* __restrict__ Al,
                                                 const short* __restrict__ Bth,
                                                 const short* __restrict__ Btl,
                                                 const float* __restrict__ att_s,
                                                 const float* __restrict__ att_d,
                                                 unsigned short* __restrict__ hfullb,
                                                 float* __restrict__ als,
                                                 float* __restrict__ ald) {
    __shared__ short As_h[64 * 136];
    __shared__ short As_l[64 * 136];
    __shared__ float red_s[2][64], red_d[2][64];
    const int bm = blockIdx.x * 64;
    const int hd = blockIdx.y;            // head = column block
    const int bn = hd * 128;
    const int t  = threadIdx.x;
#pragma unroll
    for (int i = 0; i < 4; i++) {
        int idx8 = t + i * 256;              // 1024 ushort8 slots
        int row = idx8 >> 4, c8 = (idx8 & 15) << 3;
        bf16x8 vh = {}, vl = {};
        if (bm + row < N_NODES) {
            vh = *(const bf16x8*)(Ah + (size_t)(bm + row) * 128 + c8);
            vl = *(const bf16x8*)(Al + (size_t)(bm + row) * 128 + c8);
        }
        *(bf16x8*)(As_h + row * 136 + c8) = vh;
        *(bf16x8*)(As_l + row * 136 + c8) = vl;
    }
    __syncthreads();

    const int w = t >> 6, lane = t & 63;
    const int wr = w >> 1, wc = w & 1;
    const int lr = lane & 15, lg = lane >> 4;
    f32x4 acc[2][4] = {};
    const size_t bofs0 = (size_t)(bn + wc * 64 + lr) * 128 + lg * 8;
#pragma unroll
    for (int kk = 0; kk < 4; kk++) {
        bf16x8 ah[2], al[2], bh[4], bl[4];
#pragma unroll
        for (int ni = 0; ni < 4; ni++) {
            size_t o = bofs0 + (size_t)ni * 16 * 128 + kk * 32;
            bh[ni] = *(const bf16x8*)(Bth + o);
            bl[ni] = *(const bf16x8*)(Btl + o);
        }
        int ko = kk * 32 + lg * 8;
#pragma unroll
        for (int mi = 0; mi < 2; mi++) {
            int r = wr * 32 + mi * 16 + lr;
            ah[mi] = *(const bf16x8*)(As_h + r * 136 + ko);
            al[mi] = *(const bf16x8*)(As_l + r * 136 + ko);
        }
#pragma unroll
        for (int mi = 0; mi < 2; mi++)
#pragma unroll
            for (int ni = 0; ni < 4; ni++) {
                acc[mi][ni] = __builtin_amdgcn_mfma_f32_16x16x32_bf16(ah[mi], bh[ni], acc[mi][ni], 0, 0, 0);
                acc[mi][ni] = __builtin_amdgcn_mfma_f32_16x16x32_bf16(al[mi], bh[ni], acc[mi][ni], 0, 0, 0);
                acc[mi][ni] = __builtin_amdgcn_mfma_f32_16x16x32_bf16(ah[mi], bl[ni], acc[mi][ni], 0, 0, 0);
            }
    }
    // fused attention logits: als[m,hd] = sum_c h[m,c]*att_s[hd,c]  (fp32-exact)
    float as_c[4], ad_c[4];
#pragma unroll
    for (int ni = 0; ni < 4; ni++) {
        int cc = wc * 64 + ni * 16 + lr;
        as_c[ni] = att_s[hd * 128 + cc];
        ad_c[ni] = att_d[hd * 128 + cc];
    }
#pragma unroll
    for (int mi = 0; mi < 2; mi++) {
#pragma unroll
        for (int r = 0; r < 4; r++) {
            float ps = 0.f, pd = 0.f;
#pragma unroll
            for (int ni = 0; ni < 4; ni++) {
                ps = fmaf(acc[mi][ni][r], as_c[ni], ps);
                pd = fmaf(acc[mi][ni][r], ad_c[ni], pd);
            }
#pragma unroll
            for (int off = 1; off < 16; off <<= 1) {
                ps += __shfl_xor(ps, off);
                pd += __shfl_xor(pd, off);
            }
            if (lr == 0) {
                int row = wr * 32 + mi * 16 + lg * 4 + r;
                red_s[wc][row] = ps;
                red_d[wc][row] = pd;
            }
        }
    }
    __syncthreads();            // red complete; As tiles dead -> reuse as C staging
    // stage C tile (bf16) into As_h for coalesced store
#pragma unroll
    for (int mi = 0; mi < 2; mi++)
#pragma unroll
        for (int ni = 0; ni < 4; ni++) {
            int nl = wc * 64 + ni * 16 + lr;
#pragma unroll
            for (int r = 0; r < 4; r++) {
                int row = wr * 32 + mi * 16 + lg * 4 + r;
                As_h[row * 136 + nl] = (short)f2bf(acc[mi][ni][r]);
            }
        }
    if (t < 64) {
        int m = bm + t;
        if (m < N_NODES) als[m * 4 + hd] = red_s[0][t] + red_s[1][t];
    } else if (t < 128) {
        int tt = t - 64;
        int m = bm + tt;
        if (m < N_NODES) ald[m * 4 + hd] = red_d[0][tt] + red_d[1][tt];
    }
    __syncthreads();
    // coalesced bf16x8 store of the 64x128 tile
#pragma unroll
    for (int i2 = 0; i2 < 4; i2++) {
        int idx8 = t + i2 * 256;            // 1024 slots
        int row = idx8 >> 4, c8 = (idx8 & 15) << 3;
        int m = bm + row;
        if (m < N_NODES)
            *(bf16x8*)(hfullb + (size_t)m * 512 + bn + c8) = *(const bf16x8*)(As_h + row * 136 + c8);
    }
}

// ---------- fused skip: P = hin@Win + bn(g)@Wout ; gate+relu epilogue -> bf16 hi/lo ----
__global__ __launch_bounds__(256) void skip_gate(const short* __restrict__ hinh,
                                                 const short* __restrict__ hinl,
                                                 const float* __restrict__ g,
                                                 const float* __restrict__ bnsum,   // [0:128)=sum,[128:256)=sumsq
                                                 const float* __restrict__ gamma,
                                                 const float* __restrict__ beta,
                                                 const short* __restrict__ w1h, const short* __restrict__ w1l,
                                                 const short* __restrict__ w2h, const short* __restrict__ w2l,
                                                 const float* __restrict__ bin, const float* __restrict__ bout,
                                                 short* __restrict__ houth,
                                                 short* __restrict__ houtl) {
    __shared__ short A1h[64 * 136], A1l[64 * 136], A2h[64 * 136], A2l[64 * 136];
    __shared__ float bnp_s[256];
    const int bm = blockIdx.x * 64;
    const int bn = blockIdx.y * 64;
    const int t  = threadIdx.x;
    if (t < 128) {
        float inv = 1.f / (float)N_NODES;
        float mu  = bnsum[t] * inv;
        float var = bnsum[128 + t] * inv - mu * mu;
        float rs  = rsqrtf(var + 1e-5f);
        float sc  = gamma[t] * rs;
        bnp_s[t]       = sc;
        bnp_s[128 + t] = beta[t] - mu * sc;
    }
    __syncthreads();
    // A1: copy pre-split hin tiles
#pragma unroll
    for (int i = 0; i < 4; i++) {
        int idx8 = t + i * 256;
        int row = idx8 >> 4, c8 = (idx8 & 15) << 3;
        bf16x8 vh = {}, vl = {};
        if (bm + row < N_NODES) {
            vh = *(const bf16x8*)(hinh + (size_t)(bm + row) * 128 + c8);
            vl = *(const bf16x8*)(hinl + (size_t)(bm + row) * 128 + c8);
        }
        *(bf16x8*)(A1h + row * 136 + c8) = vh;
        *(bf16x8*)(A1l + row * 136 + c8) = vl;
    }
    // A2: bn(g) + split
#pragma unroll
    for (int i = 0; i < 8; i++) {
        int idx4 = t + i * 256;
        int row = idx4 >> 5, c4 = (idx4 & 31) << 2;
        float4 v2 = make_float4(0.f, 0.f, 0.f, 0.f);
        if (bm + row < N_NODES) {
            float4 gv = *(const float4*)(g + (size_t)(bm + row) * 128 + c4);
            v2.x = fmaf(bnp_s[c4 + 0], gv.x, bnp_s[128 + c4 + 0]);
            v2.y = fmaf(bnp_s[c4 + 1], gv.y, bnp_s[128 + c4 + 1]);
            v2.z = fmaf(bnp_s[c4 + 2], gv.z, bnp_s[128 + c4 + 2]);
            v2.w = fmaf(bnp_s[c4 + 3], gv.w, bnp_s[128 + c4 + 3]);
        }
        unsigned short b0 = f2bf(v2.x), b1 = f2bf(v2.y), b2 = f2bf(v2.z), b3 = f2bf(v2.w);
        *(bf16x4*)(A2h + row * 136 + c4) = (bf16x4){(short)b0, (short)b1, (short)b2, (short)b3};
        *(bf16x4*)(A2l + row * 136 + c4) = (bf16x4){(short)f2bf(v2.x - bf2f(b0)), (short)f2bf(v2.y - bf2f(b1)),
                                                    (short)f2bf(v2.z - bf2f(b2)), (short)f2bf(v2.w - bf2f(b3))};
    }
    __syncthreads();

    const int w = t >> 6, lane = t & 63;
    const int wr = w >> 1, wc = w & 1;
    const int lr = lane & 15, lg = lane >> 4;
    f32x4 acc[2][2] = {};
    const size_t bofs0 = (size_t)(bn + wc * 32 + lr) * 128 + lg * 8;
#pragma unroll
    for (int kk = 0; kk < 4; kk++) {
        bf16x8 a1f[2], a1g[2], a2f[2], a2g[2], b1h[2], b1l[2], b2h[2], b2l[2];
#pragma unroll
        for (int ni = 0; ni < 2; ni++) {
            size_t o = bofs0 + (size_t)ni * 16 * 128 + kk * 32;
            b1h[ni] = *(const bf16x8*)(w1h + o);
            b1l[ni] = *(const bf16x8*)(w1l + o);
            b2h[ni] = *(const bf16x8*)(w2h + o);
            b2l[ni] = *(const bf16x8*)(w2l + o);
        }
        int ko = kk * 32 + lg * 8;
#pragma unroll
        for (int mi = 0; mi < 2; mi++) {
            int r = wr * 32 + mi * 16 + lr;
            a1f[mi] = *(const bf16x8*)(A1h + r * 136 + ko);
            a1g[mi] = *(const bf16x8*)(A1l + r * 136 + ko);
            a2f[mi] = *(const bf16x8*)(A2h + r * 136 + ko);
            a2g[mi] = *(const bf16x8*)(A2l + r * 136 + ko);
        }
#pragma unroll
        for (int mi = 0; mi < 2; mi++)
#pragma unroll
            for (int ni = 0; ni < 2; ni++) {
                acc[mi][ni] = __builtin_amdgcn_mfma_f32_16x16x32_bf16(a1f[mi], b1h[ni], acc[mi][ni], 0, 0, 0);
                acc[mi][ni] = __builtin_amdgcn_mfma_f32_16x16x32_bf16(a1g[mi], b1h[ni], acc[mi][ni], 0, 0, 0);
                acc[mi][ni] = __builtin_amdgcn_mfma_f32_16x16x32_bf16(a1f[mi], b1l[ni], acc[mi][ni], 0, 0, 0);
                acc[mi][ni] = __builtin_amdgcn_mfma_f32_16x16x32_bf16(a2f[mi], b2h[ni], acc[mi][ni], 0, 0, 0);
                acc[mi][ni] = __builtin_amdgcn_mfma_f32_16x16x32_bf16(a2g[mi], b2h[ni], acc[mi][ni], 0, 0, 0);
                acc[mi][ni] = __builtin_amdgcn_mfma_f32_16x16x32_bf16(a2f[mi], b2l[ni], acc[mi][ni], 0, 0, 0);
            }
    }
    // gate+relu into acc (reads A-tiles for skip reconstruct)
#pragma unroll
    for (int mi = 0; mi < 2; mi++) {
#pragma unroll
        for (int ni = 0; ni < 2; ni++) {
            int n = bn + wc * 32 + ni * 16 + lr;
            float bsum = bin[n] + bout[n];
#pragma unroll
            for (int r = 0; r < 4; r++) {
                int lrow = wr * 32 + mi * 16 + lg * 4 + r;
                float hbnv = bf2f((unsigned short)A2h[lrow * 136 + n]) + bf2f((unsigned short)A2l[lrow * 136 + n]);
                float hv   = bf2f((unsigned short)A1h[lrow * 136 + n]) + bf2f((unsigned short)A1l[lrow * 136 + n]);
                float gt   = 1.f / (1.f + __expf(-(acc[mi][ni][r] + bsum)));
                acc[mi][ni][r] = fmaxf(gt * hbnv + (1.f - gt) * hv, 0.f);
            }
        }
    }
    __syncthreads();            // A-tiles dead -> reuse as output staging
#pragma unroll
    for (int mi = 0; mi < 2; mi++)
#pragma unroll
        for (int ni = 0; ni < 2; ni++) {
            int n = bn + wc * 32 + ni * 16 + lr;
#pragma unroll
            for (int r = 0; r < 4; r++) {
                int lrow = wr * 32 + mi * 16 + lg * 4 + r;
                float ov = acc[mi][ni][r];
                unsigned short oh = f2bf(ov);
                A1h[lrow * 136 + n] = (short)oh;
                A1l[lrow * 136 + n] = (short)f2bf(ov - bf2f(oh));
            }
        }
    __syncthreads();
    // coalesced store of 64-row x 64-col window
#pragma unroll
    for (int i2 = 0; i2 < 2; i2++) {
        int idx8 = t + i2 * 256;            // 512 slots = 64 rows x 8
        int row = idx8 >> 3, c8 = (idx8 & 7) << 3;
        int m = bm + row;
        if (m < N_NODES) {
            *(bf16x8*)(houth + (size_t)m * 128 + bn + c8) = *(const bf16x8*)(A1h + row * 136 + bn + c8);
            *(bf16x8*)(houtl + (size_t)m * 128 + bn + c8) = *(const bf16x8*)(A1l + row * 136 + bn + c8);
        }
    }
}

// ---------------- CSR build ----------------
__global__ __launch_bounds__(256) void deg_kernel(const int* __restrict__ ei1,
                                                  int* __restrict__ deg) {
    int e = blockIdx.x * 256 + threadIdx.x;
    if (e >= ETOT) return;
    int d = (e < N_EDGES) ? ei1[e] : (e - N_EDGES);
    atomicAdd(&deg[d], 1);
}

__global__ __launch_bounds__(1024) void scan_kernel(const int* __restrict__ deg,
                                                    int* __restrict__ rowptr,
                                                    int* __restrict__ wofs) {
    const int CH = 30;
    int t = threadIdx.x;
    int base = t * CH;
    int s = 0;
    for (int j = 0; j < CH; j++) { int idx = base + j; if (idx < N_NODES) s += deg[idx]; }
    __shared__ int sums[1024];
    sums[t] = s;
    __syncthreads();
    for (int off = 1; off < 1024; off <<= 1) {
        int v = (t >= off) ? sums[t - off] : 0;
        __syncthreads();
        sums[t] += v;
        __syncthreads();
    }
    int run = sums[t] - s;
    for (int j = 0; j < CH; j++) {
        int idx = base + j;
        if (idx < N_NODES) { rowptr[idx] = run; wofs[idx] = run; run += deg[idx]; }
        else if (idx == N_NODES) { rowptr[N_NODES] = run; }
    }
}

__global__ __launch_bounds__(256) void scatter_kernel(const int* __restrict__ ei0,
                                                      const int* __restrict__ ei1,
                                                      int* __restrict__ wofs,
                                                      int* __restrict__ csr_src) {
    int e = blockIdx.x * 256 + threadIdx.x;
    if (e >= ETOT) return;
    int s = (e < N_EDGES) ? ei0[e] : (e - N_EDGES);
    int d = (e < N_EDGES) ? ei1[e] : (e - N_EDGES);
    int pos = atomicAdd(&wofs[d], 1);
    csr_src[pos] = s;
}

// ---------------- fused gather: single pass, 4-edge load-clustered ----------------
__global__ __launch_bounds__(256) void gat_gather(const int* __restrict__ rowptr,
                                                  const int* __restrict__ csr_src,
                                                  const float* __restrict__ al_s,
                                                  const float* __restrict__ al_d,
                                                  const unsigned short* __restrict__ hfullb,
                                                  const float* __restrict__ conv_b,
                                                  float* __restrict__ g,
                                                  float* __restrict__ bnsum,
                                                  float* __restrict__ bnsum2) {
    const int lane = threadIdx.x & 63;
    const int wib  = threadIdx.x >> 6;
    const int gwid = blockIdx.x * 4 + wib;
    const int nw   = gridDim.x * 4;
    const int h    = lane >> 4;
    const int sub  = lane & 15;
    float s1[8] = {}, s2[8] = {};

    for (int n = gwid; n < N_NODES; n += nw) {
        const int e0 = rowptr[n], e1 = rowptr[n + 1];
        const float ald_h = al_d[n * 4 + h];

        float acc[8] = {};
        float zs = 0.f;
        int i = e0;
        for (; i + 3 < e1; i += 4) {
            int sA = csr_src[i], sB = csr_src[i + 1], sC = csr_src[i + 2], sD = csr_src[i + 3];
            bf16x8 ha = *(const bf16x8*)(hfullb + (size_t)sA * 512 + lane * 8);
            bf16x8 hb = *(const bf16x8*)(hfullb + (size_t)sB * 512 + lane * 8);
            bf16x8 hc = *(const bf16x8*)(hfullb + (size_t)sC * 512 + lane * 8);
            bf16x8 hd = *(const bf16x8*)(hfullb + (size_t)sD * 512 + lane * 8);
            float vA = al_s[sA * 4 + h] + ald_h; vA = (vA > 0.f) ? vA : 0.2f * vA;
            float vB = al_s[sB * 4 + h] + ald_h; vB = (vB > 0.f) ? vB : 0.2f * vB;
            float vC = al_s[sC * 4 + h] + ald_h; vC = (vC > 0.f) ? vC : 0.2f * vC;
            float vD = al_s[sD * 4 + h] + ald_h; vD = (vD > 0.f) ? vD : 0.2f * vD;
            float exA = __expf(vA), exB = __expf(vB), exC = __expf(vC), exD = __expf(vD);
            zs += (exA + exB) + (exC + exD);
#pragma unroll
            for (int j = 0; j < 8; j++) {
                float a = fmaf(exA, bf2f((unsigned short)ha[j]), acc[j]);
                a = fmaf(exB, bf2f((unsigned short)hb[j]), a);
                a = fmaf(exC, bf2f((unsigned short)hc[j]), a);
                acc[j] = fmaf(exD, bf2f((unsigned short)hd[j]), a);
            }
        }
        for (; i < e1; i++) {
            int sA = csr_src[i];
            bf16x8 ha = *(const bf16x8*)(hfullb + (size_t)sA * 512 + lane * 8);
            float vA = al_s[sA * 4 + h] + ald_h; vA = (vA > 0.f) ? vA : 0.2f * vA;
            float exA = __expf(vA);
            zs += exA;
#pragma unroll
            for (int j = 0; j < 8; j++)
                acc[j] = fmaf(exA, bf2f((unsigned short)ha[j]), acc[j]);
        }

        float inv = 0.25f / (zs + 1e-16f);
#pragma unroll
        for (int j = 0; j < 8; j++) {
            float a = acc[j] * inv;
            a += __shfl_xor(a, 16);
            a += __shfl_xor(a, 32);
            acc[j] = a;
        }
        if (lane < 16) {
            float o[8];
#pragma unroll
            for (int j = 0; j < 8; j++) {
                float tv = acc[j] + conv_b[sub * 8 + j];
                o[j] = tv;
                s1[j] += tv;
                s2[j] = fmaf(tv, tv, s2[j]);
            }
            float* gp = g + (size_t)n * 128 + sub * 8;
            *(float4*)gp       = make_float4(o[0], o[1], o[2], o[3]);
            *(float4*)(gp + 4) = make_float4(o[4], o[5], o[6], o[7]);
        }
    }

    __shared__ float redA[4][128], redB[4][128];
    if (lane < 16) {
#pragma unroll
        for (int j = 0; j < 8; j++) {
            redA[wib][sub * 8 + j] = s1[j];
            redB[wib][sub * 8 + j] = s2[j];
        }
    }
    __syncthreads();
    int t = threadIdx.x;
    if (t < 128) {
        atomicAdd(&bnsum[t], redA[0][t] + redA[1][t] + redA[2][t] + redA[3][t]);
    } else {
        int c = t - 128;
        atomicAdd(&bnsum2[c], redB[0][c] + redB[1][c] + redB[2][c] + redB[3][c]);
    }
}

// ---------------- pooling + MLP head fused; sorted batch -> segment sums ----------------
__global__ void bounds_kernel(const int* __restrict__ batch, int* __restrict__ gstart) {
    int t = threadIdx.x;
    if (t > NGRAPH) return;
    int lo = 0, hi = N_NODES;
    while (lo < hi) { int mid = (lo + hi) >> 1; if (batch[mid] < t) lo = mid + 1; else hi = mid; }
    gstart[t] = lo;
}

__global__ __launch_bounds__(256) void pool_head(const short* __restrict__ hh,
                                                 const short* __restrict__ hl,
                                                 const int* __restrict__ gstart,
                                                 const float* __restrict__ fc1W,
                                                 const float* __restrict__ fc1b,
                                                 const float* __restrict__ fc3W,
                                                 const float* __restrict__ fc3b,
                                                 float* __restrict__ out) {
    int gid = blockIdx.x, t = threadIdx.x;
    int lo = gstart[gid], hi = gstart[gid + 1];
    int c = t & 127, half = t >> 7;
    float s = 0.f;
    for (int n = lo + half; n < hi; n += 2) {
        size_t idx = (size_t)n * 128 + c;
        s += bf2f((unsigned short)hh[idx]) + bf2f((unsigned short)hl[idx]);
    }
    __shared__ float sh[256];
    __shared__ float hg[128], a1[128];
    sh[t] = s;
    __syncthreads();
    if (half == 0) {
        float cc = fmaxf((float)(hi - lo), 1.f);
        hg[c] = (sh[c] + sh[c + 128]) / cc;
    }
    __syncthreads();
    if (t < 128) {
        float v = fc1b[t];
        for (int c2 = 0; c2 < 128; c2++) v = fmaf(hg[c2], fc1W[c2 * 128 + t], v);
        a1[t] = fmaxf(v, 0.f);
    }
    __syncthreads();
    if (t < 16) {
        float o = fc3b[t];
        for (int j = 0; j < 128; j++) o = fmaf(a1[j], fc3W[j * 16 + t], o);
        out[gid * 16 + t] = o;
    }
}

extern "C" void kernel_launch(void* const* d_in, const int* in_sizes, int n_in,
                              void* d_out, int out_size, void* d_ws, size_t ws_size,
                              hipStream_t stream) {
    const float* x       = (const float*)d_in[0];
    const int*   ei      = (const int*)d_in[1];
    const int*   batch   = (const int*)d_in[2];
    const float* W       = (const float*)d_in[3];
    const float* att_src = (const float*)d_in[4];
    const float* att_dst = (const float*)d_in[5];
    const float* conv_b  = (const float*)d_in[6];
    const float* gamma   = (const float*)d_in[7];
    const float* beta    = (const float*)d_in[8];
    const float* sk_Win  = (const float*)d_in[9];
    const float* sk_bin  = (const float*)d_in[10];
    const float* sk_Wout = (const float*)d_in[11];
    const float* sk_bout = (const float*)d_in[12];
    const float* fc1_W   = (const float*)d_in[13];
    const float* fc1_b   = (const float*)d_in[14];
    const float* fc3_W   = (const float*)d_in[15];
    const float* fc3_b   = (const float*)d_in[16];
    float* out = (float*)d_out;
    const int* ei0 = ei;
    const int* ei1 = ei + N_EDGES;

    float* ws = (float*)d_ws;
    size_t o = 0;
    unsigned short* hfullb = (unsigned short*)(ws + o); o += (size_t)N_NODES * 256;  // bf16 [N,512]
    float* gbuf   = ws + o; o += (size_t)N_NODES * 128;
    short* spAh   = (short*)(ws + o); o += (size_t)N_NODES * 64;   // bf16 [N,128] ping
    short* spAl   = (short*)(ws + o); o += (size_t)N_NODES * 64;
    short* spBh   = (short*)(ws + o); o += (size_t)N_NODES * 64;   // pong
    short* spBl   = (short*)(ws + o); o += (size_t)N_NODES * 64;
    float* als    = ws + o; o += N_NODES * 4;
    float* ald    = ws + o; o += N_NODES * 4;
    float* bnsum  = ws + o; o += 768;      // 3 layers x (128 sum + 128 sumsq)
    short* wt_hi   = (short*)(ws + o); o += 98304;   // 3*512*128 shorts
    short* wt_lo   = (short*)(ws + o); o += 98304;
    short* wint_hi = (short*)(ws + o); o += 24576;   // 3*128*128 shorts
    short* wint_lo = (short*)(ws + o); o += 24576;
    short* woutt_hi = (short*)(ws + o); o += 24576;
    short* woutt_lo = (short*)(ws + o); o += 24576;
    int* gstart   = (int*)(ws + o); o += 132;
    int* deg      = (int*)(ws + o); o += N_NODES;
    int* rowptr   = (int*)(ws + o); o += N_NODES + 4;
    int* wofs     = (int*)(ws + o); o += N_NODES;
    int* csr_src  = (int*)(ws + o); o += ETOT;

    conv_weights<<<1152, 256, 0, stream>>>(W, sk_Win, sk_Wout,
                                           wt_hi, wt_lo, wint_hi, wint_lo, woutt_hi, woutt_lo);

    hipMemsetAsync(deg, 0, N_NODES * 4, stream);
    hipMemsetAsync(bnsum, 0, 768 * 4, stream);
    deg_kernel<<<(ETOT + 255) / 256, 256, 0, stream>>>(ei1, deg);
    scan_kernel<<<1, 1024, 0, stream>>>(deg, rowptr, wofs);
    scatter_kernel<<<(ETOT + 255) / 256, 256, 0, stream>>>(ei0, ei1, wofs, csr_src);
    bounds_kernel<<<1, 256, 0, stream>>>(batch, gstart);
    split_act<<<1875, 256, 0, stream>>>(x, spAh, spAl);

    short* sih = spAh; short* sil = spAl;
    short* soh = spBh; short* sol = spBl;
    for (int l = 0; l < 3; l++) {
        gemm_conv<<<dim3(469, 4), 256, 0, stream>>>(sih, sil,
                                                    wt_hi + (size_t)l * 65536, wt_lo + (size_t)l * 65536,
                                                    att_src + l * 512, att_dst + l * 512,
                                                    hfullb, als, ald);
        gat_gather<<<1024, 256, 0, stream>>>(rowptr, csr_src, als, ald, hfullb,
                                             conv_b + l * 128, gbuf,
                                             bnsum + l * 256, bnsum + l * 256 + 128);
        skip_gate<<<dim3(469, 2), 256, 0, stream>>>(sih, sil, gbuf,
                                                    bnsum + l * 256, gamma + l * 128, beta + l * 128,
                                                    wint_hi + (size_t)l * 16384, wint_lo + (size_t)l * 16384,
                                                    woutt_hi + (size_t)l * 16384, woutt_lo + (size_t)l * 16384,
                                                    sk_bin + l * 128, sk_bout + l * 128,
                                                    soh, sol);
        short* th = sih; short* tl = sil;
        sih = soh; sil = sol;
        soh = th; sol = tl;
    }

    pool_head<<<NGRAPH, 256, 0, stream>>>(sih, sil, gstart, fc1_W, fc1_b, fc3_W, fc3_b, out);
}

// Round 8
// 500.285 us; speedup vs baseline: 1.2917x; 1.1127x over previous
//
#include <hip/hip_runtime.h>
#include <hip/hip_bf16.h>

#define N_NODES 30000
#define N_EDGES 240000
#define ETOT    (N_EDGES + N_NODES)   // 270000 (self loops appended)
#define NGRAPH  128
#define NBLK    118                   // ceil(30000/256)

typedef __attribute__((ext_vector_type(8))) short bf16x8;
typedef __attribute__((ext_vector_type(4))) short bf16x4;
typedef __attribute__((ext_vector_type(4))) float f32x4;

__device__ __forceinline__ unsigned short f2bf(float f) {
    unsigned u = __float_as_uint(f);
    u += 0x7fff + ((u >> 16) & 1);        // round-to-nearest-even
    return (unsigned short)(u >> 16);
}
__device__ __forceinline__ float bf2f(unsigned short h) {
    return __uint_as_float(((unsigned)h) << 16);
}

// ---------- weight transpose + hi/lo bf16 split (once per call) ----------
__global__ __launch_bounds__(256) void conv_weights(const float* __restrict__ W,
                                                    const float* __restrict__ Win,
                                                    const float* __restrict__ Wout,
                                                    short* __restrict__ wt_hi, short* __restrict__ wt_lo,
                                                    short* __restrict__ wint_hi, short* __restrict__ wint_lo,
                                                    short* __restrict__ woutt_hi, short* __restrict__ woutt_lo) {
    int i = blockIdx.x * 256 + threadIdx.x;
    float v; short* dh; short* dl; int di;
    if (i < 196608) {                       // 3*512*128
        int l = i >> 16, r = i & 65535;
        int n = r >> 7, k = r & 127;
        v = W[(size_t)l * 65536 + k * 512 + n];
        dh = wt_hi; dl = wt_lo; di = i;
    } else if (i < 245760) {                // + 3*128*128
        int j = i - 196608;
        int l = j >> 14, r = j & 16383;
        int n = r >> 7, k = r & 127;
        v = Win[(size_t)l * 16384 + k * 128 + n];
        dh = wint_hi; dl = wint_lo; di = j;
    } else if (i < 294912) {
        int j = i - 245760;
        int l = j >> 14, r = j & 16383;
        int n = r >> 7, k = r & 127;
        v = Wout[(size_t)l * 16384 + k * 128 + n];
        dh = woutt_hi; dl = woutt_lo; di = j;
    } else return;
    unsigned short hi = f2bf(v);
    unsigned short lo = f2bf(v - bf2f(hi));
    dh[di] = (short)hi; dl[di] = (short)lo;
}

// ---------- activation split: fp32 [N,128] -> bf16 hi/lo (only for x, once) ----------
__global__ __launch_bounds__(256) void split_act(const float* __restrict__ A,
                                                 short* __restrict__ Ah,
                                                 short* __restrict__ Al) {
    int i = blockIdx.x * 256 + threadIdx.x;       // covers 8 floats each
    if (i >= N_NODES * 16) return;
    const float4* p = (const float4*)A + (size_t)i * 2;
    float4 v0 = p[0], v1 = p[1];
    float f[8] = {v0.x, v0.y, v0.z, v0.w, v1.x, v1.y, v1.z, v1.w};
    bf16x8 h, l;
#pragma unroll
    for (int j = 0; j < 8; j++) {
        unsigned short hh = f2bf(f[j]);
        h[j] = (short)hh;
        l[j] = (short)f2bf(f[j] - bf2f(hh));
    }
    *(bf16x8*)(Ah + (size_t)i * 8) = h;
    *(bf16x8*)(Al + (size_t)i * 8) = l;
}

// ---------- conv GEMM + fused attention-logit epilogue + coalesced bf16 store ----------
// block: 64 rows x 128 cols (one head)
__global__ __launch_bounds__(256) void gemm_conv(const short* __restrict__ Ah,
                                                 const short* __restrict__ Al,
                                                 const short* __restrict__ Bth,
                                                 const short* __restrict__ Btl,
                                                 const float* __restrict__ att_s,
                                                 const float* __restrict__ att_d,
                                                 unsigned short* __restrict__ hfullb,
                                                 float* __restrict__ als,
                                                 float* __restrict__ ald) {
    __shared__ short As_h[64 * 136];
    __shared__ short As_l[64 * 136];
    __shared__ float red_s[2][64], red_d[2][64];
    const int bm = blockIdx.x * 64;
    const int hd = blockIdx.y;            // head = column block
    const int bn = hd * 128;
    const int t  = threadIdx.x;
#pragma unroll
    for (int i = 0; i < 4; i++) {
        int idx8 = t + i * 256;              // 1024 ushort8 slots
        int row = idx8 >> 4, c8 = (idx8 & 15) << 3;
        bf16x8 vh = {}, vl = {};
        if (bm + row < N_NODES) {
            vh = *(const bf16x8*)(Ah + (size_t)(bm + row) * 128 + c8);
            vl = *(const bf16x8*)(Al + (size_t)(bm + row) * 128 + c8);
        }
        *(bf16x8*)(As_h + row * 136 + c8) = vh;
        *(bf16x8*)(As_l + row * 136 + c8) = vl;
    }
    __syncthreads();

    const int w = t >> 6, lane = t & 63;
    const int wr = w >> 1, wc = w & 1;
    const int lr = lane & 15, lg = lane >> 4;
    f32x4 acc[2][4] = {};
    const size_t bofs0 = (size_t)(bn + wc * 64 + lr) * 128 + lg * 8;
#pragma unroll
    for (int kk = 0; kk < 4; kk++) {
        bf16x8 ah[2], al[2], bh[4], bl[4];
#pragma unroll
        for (int ni = 0; ni < 4; ni++) {
            size_t o = bofs0 + (size_t)ni * 16 * 128 + kk * 32;
            bh[ni] = *(const bf16x8*)(Bth + o);
            bl[ni] = *(const bf16x8*)(Btl + o);
        }
        int ko = kk * 32 + lg * 8;
#pragma unroll
        for (int mi = 0; mi < 2; mi++) {
            int r = wr * 32 + mi * 16 + lr;
            ah[mi] = *(const bf16x8*)(As_h + r * 136 + ko);
            al[mi] = *(const bf16x8*)(As_l + r * 136 + ko);
        }
#pragma unroll
        for (int mi = 0; mi < 2; mi++)
#pragma unroll
            for (int ni = 0; ni < 4; ni++) {
                acc[mi][ni] = __builtin_amdgcn_mfma_f32_16x16x32_bf16(ah[mi], bh[ni], acc[mi][ni], 0, 0, 0);
                acc[mi][ni] = __builtin_amdgcn_mfma_f32_16x16x32_bf16(al[mi], bh[ni], acc[mi][ni], 0, 0, 0);
                acc[mi][ni] = __builtin_amdgcn_mfma_f32_16x16x32_bf16(ah[mi], bl[ni], acc[mi][ni], 0, 0, 0);
            }
    }
    // fused attention logits: als[m,hd] = sum_c h[m,c]*att_s[hd,c]  (fp32-exact)
    float as_c[4], ad_c[4];
#pragma unroll
    for (int ni = 0; ni < 4; ni++) {
        int cc = wc * 64 + ni * 16 + lr;
        as_c[ni] = att_s[hd * 128 + cc];
        ad_c[ni] = att_d[hd * 128 + cc];
    }
#pragma unroll
    for (int mi = 0; mi < 2; mi++) {
#pragma unroll
        for (int r = 0; r < 4; r++) {
            float ps = 0.f, pd = 0.f;
#pragma unroll
            for (int ni = 0; ni < 4; ni++) {
                ps = fmaf(acc[mi][ni][r], as_c[ni], ps);
                pd = fmaf(acc[mi][ni][r], ad_c[ni], pd);
            }
#pragma unroll
            for (int off = 1; off < 16; off <<= 1) {
                ps += __shfl_xor(ps, off);
                pd += __shfl_xor(pd, off);
            }
            if (lr == 0) {
                int row = wr * 32 + mi * 16 + lg * 4 + r;
                red_s[wc][row] = ps;
                red_d[wc][row] = pd;
            }
        }
    }
    __syncthreads();            // red complete; As tiles dead -> reuse as C staging
    // stage C tile (bf16) into As_h for coalesced store
#pragma unroll
    for (int mi = 0; mi < 2; mi++)
#pragma unroll
        for (int ni = 0; ni < 4; ni++) {
            int nl = wc * 64 + ni * 16 + lr;
#pragma unroll
            for (int r = 0; r < 4; r++) {
                int row = wr * 32 + mi * 16 + lg * 4 + r;
                As_h[row * 136 + nl] = (short)f2bf(acc[mi][ni][r]);
            }
        }
    if (t < 64) {
        int m = bm + t;
        if (m < N_NODES) als[m * 4 + hd] = red_s[0][t] + red_s[1][t];
    } else if (t < 128) {
        int tt = t - 64;
        int m = bm + tt;
        if (m < N_NODES) ald[m * 4 + hd] = red_d[0][tt] + red_d[1][tt];
    }
    __syncthreads();
    // coalesced bf16x8 store of the 64x128 tile
#pragma unroll
    for (int i2 = 0; i2 < 4; i2++) {
        int idx8 = t + i2 * 256;            // 1024 slots
        int row = idx8 >> 4, c8 = (idx8 & 15) << 3;
        int m = bm + row;
        if (m < N_NODES)
            *(bf16x8*)(hfullb + (size_t)m * 512 + bn + c8) = *(const bf16x8*)(As_h + row * 136 + c8);
    }
}

// ---------- fused skip: P = hin@Win + bn(g)@Wout ; gate+relu epilogue -> bf16 hi/lo ----
__global__ __launch_bounds__(256) void skip_gate(const short* __restrict__ hinh,
                                                 const short* __restrict__ hinl,
                                                 const float* __restrict__ g,
                                                 const float* __restrict__ bnsum,   // [0:128)=sum,[128:256)=sumsq
                                                 const float* __restrict__ gamma,
                                                 const float* __restrict__ beta,
                                                 const short* __restrict__ w1h, const short* __restrict__ w1l,
                                                 const short* __restrict__ w2h, const short* __restrict__ w2l,
                                                 const float* __restrict__ bin, const float* __restrict__ bout,
                                                 short* __restrict__ houth,
                                                 short* __restrict__ houtl) {
    __shared__ short A1h[64 * 136], A1l[64 * 136], A2h[64 * 136], A2l[64 * 136];
    __shared__ float bnp_s[256];
    const int bm = blockIdx.x * 64;
    const int bn = blockIdx.y * 64;
    const int t  = threadIdx.x;
    if (t < 128) {
        float inv = 1.f / (float)N_NODES;
        float mu  = bnsum[t] * inv;
        float var = bnsum[128 + t] * inv - mu * mu;
        float rs  = rsqrtf(var + 1e-5f);
        float sc  = gamma[t] * rs;
        bnp_s[t]       = sc;
        bnp_s[128 + t] = beta[t] - mu * sc;
    }
    __syncthreads();
    // A1: copy pre-split hin tiles
#pragma unroll
    for (int i = 0; i < 4; i++) {
        int idx8 = t + i * 256;
        int row = idx8 >> 4, c8 = (idx8 & 15) << 3;
        bf16x8 vh = {}, vl = {};
        if (bm + row < N_NODES) {
            vh = *(const bf16x8*)(hinh + (size_t)(bm + row) * 128 + c8);
            vl = *(const bf16x8*)(hinl + (size_t)(bm + row) * 128 + c8);
        }
        *(bf16x8*)(A1h + row * 136 + c8) = vh;
        *(bf16x8*)(A1l + row * 136 + c8) = vl;
    }
    // A2: bn(g) + split
#pragma unroll
    for (int i = 0; i < 8; i++) {
        int idx4 = t + i * 256;
        int row = idx4 >> 5, c4 = (idx4 & 31) << 2;
        float4 v2 = make_float4(0.f, 0.f, 0.f, 0.f);
        if (bm + row < N_NODES) {
            float4 gv = *(const float4*)(g + (size_t)(bm + row) * 128 + c4);
            v2.x = fmaf(bnp_s[c4 + 0], gv.x, bnp_s[128 + c4 + 0]);
            v2.y = fmaf(bnp_s[c4 + 1], gv.y, bnp_s[128 + c4 + 1]);
            v2.z = fmaf(bnp_s[c4 + 2], gv.z, bnp_s[128 + c4 + 2]);
            v2.w = fmaf(bnp_s[c4 + 3], gv.w, bnp_s[128 + c4 + 3]);
        }
        unsigned short b0 = f2bf(v2.x), b1 = f2bf(v2.y), b2 = f2bf(v2.z), b3 = f2bf(v2.w);
        *(bf16x4*)(A2h + row * 136 + c4) = (bf16x4){(short)b0, (short)b1, (short)b2, (short)b3};
        *(bf16x4*)(A2l + row * 136 + c4) = (bf16x4){(short)f2bf(v2.x - bf2f(b0)), (short)f2bf(v2.y - bf2f(b1)),
                                                    (short)f2bf(v2.z - bf2f(b2)), (short)f2bf(v2.w - bf2f(b3))};
    }
    __syncthreads();

    const int w = t >> 6, lane = t & 63;
    const int wr = w >> 1, wc = w & 1;
    const int lr = lane & 15, lg = lane >> 4;
    f32x4 acc[2][2] = {};
    const size_t bofs0 = (size_t)(bn + wc * 32 + lr) * 128 + lg * 8;
#pragma unroll
    for (int kk = 0; kk < 4; kk++) {
        bf16x8 a1f[2], a1g[2], a2f[2], a2g[2], b1h[2], b1l[2], b2h[2], b2l[2];
#pragma unroll
        for (int ni = 0; ni < 2; ni++) {
            size_t o = bofs0 + (size_t)ni * 16 * 128 + kk * 32;
            b1h[ni] = *(const bf16x8*)(w1h + o);
            b1l[ni] = *(const bf16x8*)(w1l + o);
            b2h[ni] = *(const bf16x8*)(w2h + o);
            b2l[ni] = *(const bf16x8*)(w2l + o);
        }
        int ko = kk * 32 + lg * 8;
#pragma unroll
        for (int mi = 0; mi < 2; mi++) {
            int r = wr * 32 + mi * 16 + lr;
            a1f[mi] = *(const bf16x8*)(A1h + r * 136 + ko);
            a1g[mi] = *(const bf16x8*)(A1l + r * 136 + ko);
            a2f[mi] = *(const bf16x8*)(A2h + r * 136 + ko);
            a2g[mi] = *(const bf16x8*)(A2l + r * 136 + ko);
        }
#pragma unroll
        for (int mi = 0; mi < 2; mi++)
#pragma unroll
            for (int ni = 0; ni < 2; ni++) {
                acc[mi][ni] = __builtin_amdgcn_mfma_f32_16x16x32_bf16(a1f[mi], b1h[ni], acc[mi][ni], 0, 0, 0);
                acc[mi][ni] = __builtin_amdgcn_mfma_f32_16x16x32_bf16(a1g[mi], b1h[ni], acc[mi][ni], 0, 0, 0);
                acc[mi][ni] = __builtin_amdgcn_mfma_f32_16x16x32_bf16(a1f[mi], b1l[ni], acc[mi][ni], 0, 0, 0);
                acc[mi][ni] = __builtin_amdgcn_mfma_f32_16x16x32_bf16(a2f[mi], b2h[ni], acc[mi][ni], 0, 0, 0);
                acc[mi][ni] = __builtin_amdgcn_mfma_f32_16x16x32_bf16(a2g[mi], b2h[ni], acc[mi][ni], 0, 0, 0);
                acc[mi][ni] = __builtin_amdgcn_mfma_f32_16x16x32_bf16(a2f[mi], b2l[ni], acc[mi][ni], 0, 0, 0);
            }
    }
    // gate+relu into acc (reads A-tiles for skip reconstruct)
#pragma unroll
    for (int mi = 0; mi < 2; mi++) {
#pragma unroll
        for (int ni = 0; ni < 2; ni++) {
            int n = bn + wc * 32 + ni * 16 + lr;
            float bsum = bin[n] + bout[n];
#pragma unroll
            for (int r = 0; r < 4; r++) {
                int lrow = wr * 32 + mi * 16 + lg * 4 + r;
                float hbnv = bf2f((unsigned short)A2h[lrow * 136 + n]) + bf2f((unsigned short)A2l[lrow * 136 + n]);
                float hv   = bf2f((unsigned short)A1h[lrow * 136 + n]) + bf2f((unsigned short)A1l[lrow * 136 + n]);
                float gt   = 1.f / (1.f + __expf(-(acc[mi][ni][r] + bsum)));
                acc[mi][ni][r] = fmaxf(gt * hbnv + (1.f - gt) * hv, 0.f);
            }
        }
    }
    __syncthreads();            // A-tiles dead -> reuse as output staging
#pragma unroll
    for (int mi = 0; mi < 2; mi++)
#pragma unroll
        for (int ni = 0; ni < 2; ni++) {
            int n = bn + wc * 32 + ni * 16 + lr;
#pragma unroll
            for (int r = 0; r < 4; r++) {
                int lrow = wr * 32 + mi * 16 + lg * 4 + r;
                float ov = acc[mi][ni][r];
                unsigned short oh = f2bf(ov);
                A1h[lrow * 136 + n] = (short)oh;
                A1l[lrow * 136 + n] = (short)f2bf(ov - bf2f(oh));
            }
        }
    __syncthreads();
    // coalesced store of 64-row x 64-col window
#pragma unroll
    for (int i2 = 0; i2 < 2; i2++) {
        int idx8 = t + i2 * 256;            // 512 slots = 64 rows x 8
        int row = idx8 >> 3, c8 = (idx8 & 7) << 3;
        int m = bm + row;
        if (m < N_NODES) {
            *(bf16x8*)(houth + (size_t)m * 128 + bn + c8) = *(const bf16x8*)(A1h + row * 136 + bn + c8);
            *(bf16x8*)(houtl + (size_t)m * 128 + bn + c8) = *(const bf16x8*)(A1l + row * 136 + bn + c8);
        }
    }
}

// ---------------- CSR build ----------------
__global__ __launch_bounds__(256) void deg_kernel(const int* __restrict__ ei1,
                                                  int* __restrict__ deg) {
    int e = blockIdx.x * 256 + threadIdx.x;
    if (e >= ETOT) return;
    int d = (e < N_EDGES) ? ei1[e] : (e - N_EDGES);
    atomicAdd(&deg[d], 1);
}

// hierarchical scan: scan1 (per-block) -> scan2 (block sums) -> scan3 (combine)
__global__ __launch_bounds__(256) void scan1(const int* __restrict__ deg,
                                             int* __restrict__ tmp,
                                             int* __restrict__ blksum) {
    int i = blockIdx.x * 256 + threadIdx.x;
    int v = (i < N_NODES) ? deg[i] : 0;
    __shared__ int sh[256];
    sh[threadIdx.x] = v;
    __syncthreads();
    int acc = v;
    for (int off = 1; off < 256; off <<= 1) {
        int u = (threadIdx.x >= off) ? sh[threadIdx.x - off] : 0;
        __syncthreads();
        acc += u;
        sh[threadIdx.x] = acc;
        __syncthreads();
    }
    if (i < N_NODES) tmp[i] = acc - v;     // exclusive within block
    if (threadIdx.x == 255) blksum[blockIdx.x] = acc;
}

__global__ void scan2(const int* __restrict__ blksum, int* __restrict__ blkoff) {
    int t = threadIdx.x;                   // 128 threads >= NBLK
    int v = (t < NBLK) ? blksum[t] : 0;
    __shared__ int sh[128];
    sh[t] = v;
    __syncthreads();
    int acc = v;
    for (int off = 1; off < 128; off <<= 1) {
        int u = (t >= off) ? sh[t - off] : 0;
        __syncthreads();
        acc += u;
        sh[t] = acc;
        __syncthreads();
    }
    if (t < NBLK) blkoff[t] = acc - v;     // exclusive block offset
}

__global__ __launch_bounds__(256) void scan3(const int* __restrict__ tmp,
                                             const int* __restrict__ blkoff,
                                             int* __restrict__ rowptr,
                                             int* __restrict__ wofs) {
    int i = blockIdx.x * 256 + threadIdx.x;
    if (i == 0) rowptr[N_NODES] = ETOT;    // total is a compile-time constant
    if (i < N_NODES) {
        int r = tmp[i] + blkoff[blockIdx.x];
        rowptr[i] = r;
        wofs[i]   = r;
    }
}

__global__ __launch_bounds__(256) void scatter_kernel(const int* __restrict__ ei0,
                                                      const int* __restrict__ ei1,
                                                      int* __restrict__ wofs,
                                                      int* __restrict__ csr_src) {
    int e = blockIdx.x * 256 + threadIdx.x;
    if (e >= ETOT) return;
    int s = (e < N_EDGES) ? ei0[e] : (e - N_EDGES);
    int d = (e < N_EDGES) ? ei1[e] : (e - N_EDGES);
    int pos = atomicAdd(&wofs[d], 1);
    csr_src[pos] = s;
}

// ---------------- fused gather: single pass, 4-edge load-clustered ----------------
__global__ __launch_bounds__(256) void gat_gather(const int* __restrict__ rowptr,
                                                  const int* __restrict__ csr_src,
                                                  const float* __restrict__ al_s,
                                                  const float* __restrict__ al_d,
                                                  const unsigned short* __restrict__ hfullb,
                                                  const float* __restrict__ conv_b,
                                                  float* __restrict__ g,
                                                  float* __restrict__ bnsum,
                                                  float* __restrict__ bnsum2) {
    const int lane = threadIdx.x & 63;
    const int wib  = threadIdx.x >> 6;
    const int gwid = blockIdx.x * 4 + wib;
    const int nw   = gridDim.x * 4;
    const int h    = lane >> 4;
    const int sub  = lane & 15;
    float s1[8] = {}, s2[8] = {};

    for (int n = gwid; n < N_NODES; n += nw) {
        const int e0 = rowptr[n], e1 = rowptr[n + 1];
        const float ald_h = al_d[n * 4 + h];

        float acc[8] = {};
        float zs = 0.f;
        int i = e0;
        for (; i + 3 < e1; i += 4) {
            int sA = csr_src[i], sB = csr_src[i + 1], sC = csr_src[i + 2], sD = csr_src[i + 3];
            bf16x8 ha = *(const bf16x8*)(hfullb + (size_t)sA * 512 + lane * 8);
            bf16x8 hb = *(const bf16x8*)(hfullb + (size_t)sB * 512 + lane * 8);
            bf16x8 hc = *(const bf16x8*)(hfullb + (size_t)sC * 512 + lane * 8);
            bf16x8 hd = *(const bf16x8*)(hfullb + (size_t)sD * 512 + lane * 8);
            float vA = al_s[sA * 4 + h] + ald_h; vA = (vA > 0.f) ? vA : 0.2f * vA;
            float vB = al_s[sB * 4 + h] + ald_h; vB = (vB > 0.f) ? vB : 0.2f * vB;
            float vC = al_s[sC * 4 + h] + ald_h; vC = (vC > 0.f) ? vC : 0.2f * vC;
            float vD = al_s[sD * 4 + h] + ald_h; vD = (vD > 0.f) ? vD : 0.2f * vD;
            float exA = __expf(vA), exB = __expf(vB), exC = __expf(vC), exD = __expf(vD);
            zs += (exA + exB) + (exC + exD);
#pragma unroll
            for (int j = 0; j < 8; j++) {
                float a = fmaf(exA, bf2f((unsigned short)ha[j]), acc[j]);
                a = fmaf(exB, bf2f((unsigned short)hb[j]), a);
                a = fmaf(exC, bf2f((unsigned short)hc[j]), a);
                acc[j] = fmaf(exD, bf2f((unsigned short)hd[j]), a);
            }
        }
        for (; i < e1; i++) {
            int sA = csr_src[i];
            bf16x8 ha = *(const bf16x8*)(hfullb + (size_t)sA * 512 + lane * 8);
            float vA = al_s[sA * 4 + h] + ald_h; vA = (vA > 0.f) ? vA : 0.2f * vA;
            float exA = __expf(vA);
            zs += exA;
#pragma unroll
            for (int j = 0; j < 8; j++)
                acc[j] = fmaf(exA, bf2f((unsigned short)ha[j]), acc[j]);
        }

        float inv = 0.25f / (zs + 1e-16f);
#pragma unroll
        for (int j = 0; j < 8; j++) {
            float a = acc[j] * inv;
            a += __shfl_xor(a, 16);
            a += __shfl_xor(a, 32);
            acc[j] = a;
        }
        if (lane < 16) {
            float o[8];
#pragma unroll
            for (int j = 0; j < 8; j++) {
                float tv = acc[j] + conv_b[sub * 8 + j];
                o[j] = tv;
                s1[j] += tv;
                s2[j] = fmaf(tv, tv, s2[j]);
            }
            float* gp = g + (size_t)n * 128 + sub * 8;
            *(float4*)gp       = make_float4(o[0], o[1], o[2], o[3]);
            *(float4*)(gp + 4) = make_float4(o[4], o[5], o[6], o[7]);
        }
    }

    __shared__ float redA[4][128], redB[4][128];
    if (lane < 16) {
#pragma unroll
        for (int j = 0; j < 8; j++) {
            redA[wib][sub * 8 + j] = s1[j];
            redB[wib][sub * 8 + j] = s2[j];
        }
    }
    __syncthreads();
    int t = threadIdx.x;
    if (t < 128) {
        atomicAdd(&bnsum[t], redA[0][t] + redA[1][t] + redA[2][t] + redA[3][t]);
    } else {
        int c = t - 128;
        atomicAdd(&bnsum2[c], redB[0][c] + redB[1][c] + redB[2][c] + redB[3][c]);
    }
}

// ---------------- pooling + MLP head fused; sorted batch -> segment sums ----------------
__global__ void bounds_kernel(const int* __restrict__ batch, int* __restrict__ gstart) {
    int t = threadIdx.x;
    if (t > NGRAPH) return;
    int lo = 0, hi = N_NODES;
    while (lo < hi) { int mid = (lo + hi) >> 1; if (batch[mid] < t) lo = mid + 1; else hi = mid; }
    gstart[t] = lo;
}

__global__ __launch_bounds__(256) void pool_head(const short* __restrict__ hh,
                                                 const short* __restrict__ hl,
                                                 const int* __restrict__ gstart,
                                                 const float* __restrict__ fc1W,
                                                 const float* __restrict__ fc1b,
                                                 const float* __restrict__ fc3W,
                                                 const float* __restrict__ fc3b,
                                                 float* __restrict__ out) {
    int gid = blockIdx.x, t = threadIdx.x;
    int lo = gstart[gid], hi = gstart[gid + 1];
    int c = t & 127, half = t >> 7;
    float s = 0.f;
    for (int n = lo + half; n < hi; n += 2) {
        size_t idx = (size_t)n * 128 + c;
        s += bf2f((unsigned short)hh[idx]) + bf2f((unsigned short)hl[idx]);
    }
    __shared__ float sh[256];
    __shared__ float hg[128], a1[128];
    sh[t] = s;
    __syncthreads();
    if (half == 0) {
        float cc = fmaxf((float)(hi - lo), 1.f);
        hg[c] = (sh[c] + sh[c + 128]) / cc;
    }
    __syncthreads();
    if (t < 128) {
        float v = fc1b[t];
        for (int c2 = 0; c2 < 128; c2++) v = fmaf(hg[c2], fc1W[c2 * 128 + t], v);
        a1[t] = fmaxf(v, 0.f);
    }
    __syncthreads();
    if (t < 16) {
        float o = fc3b[t];
        for (int j = 0; j < 128; j++) o = fmaf(a1[j], fc3W[j * 16 + t], o);
        out[gid * 16 + t] = o;
    }
}

extern "C" void kernel_launch(void* const* d_in, const int* in_sizes, int n_in,
                              void* d_out, int out_size, void* d_ws, size_t ws_size,
                              hipStream_t stream) {
    const float* x       = (const float*)d_in[0];
    const int*   ei      = (const int*)d_in[1];
    const int*   batch   = (const int*)d_in[2];
    const float* W       = (const float*)d_in[3];
    const float* att_src = (const float*)d_in[4];
    const float* att_dst = (const float*)d_in[5];
    const float* conv_b  = (const float*)d_in[6];
    const float* gamma   = (const float*)d_in[7];
    const float* beta    = (const float*)d_in[8];
    const float* sk_Win  = (const float*)d_in[9];
    const float* sk_bin  = (const float*)d_in[10];
    const float* sk_Wout = (const float*)d_in[11];
    const float* sk_bout = (const float*)d_in[12];
    const float* fc1_W   = (const float*)d_in[13];
    const float* fc1_b   = (const float*)d_in[14];
    const float* fc3_W   = (const float*)d_in[15];
    const float* fc3_b   = (const float*)d_in[16];
    float* out = (float*)d_out;
    const int* ei0 = ei;
    const int* ei1 = ei + N_EDGES;

    float* ws = (float*)d_ws;
    size_t o = 0;
    unsigned short* hfullb = (unsigned short*)(ws + o); o += (size_t)N_NODES * 256;  // bf16 [N,512]
    float* gbuf   = ws + o; o += (size_t)N_NODES * 128;
    short* spAh   = (short*)(ws + o); o += (size_t)N_NODES * 64;   // bf16 [N,128] ping
    short* spAl   = (short*)(ws + o); o += (size_t)N_NODES * 64;
    short* spBh   = (short*)(ws + o); o += (size_t)N_NODES * 64;   // pong
    short* spBl   = (short*)(ws + o); o += (size_t)N_NODES * 64;
    float* als    = ws + o; o += N_NODES * 4;
    float* ald    = ws + o; o += N_NODES * 4;
    float* bnsum  = ws + o; o += 768;      // 3 layers x (128 sum + 128 sumsq)
    short* wt_hi   = (short*)(ws + o); o += 98304;   // 3*512*128 shorts
    short* wt_lo   = (short*)(ws + o); o += 98304;
    short* wint_hi = (short*)(ws + o); o += 24576;   // 3*128*128 shorts
    short* wint_lo = (short*)(ws + o); o += 24576;
    short* woutt_hi = (short*)(ws + o); o += 24576;
    short* woutt_lo = (short*)(ws + o); o += 24576;
    int* gstart   = (int*)(ws + o); o += 132;
    int* deg      = (int*)(ws + o); o += N_NODES;
    int* rowptr   = (int*)(ws + o); o += N_NODES + 4;
    int* wofs     = (int*)(ws + o); o += N_NODES;
    int* scantmp  = (int*)(ws + o); o += N_NODES;
    int* blksum   = (int*)(ws + o); o += NBLK + 2;
    int* blkoff   = (int*)(ws + o); o += NBLK + 2;
    int* csr_src  = (int*)(ws + o); o += ETOT;

    conv_weights<<<1152, 256, 0, stream>>>(W, sk_Win, sk_Wout,
                                           wt_hi, wt_lo, wint_hi, wint_lo, woutt_hi, woutt_lo);

    hipMemsetAsync(deg, 0, N_NODES * 4, stream);
    hipMemsetAsync(bnsum, 0, 768 * 4, stream);
    deg_kernel<<<(ETOT + 255) / 256, 256, 0, stream>>>(ei1, deg);
    scan1<<<NBLK, 256, 0, stream>>>(deg, scantmp, blksum);
    scan2<<<1, 128, 0, stream>>>(blksum, blkoff);
    scan3<<<NBLK, 256, 0, stream>>>(scantmp, blkoff, rowptr, wofs);
    scatter_kernel<<<(ETOT + 255) / 256, 256, 0, stream>>>(ei0, ei1, wofs, csr_src);
    bounds_kernel<<<1, 256, 0, stream>>>(batch, gstart);
    split_act<<<1875, 256, 0, stream>>>(x, spAh, spAl);

    short* sih = spAh; short* sil = spAl;
    short* soh = spBh; short* sol = spBl;
    for (int l = 0; l < 3; l++) {
        gemm_conv<<<dim3(469, 4), 256, 0, stream>>>(sih, sil,
                                                    wt_hi + (size_t)l * 65536, wt_lo + (size_t)l * 65536,
                                                    att_src + l * 512, att_dst + l * 512,
                                                    hfullb, als, ald);
        gat_gather<<<1024, 256, 0, stream>>>(rowptr, csr_src, als, ald, hfullb,
                                             conv_b + l * 128, gbuf,
                                             bnsum + l * 256, bnsum + l * 256 + 128);
        skip_gate<<<dim3(469, 2), 256, 0, stream>>>(sih, sil, gbuf,
                                                    bnsum + l * 256, gamma + l * 128, beta + l * 128,
                                                    wint_hi + (size_t)l * 16384, wint_lo + (size_t)l * 16384,
                                                    woutt_hi + (size_t)l * 16384, woutt_lo + (size_t)l * 16384,
                                                    sk_bin + l * 128, sk_bout + l * 128,
                                                    soh, sol);
        short* th = sih; short* tl = sil;
        sih = soh; sil = sol;
        soh = th; sol = tl;
    }

    pool_head<<<NGRAPH, 256, 0, stream>>>(sih, sil, gstart, fc1_W, fc1_b, fc3_W, fc3_b, out);
}

// Round 9
// 498.934 us; speedup vs baseline: 1.2952x; 1.0027x over previous
//
#include <hip/hip_runtime.h>
#include <hip/hip_bf16.h>

#define N_NODES 30000
#define N_EDGES 240000
#define ETOT    (N_EDGES + N_NODES)   // 270000 (self loops appended)
#define NGRAPH  128
#define NBLK    118                   // ceil(30000/256)

typedef __attribute__((ext_vector_type(8))) short bf16x8;
typedef __attribute__((ext_vector_type(4))) short bf16x4;
typedef __attribute__((ext_vector_type(4))) float f32x4;

__device__ __forceinline__ unsigned short f2bf(float f) {
    unsigned u = __float_as_uint(f);
    u += 0x7fff + ((u >> 16) & 1);        // round-to-nearest-even
    return (unsigned short)(u >> 16);
}
__device__ __forceinline__ float bf2f(unsigned short h) {
    return __uint_as_float(((unsigned)h) << 16);
}

// ---------- weight transpose + hi/lo bf16 split (once per call) ----------
__global__ __launch_bounds__(256) void conv_weights(const float* __restrict__ W,
                                                    const float* __restrict__ Win,
                                                    const float* __restrict__ Wout,
                                                    short* __restrict__ wt_hi, short* __restrict__ wt_lo,
                                                    short* __restrict__ wint_hi, short* __restrict__ wint_lo,
                                                    short* __restrict__ woutt_hi, short* __restrict__ woutt_lo) {
    int i = blockIdx.x * 256 + threadIdx.x;
    float v; short* dh; short* dl; int di;
    if (i < 196608) {                       // 3*512*128
        int l = i >> 16, r = i & 65535;
        int n = r >> 7, k = r & 127;
        v = W[(size_t)l * 65536 + k * 512 + n];
        dh = wt_hi; dl = wt_lo; di = i;
    } else if (i < 245760) {                // + 3*128*128
        int j = i - 196608;
        int l = j >> 14, r = j & 16383;
        int n = r >> 7, k = r & 127;
        v = Win[(size_t)l * 16384 + k * 128 + n];
        dh = wint_hi; dl = wint_lo; di = j;
    } else if (i < 294912) {
        int j = i - 245760;
        int l = j >> 14, r = j & 16383;
        int n = r >> 7, k = r & 127;
        v = Wout[(size_t)l * 16384 + k * 128 + n];
        dh = woutt_hi; dl = woutt_lo; di = j;
    } else return;
    unsigned short hi = f2bf(v);
    unsigned short lo = f2bf(v - bf2f(hi));
    dh[di] = (short)hi; dl[di] = (short)lo;
}

// ---------- activation split: fp32 [N,128] -> bf16 hi/lo (only for x, once) ----------
__global__ __launch_bounds__(256) void split_act(const float* __restrict__ A,
                                                 short* __restrict__ Ah,
                                                 short* __restrict__ Al) {
    int i = blockIdx.x * 256 + threadIdx.x;       // covers 8 floats each
    if (i >= N_NODES * 16) return;
    const float4* p = (const float4*)A + (size_t)i * 2;
    float4 v0 = p[0], v1 = p[1];
    float f[8] = {v0.x, v0.y, v0.z, v0.w, v1.x, v1.y, v1.z, v1.w};
    bf16x8 h, l;
#pragma unroll
    for (int j = 0; j < 8; j++) {
        unsigned short hh = f2bf(f[j]);
        h[j] = (short)hh;
        l[j] = (short)f2bf(f[j] - bf2f(hh));
    }
    *(bf16x8*)(Ah + (size_t)i * 8) = h;
    *(bf16x8*)(Al + (size_t)i * 8) = l;
}

// ---------- conv GEMM + fused attention-logit epilogue + coalesced bf16 store ----------
// block: 64 rows x 128 cols (one head)
__global__ __launch_bounds__(256) void gemm_conv(const short* __restrict__ Ah,
                                                 const short* __restrict__ Al,
                                                 const short* __restrict__ Bth,
                                                 const short* __restrict__ Btl,
                                                 const float* __restrict__ att_s,
                                                 const float* __restrict__ att_d,
                                                 unsigned short* __restrict__ hfullb,
                                                 float* __restrict__ als,
                                                 float* __restrict__ ald) {
    __shared__ short As_h[64 * 136];
    __shared__ short As_l[64 * 136];
    __shared__ float red_s[2][64], red_d[2][64];
    const int bm = blockIdx.x * 64;
    const int hd = blockIdx.y;            // head = column block
    const int bn = hd * 128;
    const int t  = threadIdx.x;
#pragma unroll
    for (int i = 0; i < 4; i++) {
        int idx8 = t + i * 256;              // 1024 ushort8 slots
        int row = idx8 >> 4, c8 = (idx8 & 15) << 3;
        bf16x8 vh = {}, vl = {};
        if (bm + row < N_NODES) {
            vh = *(const bf16x8*)(Ah + (size_t)(bm + row) * 128 + c8);
            vl = *(const bf16x8*)(Al + (size_t)(bm + row) * 128 + c8);
        }
        *(bf16x8*)(As_h + row * 136 + c8) = vh;
        *(bf16x8*)(As_l + row * 136 + c8) = vl;
    }
    __syncthreads();

    const int w = t >> 6, lane = t & 63;
    const int wr = w >> 1, wc = w & 1;
    const int lr = lane & 15, lg = lane >> 4;
    f32x4 acc[2][4] = {};
    const size_t bofs0 = (size_t)(bn + wc * 64 + lr) * 128 + lg * 8;
#pragma unroll
    for (int kk = 0; kk < 4; kk++) {
        bf16x8 ah[2], al[2], bh[4], bl[4];
#pragma unroll
        for (int ni = 0; ni < 4; ni++) {
            size_t o = bofs0 + (size_t)ni * 16 * 128 + kk * 32;
            bh[ni] = *(const bf16x8*)(Bth + o);
            bl[ni] = *(const bf16x8*)(Btl + o);
        }
        int ko = kk * 32 + lg * 8;
#pragma unroll
        for (int mi = 0; mi < 2; mi++) {
            int r = wr * 32 + mi * 16 + lr;
            ah[mi] = *(const bf16x8*)(As_h + r * 136 + ko);
            al[mi] = *(const bf16x8*)(As_l + r * 136 + ko);
        }
#pragma unroll
        for (int mi = 0; mi < 2; mi++)
#pragma unroll
            for (int ni = 0; ni < 4; ni++) {
                acc[mi][ni] = __builtin_amdgcn_mfma_f32_16x16x32_bf16(ah[mi], bh[ni], acc[mi][ni], 0, 0, 0);
                acc[mi][ni] = __builtin_amdgcn_mfma_f32_16x16x32_bf16(al[mi], bh[ni], acc[mi][ni], 0, 0, 0);
                acc[mi][ni] = __builtin_amdgcn_mfma_f32_16x16x32_bf16(ah[mi], bl[ni], acc[mi][ni], 0, 0, 0);
            }
    }
    // fused attention logits: als[m,hd] = sum_c h[m,c]*att_s[hd,c]  (fp32-exact)
    float as_c[4], ad_c[4];
#pragma unroll
    for (int ni = 0; ni < 4; ni++) {
        int cc = wc * 64 + ni * 16 + lr;
        as_c[ni] = att_s[hd * 128 + cc];
        ad_c[ni] = att_d[hd * 128 + cc];
    }
#pragma unroll
    for (int mi = 0; mi < 2; mi++) {
#pragma unroll
        for (int r = 0; r < 4; r++) {
            float ps = 0.f, pd = 0.f;
#pragma unroll
            for (int ni = 0; ni < 4; ni++) {
                ps = fmaf(acc[mi][ni][r], as_c[ni], ps);
                pd = fmaf(acc[mi][ni][r], ad_c[ni], pd);
            }
#pragma unroll
            for (int off = 1; off < 16; off <<= 1) {
                ps += __shfl_xor(ps, off);
                pd += __shfl_xor(pd, off);
            }
            if (lr == 0) {
                int row = wr * 32 + mi * 16 + lg * 4 + r;
                red_s[wc][row] = ps;
                red_d[wc][row] = pd;
            }
        }
    }
    __syncthreads();            // red complete; As tiles dead -> reuse as C staging
    // stage C tile (bf16) into As_h for coalesced store
#pragma unroll
    for (int mi = 0; mi < 2; mi++)
#pragma unroll
        for (int ni = 0; ni < 4; ni++) {
            int nl = wc * 64 + ni * 16 + lr;
#pragma unroll
            for (int r = 0; r < 4; r++) {
                int row = wr * 32 + mi * 16 + lg * 4 + r;
                As_h[row * 136 + nl] = (short)f2bf(acc[mi][ni][r]);
            }
        }
    if (t < 64) {
        int m = bm + t;
        if (m < N_NODES) als[m * 4 + hd] = red_s[0][t] + red_s[1][t];
    } else if (t < 128) {
        int tt = t - 64;
        int m = bm + tt;
        if (m < N_NODES) ald[m * 4 + hd] = red_d[0][tt] + red_d[1][tt];
    }
    __syncthreads();
    // coalesced bf16x8 store of the 64x128 tile
#pragma unroll
    for (int i2 = 0; i2 < 4; i2++) {
        int idx8 = t + i2 * 256;            // 1024 slots
        int row = idx8 >> 4, c8 = (idx8 & 15) << 3;
        int m = bm + row;
        if (m < N_NODES)
            *(bf16x8*)(hfullb + (size_t)m * 512 + bn + c8) = *(const bf16x8*)(As_h + row * 136 + c8);
    }
}

// ---------- fused skip: P = hin@Win + bn(g)@Wout ; gate+relu epilogue -> bf16 hi/lo ----
__global__ __launch_bounds__(256) void skip_gate(const short* __restrict__ hinh,
                                                 const short* __restrict__ hinl,
                                                 const float* __restrict__ g,
                                                 const float* __restrict__ bnsum,   // [0:128)=sum,[128:256)=sumsq
                                                 const float* __restrict__ gamma,
                                                 const float* __restrict__ beta,
                                                 const short* __restrict__ w1h, const short* __restrict__ w1l,
                                                 const short* __restrict__ w2h, const short* __restrict__ w2l,
                                                 const float* __restrict__ bin, const float* __restrict__ bout,
                                                 short* __restrict__ houth,
                                                 short* __restrict__ houtl) {
    __shared__ short A1h[64 * 136], A1l[64 * 136], A2h[64 * 136], A2l[64 * 136];
    __shared__ float bnp_s[256];
    const int bm = blockIdx.x * 64;
    const int bn = blockIdx.y * 64;
    const int t  = threadIdx.x;
    if (t < 128) {
        float inv = 1.f / (float)N_NODES;
        float mu  = bnsum[t] * inv;
        float var = bnsum[128 + t] * inv - mu * mu;
        float rs  = rsqrtf(var + 1e-5f);
        float sc  = gamma[t] * rs;
        bnp_s[t]       = sc;
        bnp_s[128 + t] = beta[t] - mu * sc;
    }
    __syncthreads();
    // A1: copy pre-split hin tiles
#pragma unroll
    for (int i = 0; i < 4; i++) {
        int idx8 = t + i * 256;
        int row = idx8 >> 4, c8 = (idx8 & 15) << 3;
        bf16x8 vh = {}, vl = {};
        if (bm + row < N_NODES) {
            vh = *(const bf16x8*)(hinh + (size_t)(bm + row) * 128 + c8);
            vl = *(const bf16x8*)(hinl + (size_t)(bm + row) * 128 + c8);
        }
        *(bf16x8*)(A1h + row * 136 + c8) = vh;
        *(bf16x8*)(A1l + row * 136 + c8) = vl;
    }
    // A2: bn(g) + split
#pragma unroll
    for (int i = 0; i < 8; i++) {
        int idx4 = t + i * 256;
        int row = idx4 >> 5, c4 = (idx4 & 31) << 2;
        float4 v2 = make_float4(0.f, 0.f, 0.f, 0.f);
        if (bm + row < N_NODES) {
            float4 gv = *(const float4*)(g + (size_t)(bm + row) * 128 + c4);
            v2.x = fmaf(bnp_s[c4 + 0], gv.x, bnp_s[128 + c4 + 0]);
            v2.y = fmaf(bnp_s[c4 + 1], gv.y, bnp_s[128 + c4 + 1]);
            v2.z = fmaf(bnp_s[c4 + 2], gv.z, bnp_s[128 + c4 + 2]);
            v2.w = fmaf(bnp_s[c4 + 3], gv.w, bnp_s[128 + c4 + 3]);
        }
        unsigned short b0 = f2bf(v2.x), b1 = f2bf(v2.y), b2 = f2bf(v2.z), b3 = f2bf(v2.w);
        *(bf16x4*)(A2h + row * 136 + c4) = (bf16x4){(short)b0, (short)b1, (short)b2, (short)b3};
        *(bf16x4*)(A2l + row * 136 + c4) = (bf16x4){(short)f2bf(v2.x - bf2f(b0)), (short)f2bf(v2.y - bf2f(b1)),
                                                    (short)f2bf(v2.z - bf2f(b2)), (short)f2bf(v2.w - bf2f(b3))};
    }
    __syncthreads();

    const int w = t >> 6, lane = t & 63;
    const int wr = w >> 1, wc = w & 1;
    const int lr = lane & 15, lg = lane >> 4;
    f32x4 acc[2][2] = {};
    const size_t bofs0 = (size_t)(bn + wc * 32 + lr) * 128 + lg * 8;
#pragma unroll
    for (int kk = 0; kk < 4; kk++) {
        bf16x8 a1f[2], a1g[2], a2f[2], a2g[2], b1h[2], b1l[2], b2h[2], b2l[2];
#pragma unroll
        for (int ni = 0; ni < 2; ni++) {
            size_t o = bofs0 + (size_t)ni * 16 * 128 + kk * 32;
            b1h[ni] = *(const bf16x8*)(w1h + o);
            b1l[ni] = *(const bf16x8*)(w1l + o);
            b2h[ni] = *(const bf16x8*)(w2h + o);
            b2l[ni] = *(const bf16x8*)(w2l + o);
        }
        int ko = kk * 32 + lg * 8;
#pragma unroll
        for (int mi = 0; mi < 2; mi++) {
            int r = wr * 32 + mi * 16 + lr;
            a1f[mi] = *(const bf16x8*)(A1h + r * 136 + ko);
            a1g[mi] = *(const bf16x8*)(A1l + r * 136 + ko);
            a2f[mi] = *(const bf16x8*)(A2h + r * 136 + ko);
            a2g[mi] = *(const bf16x8*)(A2l + r * 136 + ko);
        }
#pragma unroll
        for (int mi = 0; mi < 2; mi++)
#pragma unroll
            for (int ni = 0; ni < 2; ni++) {
                acc[mi][ni] = __builtin_amdgcn_mfma_f32_16x16x32_bf16(a1f[mi], b1h[ni], acc[mi][ni], 0, 0, 0);
                acc[mi][ni] = __builtin_amdgcn_mfma_f32_16x16x32_bf16(a1g[mi], b1h[ni], acc[mi][ni], 0, 0, 0);
                acc[mi][ni] = __builtin_amdgcn_mfma_f32_16x16x32_bf16(a1f[mi], b1l[ni], acc[mi][ni], 0, 0, 0);
                acc[mi][ni] = __builtin_amdgcn_mfma_f32_16x16x32_bf16(a2f[mi], b2h[ni], acc[mi][ni], 0, 0, 0);
                acc[mi][ni] = __builtin_amdgcn_mfma_f32_16x16x32_bf16(a2g[mi], b2h[ni], acc[mi][ni], 0, 0, 0);
                acc[mi][ni] = __builtin_amdgcn_mfma_f32_16x16x32_bf16(a2f[mi], b2l[ni], acc[mi][ni], 0, 0, 0);
            }
    }
    // gate+relu into acc (reads A-tiles for skip reconstruct)
#pragma unroll
    for (int mi = 0; mi < 2; mi++) {
#pragma unroll
        for (int ni = 0; ni < 2; ni++) {
            int n = bn + wc * 32 + ni * 16 + lr;
            float bsum = bin[n] + bout[n];
#pragma unroll
            for (int r = 0; r < 4; r++) {
                int lrow = wr * 32 + mi * 16 + lg * 4 + r;
                float hbnv = bf2f((unsigned short)A2h[lrow * 136 + n]) + bf2f((unsigned short)A2l[lrow * 136 + n]);
                float hv   = bf2f((unsigned short)A1h[lrow * 136 + n]) + bf2f((unsigned short)A1l[lrow * 136 + n]);
                float gt   = 1.f / (1.f + __expf(-(acc[mi][ni][r] + bsum)));
                acc[mi][ni][r] = fmaxf(gt * hbnv + (1.f - gt) * hv, 0.f);
            }
        }
    }
    __syncthreads();            // A-tiles dead -> reuse as output staging
#pragma unroll
    for (int mi = 0; mi < 2; mi++)
#pragma unroll
        for (int ni = 0; ni < 2; ni++) {
            int n = bn + wc * 32 + ni * 16 + lr;
#pragma unroll
            for (int r = 0; r < 4; r++) {
                int lrow = wr * 32 + mi * 16 + lg * 4 + r;
                float ov = acc[mi][ni][r];
                unsigned short oh = f2bf(ov);
                A1h[lrow * 136 + n] = (short)oh;
                A1l[lrow * 136 + n] = (short)f2bf(ov - bf2f(oh));
            }
        }
    __syncthreads();
    // coalesced store of 64-row x 64-col window
#pragma unroll
    for (int i2 = 0; i2 < 2; i2++) {
        int idx8 = t + i2 * 256;            // 512 slots = 64 rows x 8
        int row = idx8 >> 3, c8 = (idx8 & 7) << 3;
        int m = bm + row;
        if (m < N_NODES) {
            *(bf16x8*)(houth + (size_t)m * 128 + bn + c8) = *(const bf16x8*)(A1h + row * 136 + bn + c8);
            *(bf16x8*)(houtl + (size_t)m * 128 + bn + c8) = *(const bf16x8*)(A1l + row * 136 + bn + c8);
        }
    }
}

// ---------------- CSR build ----------------
__global__ __launch_bounds__(256) void deg_kernel(const int* __restrict__ ei1,
                                                  int* __restrict__ deg) {
    int e = blockIdx.x * 256 + threadIdx.x;
    if (e >= ETOT) return;
    int d = (e < N_EDGES) ? ei1[e] : (e - N_EDGES);
    atomicAdd(&deg[d], 1);
}

// hierarchical scan: scan1 (per-block) -> scan2 (block sums) -> scan3 (combine)
__global__ __launch_bounds__(256) void scan1(const int* __restrict__ deg,
                                             int* __restrict__ tmp,
                                             int* __restrict__ blksum) {
    int i = blockIdx.x * 256 + threadIdx.x;
    int v = (i < N_NODES) ? deg[i] : 0;
    __shared__ int sh[256];
    sh[threadIdx.x] = v;
    __syncthreads();
    int acc = v;
    for (int off = 1; off < 256; off <<= 1) {
        int u = (threadIdx.x >= off) ? sh[threadIdx.x - off] : 0;
        __syncthreads();
        acc += u;
        sh[threadIdx.x] = acc;
        __syncthreads();
    }
    if (i < N_NODES) tmp[i] = acc - v;     // exclusive within block
    if (threadIdx.x == 255) blksum[blockIdx.x] = acc;
}

__global__ void scan2(const int* __restrict__ blksum, int* __restrict__ blkoff) {
    int t = threadIdx.x;                   // 128 threads >= NBLK
    int v = (t < NBLK) ? blksum[t] : 0;
    __shared__ int sh[128];
    sh[t] = v;
    __syncthreads();
    int acc = v;
    for (int off = 1; off < 128; off <<= 1) {
        int u = (t >= off) ? sh[t - off] : 0;
        __syncthreads();
        acc += u;
        sh[t] = acc;
        __syncthreads();
    }
    if (t < NBLK) blkoff[t] = acc - v;     // exclusive block offset
}

__global__ __launch_bounds__(256) void scan3(const int* __restrict__ tmp,
                                             const int* __restrict__ blkoff,
                                             int* __restrict__ rowptr,
                                             int* __restrict__ wofs) {
    int i = blockIdx.x * 256 + threadIdx.x;
    if (i == 0) rowptr[N_NODES] = ETOT;    // total is a compile-time constant
    if (i < N_NODES) {
        int r = tmp[i] + blkoff[blockIdx.x];
        rowptr[i] = r;
        wofs[i]   = r;
    }
}

__global__ __launch_bounds__(256) void scatter_kernel(const int* __restrict__ ei0,
                                                      const int* __restrict__ ei1,
                                                      int* __restrict__ wofs,
                                                      int* __restrict__ csr_src) {
    int e = blockIdx.x * 256 + threadIdx.x;
    if (e >= ETOT) return;
    int s = (e < N_EDGES) ? ei0[e] : (e - N_EDGES);
    int d = (e < N_EDGES) ? ei1[e] : (e - N_EDGES);
    int pos = atomicAdd(&wofs[d], 1);
    csr_src[pos] = s;
}

// ---------------- fused gather: single pass, 2-deep software pipeline ----------------
__global__ __launch_bounds__(256) void gat_gather(const int* __restrict__ rowptr,
                                                  const int* __restrict__ csr_src,
                                                  const float* __restrict__ al_s,
                                                  const float* __restrict__ al_d,
                                                  const unsigned short* __restrict__ hfullb,
                                                  const float* __restrict__ conv_b,
                                                  float* __restrict__ g,
                                                  float* __restrict__ bnsum,
                                                  float* __restrict__ bnsum2) {
    const int lane = threadIdx.x & 63;
    const int wib  = threadIdx.x >> 6;
    const int gwid = blockIdx.x * 4 + wib;
    const int nw   = gridDim.x * 4;
    const int h    = lane >> 4;
    const int sub  = lane & 15;
    float s1[8] = {}, s2[8] = {};

    for (int n = gwid; n < N_NODES; n += nw) {
        const int e0 = rowptr[n], e1 = rowptr[n + 1];
        const float ald_h = al_d[n * 4 + h];

        float acc[8] = {};
        float zs = 0.f;
        int i = e0;

        if (e1 - e0 >= 8) {
            // prologue: load group 0 (indices -> gathers + logits in flight)
            int iA = csr_src[i], iB = csr_src[i + 1], iC = csr_src[i + 2], iD = csr_src[i + 3];
            bf16x8 g0a = *(const bf16x8*)(hfullb + (size_t)iA * 512 + lane * 8);
            bf16x8 g0b = *(const bf16x8*)(hfullb + (size_t)iB * 512 + lane * 8);
            bf16x8 g0c = *(const bf16x8*)(hfullb + (size_t)iC * 512 + lane * 8);
            bf16x8 g0d = *(const bf16x8*)(hfullb + (size_t)iD * 512 + lane * 8);
            float v0a = al_s[iA * 4 + h], v0b = al_s[iB * 4 + h];
            float v0c = al_s[iC * 4 + h], v0d = al_s[iD * 4 + h];
            i += 4;
            for (; i + 3 < e1; i += 4) {
                // issue group k+1 loads BEFORE consuming group k
                int jA = csr_src[i], jB = csr_src[i + 1], jC = csr_src[i + 2], jD = csr_src[i + 3];
                bf16x8 g1a = *(const bf16x8*)(hfullb + (size_t)jA * 512 + lane * 8);
                bf16x8 g1b = *(const bf16x8*)(hfullb + (size_t)jB * 512 + lane * 8);
                bf16x8 g1c = *(const bf16x8*)(hfullb + (size_t)jC * 512 + lane * 8);
                bf16x8 g1d = *(const bf16x8*)(hfullb + (size_t)jD * 512 + lane * 8);
                float v1a = al_s[jA * 4 + h], v1b = al_s[jB * 4 + h];
                float v1c = al_s[jC * 4 + h], v1d = al_s[jD * 4 + h];
                // consume group k
                float eA = v0a + ald_h; eA = (eA > 0.f) ? eA : 0.2f * eA; eA = __expf(eA);
                float eB = v0b + ald_h; eB = (eB > 0.f) ? eB : 0.2f * eB; eB = __expf(eB);
                float eC = v0c + ald_h; eC = (eC > 0.f) ? eC : 0.2f * eC; eC = __expf(eC);
                float eD = v0d + ald_h; eD = (eD > 0.f) ? eD : 0.2f * eD; eD = __expf(eD);
                zs += (eA + eB) + (eC + eD);
#pragma unroll
                for (int j = 0; j < 8; j++) {
                    float a = fmaf(eA, bf2f((unsigned short)g0a[j]), acc[j]);
                    a = fmaf(eB, bf2f((unsigned short)g0b[j]), a);
                    a = fmaf(eC, bf2f((unsigned short)g0c[j]), a);
                    acc[j] = fmaf(eD, bf2f((unsigned short)g0d[j]), a);
                }
                g0a = g1a; g0b = g1b; g0c = g1c; g0d = g1d;
                v0a = v1a; v0b = v1b; v0c = v1c; v0d = v1d;
            }
            // drain last pipelined group
            {
                float eA = v0a + ald_h; eA = (eA > 0.f) ? eA : 0.2f * eA; eA = __expf(eA);
                float eB = v0b + ald_h; eB = (eB > 0.f) ? eB : 0.2f * eB; eB = __expf(eB);
                float eC = v0c + ald_h; eC = (eC > 0.f) ? eC : 0.2f * eC; eC = __expf(eC);
                float eD = v0d + ald_h; eD = (eD > 0.f) ? eD : 0.2f * eD; eD = __expf(eD);
                zs += (eA + eB) + (eC + eD);
#pragma unroll
                for (int j = 0; j < 8; j++) {
                    float a = fmaf(eA, bf2f((unsigned short)g0a[j]), acc[j]);
                    a = fmaf(eB, bf2f((unsigned short)g0b[j]), a);
                    a = fmaf(eC, bf2f((unsigned short)g0c[j]), a);
                    acc[j] = fmaf(eD, bf2f((unsigned short)g0d[j]), a);
                }
            }
        } else {
            // small-degree path: 4-edge unroll
            for (; i + 3 < e1; i += 4) {
                int sA = csr_src[i], sB = csr_src[i + 1], sC = csr_src[i + 2], sD = csr_src[i + 3];
                bf16x8 ha = *(const bf16x8*)(hfullb + (size_t)sA * 512 + lane * 8);
                bf16x8 hb = *(const bf16x8*)(hfullb + (size_t)sB * 512 + lane * 8);
                bf16x8 hc = *(const bf16x8*)(hfullb + (size_t)sC * 512 + lane * 8);
                bf16x8 hd = *(const bf16x8*)(hfullb + (size_t)sD * 512 + lane * 8);
                float vA = al_s[sA * 4 + h] + ald_h; vA = (vA > 0.f) ? vA : 0.2f * vA;
                float vB = al_s[sB * 4 + h] + ald_h; vB = (vB > 0.f) ? vB : 0.2f * vB;
                float vC = al_s[sC * 4 + h] + ald_h; vC = (vC > 0.f) ? vC : 0.2f * vC;
                float vD = al_s[sD * 4 + h] + ald_h; vD = (vD > 0.f) ? vD : 0.2f * vD;
                float exA = __expf(vA), exB = __expf(vB), exC = __expf(vC), exD = __expf(vD);
                zs += (exA + exB) + (exC + exD);
#pragma unroll
                for (int j = 0; j < 8; j++) {
                    float a = fmaf(exA, bf2f((unsigned short)ha[j]), acc[j]);
                    a = fmaf(exB, bf2f((unsigned short)hb[j]), a);
                    a = fmaf(exC, bf2f((unsigned short)hc[j]), a);
                    acc[j] = fmaf(exD, bf2f((unsigned short)hd[j]), a);
                }
            }
        }
        // remainder (<4 edges)
        for (; i < e1; i++) {
            int sA = csr_src[i];
            bf16x8 ha = *(const bf16x8*)(hfullb + (size_t)sA * 512 + lane * 8);
            float vA = al_s[sA * 4 + h] + ald_h; vA = (vA > 0.f) ? vA : 0.2f * vA;
            float exA = __expf(vA);
            zs += exA;
#pragma unroll
            for (int j = 0; j < 8; j++)
                acc[j] = fmaf(exA, bf2f((unsigned short)ha[j]), acc[j]);
        }

        float inv = 0.25f / (zs + 1e-16f);
#pragma unroll
        for (int j = 0; j < 8; j++) {
            float a = acc[j] * inv;
            a += __shfl_xor(a, 16);
            a += __shfl_xor(a, 32);
            acc[j] = a;
        }
        if (lane < 16) {
            float o[8];
#pragma unroll
            for (int j = 0; j < 8; j++) {
                float tv = acc[j] + conv_b[sub * 8 + j];
                o[j] = tv;
                s1[j] += tv;
                s2[j] = fmaf(tv, tv, s2[j]);
            }
            float* gp = g + (size_t)n * 128 + sub * 8;
            *(float4*)gp       = make_float4(o[0], o[1], o[2], o[3]);
            *(float4*)(gp + 4) = make_float4(o[4], o[5], o[6], o[7]);
        }
    }

    __shared__ float redA[4][128], redB[4][128];
    if (lane < 16) {
#pragma unroll
        for (int j = 0; j < 8; j++) {
            redA[wib][sub * 8 + j] = s1[j];
            redB[wib][sub * 8 + j] = s2[j];
        }
    }
    __syncthreads();
    int t = threadIdx.x;
    if (t < 128) {
        atomicAdd(&bnsum[t], redA[0][t] + redA[1][t] + redA[2][t] + redA[3][t]);
    } else {
        int c = t - 128;
        atomicAdd(&bnsum2[c], redB[0][c] + redB[1][c] + redB[2][c] + redB[3][c]);
    }
}

// ---------------- pooling + MLP head fused; sorted batch -> segment sums ----------------
__global__ void bounds_kernel(const int* __restrict__ batch, int* __restrict__ gstart) {
    int t = threadIdx.x;
    if (t > NGRAPH) return;
    int lo = 0, hi = N_NODES;
    while (lo < hi) { int mid = (lo + hi) >> 1; if (batch[mid] < t) lo = mid + 1; else hi = mid; }
    gstart[t] = lo;
}

__global__ __launch_bounds__(256) void pool_head(const short* __restrict__ hh,
                                                 const short* __restrict__ hl,
                                                 const int* __restrict__ gstart,
                                                 const float* __restrict__ fc1W,
                                                 const float* __restrict__ fc1b,
                                                 const float* __restrict__ fc3W,
                                                 const float* __restrict__ fc3b,
                                                 float* __restrict__ out) {
    int gid = blockIdx.x, t = threadIdx.x;
    int lo = gstart[gid], hi = gstart[gid + 1];
    int c = t & 127, half = t >> 7;
    float s = 0.f;
    for (int n = lo + half; n < hi; n += 2) {
        size_t idx = (size_t)n * 128 + c;
        s += bf2f((unsigned short)hh[idx]) + bf2f((unsigned short)hl[idx]);
    }
    __shared__ float sh[256];
    __shared__ float hg[128], a1[128];
    sh[t] = s;
    __syncthreads();
    if (half == 0) {
        float cc = fmaxf((float)(hi - lo), 1.f);
        hg[c] = (sh[c] + sh[c + 128]) / cc;
    }
    __syncthreads();
    if (t < 128) {
        float v = fc1b[t];
        for (int c2 = 0; c2 < 128; c2++) v = fmaf(hg[c2], fc1W[c2 * 128 + t], v);
        a1[t] = fmaxf(v, 0.f);
    }
    __syncthreads();
    if (t < 16) {
        float o = fc3b[t];
        for (int j = 0; j < 128; j++) o = fmaf(a1[j], fc3W[j * 16 + t], o);
        out[gid * 16 + t] = o;
    }
}

extern "C" void kernel_launch(void* const* d_in, const int* in_sizes, int n_in,
                              void* d_out, int out_size, void* d_ws, size_t ws_size,
                              hipStream_t stream) {
    const float* x       = (const float*)d_in[0];
    const int*   ei      = (const int*)d_in[1];
    const int*   batch   = (const int*)d_in[2];
    const float* W       = (const float*)d_in[3];
    const float* att_src = (const float*)d_in[4];
    const float* att_dst = (const float*)d_in[5];
    const float* conv_b  = (const float*)d_in[6];
    const float* gamma   = (const float*)d_in[7];
    const float* beta    = (const float*)d_in[8];
    const float* sk_Win  = (const float*)d_in[9];
    const float* sk_bin  = (const float*)d_in[10];
    const float* sk_Wout = (const float*)d_in[11];
    const float* sk_bout = (const float*)d_in[12];
    const float* fc1_W   = (const float*)d_in[13];
    const float* fc1_b   = (const float*)d_in[14];
    const float* fc3_W   = (const float*)d_in[15];
    const float* fc3_b   = (const float*)d_in[16];
    float* out = (float*)d_out;
    const int* ei0 = ei;
    const int* ei1 = ei + N_EDGES;

    float* ws = (float*)d_ws;
    size_t o = 0;
    unsigned short* hfullb = (unsigned short*)(ws + o); o += (size_t)N_NODES * 256;  // bf16 [N,512]
    float* gbuf   = ws + o; o += (size_t)N_NODES * 128;
    short* spAh   = (short*)(ws + o); o += (size_t)N_NODES * 64;   // bf16 [N,128] ping
    short* spAl   = (short*)(ws + o); o += (size_t)N_NODES * 64;
    short* spBh   = (short*)(ws + o); o += (size_t)N_NODES * 64;   // pong
    short* spBl   = (short*)(ws + o); o += (size_t)N_NODES * 64;
    float* als    = ws + o; o += N_NODES * 4;
    float* ald    = ws + o; o += N_NODES * 4;
    float* bnsum  = ws + o; o += 768;      // 3 layers x (128 sum + 128 sumsq)
    short* wt_hi   = (short*)(ws + o); o += 98304;   // 3*512*128 shorts
    short* wt_lo   = (short*)(ws + o); o += 98304;
    short* wint_hi = (short*)(ws + o); o += 24576;   // 3*128*128 shorts
    short* wint_lo = (short*)(ws + o); o += 24576;
    short* woutt_hi = (short*)(ws + o); o += 24576;
    short* woutt_lo = (short*)(ws + o); o += 24576;
    int* gstart   = (int*)(ws + o); o += 132;
    int* deg      = (int*)(ws + o); o += N_NODES;
    int* rowptr   = (int*)(ws + o); o += N_NODES + 4;
    int* wofs     = (int*)(ws + o); o += N_NODES;
    int* scantmp  = (int*)(ws + o); o += N_NODES;
    int* blksum   = (int*)(ws + o); o += NBLK + 2;
    int* blkoff   = (int*)(ws + o); o += NBLK + 2;
    int* csr_src  = (int*)(ws + o); o += ETOT;

    conv_weights<<<1152, 256, 0, stream>>>(W, sk_Win, sk_Wout,
                                           wt_hi, wt_lo, wint_hi, wint_lo, woutt_hi, woutt_lo);

    hipMemsetAsync(deg, 0, N_NODES * 4, stream);
    hipMemsetAsync(bnsum, 0, 768 * 4, stream);
    deg_kernel<<<(ETOT + 255) / 256, 256, 0, stream>>>(ei1, deg);
    scan1<<<NBLK, 256, 0, stream>>>(deg, scantmp, blksum);
    scan2<<<1, 128, 0, stream>>>(blksum, blkoff);
    scan3<<<NBLK, 256, 0, stream>>>(scantmp, blkoff, rowptr, wofs);
    scatter_kernel<<<(ETOT + 255) / 256, 256, 0, stream>>>(ei0, ei1, wofs, csr_src);
    bounds_kernel<<<1, 256, 0, stream>>>(batch, gstart);
    split_act<<<1875, 256, 0, stream>>>(x, spAh, spAl);

    short* sih = spAh; short* sil = spAl;
    short* soh = spBh; short* sol = spBl;
    for (int l = 0; l < 3; l++) {
        gemm_conv<<<dim3(469, 4), 256, 0, stream>>>(sih, sil,
                                                    wt_hi + (size_t)l * 65536, wt_lo + (size_t)l * 65536,
                                                    att_src + l * 512, att_dst + l * 512,
                                                    hfullb, als, ald);
        gat_gather<<<1024, 256, 0, stream>>>(rowptr, csr_src, als, ald, hfullb,
                                             conv_b + l * 128, gbuf,
                                             bnsum + l * 256, bnsum + l * 256 + 128);
        skip_gate<<<dim3(469, 2), 256, 0, stream>>>(sih, sil, gbuf,
                                                    bnsum + l * 256, gamma + l * 128, beta + l * 128,
                                                    wint_hi + (size_t)l * 16384, wint_lo + (size_t)l * 16384,
                                                    woutt_hi + (size_t)l * 16384, woutt_lo + (size_t)l * 16384,
                                                    sk_bin + l * 128, sk_bout + l * 128,
                                                    soh, sol);
        short* th = sih; short* tl = sil;
        sih = soh; sil = sol;
        soh = th; sol = tl;
    }

    pool_head<<<NGRAPH, 256, 0, stream>>>(sih, sil, gstart, fc1_W, fc1_b, fc3_W, fc3_b, out);
}

// Round 10
// 455.104 us; speedup vs baseline: 1.4199x; 1.0963x over previous
//
#include <hip/hip_runtime.h>
#include <hip/hip_bf16.h>

#define N_NODES 30000
#define N_EDGES 240000
#define ETOT    (N_EDGES + N_NODES)   // 270000 (self loops appended)
#define NGRAPH  128
#define NBLK    118                   // ceil(30000/256)

typedef __attribute__((ext_vector_type(8))) short bf16x8;
typedef __attribute__((ext_vector_type(4))) short bf16x4;
typedef __attribute__((ext_vector_type(4))) float f32x4;

__device__ __forceinline__ unsigned short f2bf(float f) {
    unsigned u = __float_as_uint(f);
    u += 0x7fff + ((u >> 16) & 1);        // round-to-nearest-even
    return (unsigned short)(u >> 16);
}
__device__ __forceinline__ float bf2f(unsigned short h) {
    return __uint_as_float(((unsigned)h) << 16);
}

// ---------- weight transpose + bf16 round (hi only; once per call) ----------
__global__ __launch_bounds__(256) void conv_weights(const float* __restrict__ W,
                                                    const float* __restrict__ Win,
                                                    const float* __restrict__ Wout,
                                                    short* __restrict__ wt_hi,
                                                    short* __restrict__ wint_hi,
                                                    short* __restrict__ woutt_hi) {
    int i = blockIdx.x * 256 + threadIdx.x;
    float v; short* dh; int di;
    if (i < 196608) {                       // 3*512*128
        int l = i >> 16, r = i & 65535;
        int n = r >> 7, k = r & 127;
        v = W[(size_t)l * 65536 + k * 512 + n];
        dh = wt_hi; di = i;
    } else if (i < 245760) {                // + 3*128*128
        int j = i - 196608;
        int l = j >> 14, r = j & 16383;
        int n = r >> 7, k = r & 127;
        v = Win[(size_t)l * 16384 + k * 128 + n];
        dh = wint_hi; di = j;
    } else if (i < 294912) {
        int j = i - 245760;
        int l = j >> 14, r = j & 16383;
        int n = r >> 7, k = r & 127;
        v = Wout[(size_t)l * 16384 + k * 128 + n];
        dh = woutt_hi; di = j;
    } else return;
    dh[di] = (short)f2bf(v);
}

// ---------- activation split: fp32 [N,128] -> bf16 hi/lo (only for x, once) ----------
__global__ __launch_bounds__(256) void split_act(const float* __restrict__ A,
                                                 short* __restrict__ Ah,
                                                 short* __restrict__ Al) {
    int i = blockIdx.x * 256 + threadIdx.x;       // covers 8 floats each
    if (i >= N_NODES * 16) return;
    const float4* p = (const float4*)A + (size_t)i * 2;
    float4 v0 = p[0], v1 = p[1];
    float f[8] = {v0.x, v0.y, v0.z, v0.w, v1.x, v1.y, v1.z, v1.w};
    bf16x8 h, l;
#pragma unroll
    for (int j = 0; j < 8; j++) {
        unsigned short hh = f2bf(f[j]);
        h[j] = (short)hh;
        l[j] = (short)f2bf(f[j] - bf2f(hh));
    }
    *(bf16x8*)(Ah + (size_t)i * 8) = h;
    *(bf16x8*)(Al + (size_t)i * 8) = l;
}

// ---------- conv GEMM (exact-A x bf16-B, 2 products) + logits + coalesced store ----
// block: 64 rows x 128 cols (one head)
__global__ __launch_bounds__(256) void gemm_conv(const short* __restrict__ Ah,
                                                 const short* __restrict__ Al,
                                                 const short* __restrict__ Bth,
                                                 const float* __restrict__ att_s,
                                                 const float* __restrict__ att_d,
                                                 unsigned short* __restrict__ hfullb,
                                                 float* __restrict__ als,
                                                 float* __restrict__ ald) {
    __shared__ short As_h[64 * 136];
    __shared__ short As_l[64 * 136];
    __shared__ float red_s[2][64], red_d[2][64];
    const int bm = blockIdx.x * 64;
    const int hd = blockIdx.y;            // head = column block
    const int bn = hd * 128;
    const int t  = threadIdx.x;
#pragma unroll
    for (int i = 0; i < 4; i++) {
        int idx8 = t + i * 256;              // 1024 ushort8 slots
        int row = idx8 >> 4, c8 = (idx8 & 15) << 3;
        bf16x8 vh = {}, vl = {};
        if (bm + row < N_NODES) {
            vh = *(const bf16x8*)(Ah + (size_t)(bm + row) * 128 + c8);
            vl = *(const bf16x8*)(Al + (size_t)(bm + row) * 128 + c8);
        }
        *(bf16x8*)(As_h + row * 136 + c8) = vh;
        *(bf16x8*)(As_l + row * 136 + c8) = vl;
    }
    __syncthreads();

    const int w = t >> 6, lane = t & 63;
    const int wr = w >> 1, wc = w & 1;
    const int lr = lane & 15, lg = lane >> 4;
    f32x4 acc[2][4] = {};
    const size_t bofs0 = (size_t)(bn + wc * 64 + lr) * 128 + lg * 8;
#pragma unroll
    for (int kk = 0; kk < 4; kk++) {
        bf16x8 ah[2], al[2], bh[4];
#pragma unroll
        for (int ni = 0; ni < 4; ni++) {
            size_t o = bofs0 + (size_t)ni * 16 * 128 + kk * 32;
            bh[ni] = *(const bf16x8*)(Bth + o);
        }
        int ko = kk * 32 + lg * 8;
#pragma unroll
        for (int mi = 0; mi < 2; mi++) {
            int r = wr * 32 + mi * 16 + lr;
            ah[mi] = *(const bf16x8*)(As_h + r * 136 + ko);
            al[mi] = *(const bf16x8*)(As_l + r * 136 + ko);
        }
#pragma unroll
        for (int mi = 0; mi < 2; mi++)
#pragma unroll
            for (int ni = 0; ni < 4; ni++) {
                acc[mi][ni] = __builtin_amdgcn_mfma_f32_16x16x32_bf16(ah[mi], bh[ni], acc[mi][ni], 0, 0, 0);
                acc[mi][ni] = __builtin_amdgcn_mfma_f32_16x16x32_bf16(al[mi], bh[ni], acc[mi][ni], 0, 0, 0);
            }
    }
    // fused attention logits: als[m,hd] = sum_c h[m,c]*att_s[hd,c]  (fp32-exact)
    float as_c[4], ad_c[4];
#pragma unroll
    for (int ni = 0; ni < 4; ni++) {
        int cc = wc * 64 + ni * 16 + lr;
        as_c[ni] = att_s[hd * 128 + cc];
        ad_c[ni] = att_d[hd * 128 + cc];
    }
#pragma unroll
    for (int mi = 0; mi < 2; mi++) {
#pragma unroll
        for (int r = 0; r < 4; r++) {
            float ps = 0.f, pd = 0.f;
#pragma unroll
            for (int ni = 0; ni < 4; ni++) {
                ps = fmaf(acc[mi][ni][r], as_c[ni], ps);
                pd = fmaf(acc[mi][ni][r], ad_c[ni], pd);
            }
#pragma unroll
            for (int off = 1; off < 16; off <<= 1) {
                ps += __shfl_xor(ps, off);
                pd += __shfl_xor(pd, off);
            }
            if (lr == 0) {
                int row = wr * 32 + mi * 16 + lg * 4 + r;
                red_s[wc][row] = ps;
                red_d[wc][row] = pd;
            }
        }
    }
    __syncthreads();            // red complete; As tiles dead -> reuse as C staging
    // stage C tile (bf16) into As_h for coalesced store
#pragma unroll
    for (int mi = 0; mi < 2; mi++)
#pragma unroll
        for (int ni = 0; ni < 4; ni++) {
            int nl = wc * 64 + ni * 16 + lr;
#pragma unroll
            for (int r = 0; r < 4; r++) {
                int row = wr * 32 + mi * 16 + lg * 4 + r;
                As_h[row * 136 + nl] = (short)f2bf(acc[mi][ni][r]);
            }
        }
    if (t < 64) {
        int m = bm + t;
        if (m < N_NODES) als[m * 4 + hd] = red_s[0][t] + red_s[1][t];
    } else if (t < 128) {
        int tt = t - 64;
        int m = bm + tt;
        if (m < N_NODES) ald[m * 4 + hd] = red_d[0][tt] + red_d[1][tt];
    }
    __syncthreads();
    // coalesced bf16x8 store of the 64x128 tile
#pragma unroll
    for (int i2 = 0; i2 < 4; i2++) {
        int idx8 = t + i2 * 256;            // 1024 slots
        int row = idx8 >> 4, c8 = (idx8 & 15) << 3;
        int m = bm + row;
        if (m < N_NODES)
            *(bf16x8*)(hfullb + (size_t)m * 512 + bn + c8) = *(const bf16x8*)(As_h + row * 136 + c8);
    }
}

// ---------- fused skip: P = hin@Win + bn(g)@Wout (bf16 x bf16, 1 product each) ----
__global__ __launch_bounds__(256) void skip_gate(const short* __restrict__ hinh,
                                                 const short* __restrict__ hinl,
                                                 const float* __restrict__ g,
                                                 const float* __restrict__ bnsum,   // [0:128)=sum,[128:256)=sumsq
                                                 const float* __restrict__ gamma,
                                                 const float* __restrict__ beta,
                                                 const short* __restrict__ w1h,
                                                 const short* __restrict__ w2h,
                                                 const float* __restrict__ bin, const float* __restrict__ bout,
                                                 short* __restrict__ houth,
                                                 short* __restrict__ houtl) {
    __shared__ short A1h[64 * 136], A1l[64 * 136], A2h[64 * 136], A2l[64 * 136];
    __shared__ float bnp_s[256];
    const int bm = blockIdx.x * 64;
    const int bn = blockIdx.y * 64;
    const int t  = threadIdx.x;
    if (t < 128) {
        float inv = 1.f / (float)N_NODES;
        float mu  = bnsum[t] * inv;
        float var = bnsum[128 + t] * inv - mu * mu;
        float rs  = rsqrtf(var + 1e-5f);
        float sc  = gamma[t] * rs;
        bnp_s[t]       = sc;
        bnp_s[128 + t] = beta[t] - mu * sc;
    }
    __syncthreads();
    // A1: copy pre-split hin tiles
#pragma unroll
    for (int i = 0; i < 4; i++) {
        int idx8 = t + i * 256;
        int row = idx8 >> 4, c8 = (idx8 & 15) << 3;
        bf16x8 vh = {}, vl = {};
        if (bm + row < N_NODES) {
            vh = *(const bf16x8*)(hinh + (size_t)(bm + row) * 128 + c8);
            vl = *(const bf16x8*)(hinl + (size_t)(bm + row) * 128 + c8);
        }
        *(bf16x8*)(A1h + row * 136 + c8) = vh;
        *(bf16x8*)(A1l + row * 136 + c8) = vl;
    }
    // A2: bn(g) + split
#pragma unroll
    for (int i = 0; i < 8; i++) {
        int idx4 = t + i * 256;
        int row = idx4 >> 5, c4 = (idx4 & 31) << 2;
        float4 v2 = make_float4(0.f, 0.f, 0.f, 0.f);
        if (bm + row < N_NODES) {
            float4 gv = *(const float4*)(g + (size_t)(bm + row) * 128 + c4);
            v2.x = fmaf(bnp_s[c4 + 0], gv.x, bnp_s[128 + c4 + 0]);
            v2.y = fmaf(bnp_s[c4 + 1], gv.y, bnp_s[128 + c4 + 1]);
            v2.z = fmaf(bnp_s[c4 + 2], gv.z, bnp_s[128 + c4 + 2]);
            v2.w = fmaf(bnp_s[c4 + 3], gv.w, bnp_s[128 + c4 + 3]);
        }
        unsigned short b0 = f2bf(v2.x), b1 = f2bf(v2.y), b2 = f2bf(v2.z), b3 = f2bf(v2.w);
        *(bf16x4*)(A2h + row * 136 + c4) = (bf16x4){(short)b0, (short)b1, (short)b2, (short)b3};
        *(bf16x4*)(A2l + row * 136 + c4) = (bf16x4){(short)f2bf(v2.x - bf2f(b0)), (short)f2bf(v2.y - bf2f(b1)),
                                                    (short)f2bf(v2.z - bf2f(b2)), (short)f2bf(v2.w - bf2f(b3))};
    }
    __syncthreads();

    const int w = t >> 6, lane = t & 63;
    const int wr = w >> 1, wc = w & 1;
    const int lr = lane & 15, lg = lane >> 4;
    f32x4 acc[2][2] = {};
    const size_t bofs0 = (size_t)(bn + wc * 32 + lr) * 128 + lg * 8;
#pragma unroll
    for (int kk = 0; kk < 4; kk++) {
        bf16x8 a1f[2], a2f[2], b1h[2], b2h[2];
#pragma unroll
        for (int ni = 0; ni < 2; ni++) {
            size_t o = bofs0 + (size_t)ni * 16 * 128 + kk * 32;
            b1h[ni] = *(const bf16x8*)(w1h + o);
            b2h[ni] = *(const bf16x8*)(w2h + o);
        }
        int ko = kk * 32 + lg * 8;
#pragma unroll
        for (int mi = 0; mi < 2; mi++) {
            int r = wr * 32 + mi * 16 + lr;
            a1f[mi] = *(const bf16x8*)(A1h + r * 136 + ko);
            a2f[mi] = *(const bf16x8*)(A2h + r * 136 + ko);
        }
#pragma unroll
        for (int mi = 0; mi < 2; mi++)
#pragma unroll
            for (int ni = 0; ni < 2; ni++) {
                acc[mi][ni] = __builtin_amdgcn_mfma_f32_16x16x32_bf16(a1f[mi], b1h[ni], acc[mi][ni], 0, 0, 0);
                acc[mi][ni] = __builtin_amdgcn_mfma_f32_16x16x32_bf16(a2f[mi], b2h[ni], acc[mi][ni], 0, 0, 0);
            }
    }
    // gate+relu into acc (reads A-tiles for skip reconstruct)
#pragma unroll
    for (int mi = 0; mi < 2; mi++) {
#pragma unroll
        for (int ni = 0; ni < 2; ni++) {
            int n = bn + wc * 32 + ni * 16 + lr;
            float bsum = bin[n] + bout[n];
#pragma unroll
            for (int r = 0; r < 4; r++) {
                int lrow = wr * 32 + mi * 16 + lg * 4 + r;
                float hbnv = bf2f((unsigned short)A2h[lrow * 136 + n]) + bf2f((unsigned short)A2l[lrow * 136 + n]);
                float hv   = bf2f((unsigned short)A1h[lrow * 136 + n]) + bf2f((unsigned short)A1l[lrow * 136 + n]);
                float gt   = 1.f / (1.f + __expf(-(acc[mi][ni][r] + bsum)));
                acc[mi][ni][r] = fmaxf(gt * hbnv + (1.f - gt) * hv, 0.f);
            }
        }
    }
    __syncthreads();            // A-tiles dead -> reuse as output staging
#pragma unroll
    for (int mi = 0; mi < 2; mi++)
#pragma unroll
        for (int ni = 0; ni < 2; ni++) {
            int n = bn + wc * 32 + ni * 16 + lr;
#pragma unroll
            for (int r = 0; r < 4; r++) {
                int lrow = wr * 32 + mi * 16 + lg * 4 + r;
                float ov = acc[mi][ni][r];
                unsigned short oh = f2bf(ov);
                A1h[lrow * 136 + n] = (short)oh;
                A1l[lrow * 136 + n] = (short)f2bf(ov - bf2f(oh));
            }
        }
    __syncthreads();
    // coalesced store of 64-row x 64-col window
#pragma unroll
    for (int i2 = 0; i2 < 2; i2++) {
        int idx8 = t + i2 * 256;            // 512 slots = 64 rows x 8
        int row = idx8 >> 3, c8 = (idx8 & 7) << 3;
        int m = bm + row;
        if (m < N_NODES) {
            *(bf16x8*)(houth + (size_t)m * 128 + bn + c8) = *(const bf16x8*)(A1h + row * 136 + bn + c8);
            *(bf16x8*)(houtl + (size_t)m * 128 + bn + c8) = *(const bf16x8*)(A1l + row * 136 + bn + c8);
        }
    }
}

// ---------------- CSR build ----------------
__global__ __launch_bounds__(256) void deg_kernel(const int* __restrict__ ei1,
                                                  int* __restrict__ deg) {
    int e = blockIdx.x * 256 + threadIdx.x;
    if (e >= ETOT) return;
    int d = (e < N_EDGES) ? ei1[e] : (e - N_EDGES);
    atomicAdd(&deg[d], 1);
}

// hierarchical scan: scan1 (per-block) -> scan2 (block sums) -> scan3 (combine)
__global__ __launch_bounds__(256) void scan1(const int* __restrict__ deg,
                                             int* __restrict__ tmp,
                                             int* __restrict__ blksum) {
    int i = blockIdx.x * 256 + threadIdx.x;
    int v = (i < N_NODES) ? deg[i] : 0;
    __shared__ int sh[256];
    sh[threadIdx.x] = v;
    __syncthreads();
    int acc = v;
    for (int off = 1; off < 256; off <<= 1) {
        int u = (threadIdx.x >= off) ? sh[threadIdx.x - off] : 0;
        __syncthreads();
        acc += u;
        sh[threadIdx.x] = acc;
        __syncthreads();
    }
    if (i < N_NODES) tmp[i] = acc - v;     // exclusive within block
    if (threadIdx.x == 255) blksum[blockIdx.x] = acc;
}

__global__ void scan2(const int* __restrict__ blksum, int* __restrict__ blkoff) {
    int t = threadIdx.x;                   // 128 threads >= NBLK
    int v = (t < NBLK) ? blksum[t] : 0;
    __shared__ int sh[128];
    sh[t] = v;
    __syncthreads();
    int acc = v;
    for (int off = 1; off < 128; off <<= 1) {
        int u = (t >= off) ? sh[t - off] : 0;
        __syncthreads();
        acc += u;
        sh[t] = acc;
        __syncthreads();
    }
    if (t < NBLK) blkoff[t] = acc - v;     // exclusive block offset
}

__global__ __launch_bounds__(256) void scan3(const int* __restrict__ tmp,
                                             const int* __restrict__ blkoff,
                                             int* __restrict__ rowptr,
                                             int* __restrict__ wofs) {
    int i = blockIdx.x * 256 + threadIdx.x;
    if (i == 0) rowptr[N_NODES] = ETOT;    // total is a compile-time constant
    if (i < N_NODES) {
        int r = tmp[i] + blkoff[blockIdx.x];
        rowptr[i] = r;
        wofs[i]   = r;
    }
}

__global__ __launch_bounds__(256) void scatter_kernel(const int* __restrict__ ei0,
                                                      const int* __restrict__ ei1,
                                                      int* __restrict__ wofs,
                                                      int* __restrict__ csr_src) {
    int e = blockIdx.x * 256 + threadIdx.x;
    if (e >= ETOT) return;
    int s = (e < N_EDGES) ? ei0[e] : (e - N_EDGES);
    int d = (e < N_EDGES) ? ei1[e] : (e - N_EDGES);
    int pos = atomicAdd(&wofs[d], 1);
    csr_src[pos] = s;
}

// ---------------- fused gather: single pass, 4-edge load-clustered ----------------
__global__ __launch_bounds__(256) void gat_gather(const int* __restrict__ rowptr,
                                                  const int* __restrict__ csr_src,
                                                  const float* __restrict__ al_s,
                                                  const float* __restrict__ al_d,
                                                  const unsigned short* __restrict__ hfullb,
                                                  const float* __restrict__ conv_b,
                                                  float* __restrict__ g,
                                                  float* __restrict__ bnsum,
                                                  float* __restrict__ bnsum2) {
    const int lane = threadIdx.x & 63;
    const int wib  = threadIdx.x >> 6;
    const int gwid = blockIdx.x * 4 + wib;
    const int nw   = gridDim.x * 4;
    const int h    = lane >> 4;
    const int sub  = lane & 15;
    float s1[8] = {}, s2[8] = {};

    for (int n = gwid; n < N_NODES; n += nw) {
        const int e0 = rowptr[n], e1 = rowptr[n + 1];
        const float ald_h = al_d[n * 4 + h];

        float acc[8] = {};
        float zs = 0.f;
        int i = e0;
        for (; i + 3 < e1; i += 4) {
            int sA = csr_src[i], sB = csr_src[i + 1], sC = csr_src[i + 2], sD = csr_src[i + 3];
            bf16x8 ha = *(const bf16x8*)(hfullb + (size_t)sA * 512 + lane * 8);
            bf16x8 hb = *(const bf16x8*)(hfullb + (size_t)sB * 512 + lane * 8);
            bf16x8 hc = *(const bf16x8*)(hfullb + (size_t)sC * 512 + lane * 8);
            bf16x8 hd = *(const bf16x8*)(hfullb + (size_t)sD * 512 + lane * 8);
            float vA = al_s[sA * 4 + h] + ald_h; vA = (vA > 0.f) ? vA : 0.2f * vA;
            float vB = al_s[sB * 4 + h] + ald_h; vB = (vB > 0.f) ? vB : 0.2f * vB;
            float vC = al_s[sC * 4 + h] + ald_h; vC = (vC > 0.f) ? vC : 0.2f * vC;
            float vD = al_s[sD * 4 + h] + ald_h; vD = (vD > 0.f) ? vD : 0.2f * vD;
            float exA = __expf(vA), exB = __expf(vB), exC = __expf(vC), exD = __expf(vD);
            zs += (exA + exB) + (exC + exD);
#pragma unroll
            for (int j = 0; j < 8; j++) {
                float a = fmaf(exA, bf2f((unsigned short)ha[j]), acc[j]);
                a = fmaf(exB, bf2f((unsigned short)hb[j]), a);
                a = fmaf(exC, bf2f((unsigned short)hc[j]), a);
                acc[j] = fmaf(exD, bf2f((unsigned short)hd[j]), a);
            }
        }
        for (; i < e1; i++) {
            int sA = csr_src[i];
            bf16x8 ha = *(const bf16x8*)(hfullb + (size_t)sA * 512 + lane * 8);
            float vA = al_s[sA * 4 + h] + ald_h; vA = (vA > 0.f) ? vA : 0.2f * vA;
            float exA = __expf(vA);
            zs += exA;
#pragma unroll
            for (int j = 0; j < 8; j++)
                acc[j] = fmaf(exA, bf2f((unsigned short)ha[j]), acc[j]);
        }

        float inv = 0.25f / (zs + 1e-16f);
#pragma unroll
        for (int j = 0; j < 8; j++) {
            float a = acc[j] * inv;
            a += __shfl_xor(a, 16);
            a += __shfl_xor(a, 32);
            acc[j] = a;
        }
        if (lane < 16) {
            float o[8];
#pragma unroll
            for (int j = 0; j < 8; j++) {
                float tv = acc[j] + conv_b[sub * 8 + j];
                o[j] = tv;
                s1[j] += tv;
                s2[j] = fmaf(tv, tv, s2[j]);
            }
            float* gp = g + (size_t)n * 128 + sub * 8;
            *(float4*)gp       = make_float4(o[0], o[1], o[2], o[3]);
            *(float4*)(gp + 4) = make_float4(o[4], o[5], o[6], o[7]);
        }
    }

    __shared__ float redA[4][128], redB[4][128];
    if (lane < 16) {
#pragma unroll
        for (int j = 0; j < 8; j++) {
            redA[wib][sub * 8 + j] = s1[j];
            redB[wib][sub * 8 + j] = s2[j];
        }
    }
    __syncthreads();
    int t = threadIdx.x;
    if (t < 128) {
        atomicAdd(&bnsum[t], redA[0][t] + redA[1][t] + redA[2][t] + redA[3][t]);
    } else {
        int c = t - 128;
        atomicAdd(&bnsum2[c], redB[0][c] + redB[1][c] + redB[2][c] + redB[3][c]);
    }
}

// ---------------- pooling + MLP head fused; sorted batch -> segment sums ----------------
__global__ void bounds_kernel(const int* __restrict__ batch, int* __restrict__ gstart) {
    int t = threadIdx.x;
    if (t > NGRAPH) return;
    int lo = 0, hi = N_NODES;
    while (lo < hi) { int mid = (lo + hi) >> 1; if (batch[mid] < t) lo = mid + 1; else hi = mid; }
    gstart[t] = lo;
}

__global__ __launch_bounds__(256) void pool_head(const short* __restrict__ hh,
                                                 const short* __restrict__ hl,
                                                 const int* __restrict__ gstart,
                                                 const float* __restrict__ fc1W,
                                                 const float* __restrict__ fc1b,
                                                 const float* __restrict__ fc3W,
                                                 const float* __restrict__ fc3b,
                                                 float* __restrict__ out) {
    int gid = blockIdx.x, t = threadIdx.x;
    int lo = gstart[gid], hi = gstart[gid + 1];
    int c = t & 127, half = t >> 7;
    float s = 0.f;
    for (int n = lo + half; n < hi; n += 2) {
        size_t idx = (size_t)n * 128 + c;
        s += bf2f((unsigned short)hh[idx]) + bf2f((unsigned short)hl[idx]);
    }
    __shared__ float sh[256];
    __shared__ float hg[128], a1[128];
    sh[t] = s;
    __syncthreads();
    if (half == 0) {
        float cc = fmaxf((float)(hi - lo), 1.f);
        hg[c] = (sh[c] + sh[c + 128]) / cc;
    }
    __syncthreads();
    if (t < 128) {
        float v = fc1b[t];
        for (int c2 = 0; c2 < 128; c2++) v = fmaf(hg[c2], fc1W[c2 * 128 + t], v);
        a1[t] = fmaxf(v, 0.f);
    }
    __syncthreads();
    if (t < 16) {
        float o = fc3b[t];
        for (int j = 0; j < 128; j++) o = fmaf(a1[j], fc3W[j * 16 + t], o);
        out[gid * 16 + t] = o;
    }
}

extern "C" void kernel_launch(void* const* d_in, const int* in_sizes, int n_in,
                              void* d_out, int out_size, void* d_ws, size_t ws_size,
                              hipStream_t stream) {
    const float* x       = (const float*)d_in[0];
    const int*   ei      = (const int*)d_in[1];
    const int*   batch   = (const int*)d_in[2];
    const float* W       = (const float*)d_in[3];
    const float* att_src = (const float*)d_in[4];
    const float* att_dst = (const float*)d_in[5];
    const float* conv_b  = (const float*)d_in[6];
    const float* gamma   = (const float*)d_in[7];
    const float* beta    = (const float*)d_in[8];
    const float* sk_Win  = (const float*)d_in[9];
    const float* sk_bin  = (const float*)d_in[10];
    const float* sk_Wout = (const float*)d_in[11];
    const float* sk_bout = (const float*)d_in[12];
    const float* fc1_W   = (const float*)d_in[13];
    const float* fc1_b   = (const float*)d_in[14];
    const float* fc3_W   = (const float*)d_in[15];
    const float* fc3_b   = (const float*)d_in[16];
    float* out = (float*)d_out;
    const int* ei0 = ei;
    const int* ei1 = ei + N_EDGES;

    float* ws = (float*)d_ws;
    size_t o = 0;
    unsigned short* hfullb = (unsigned short*)(ws + o); o += (size_t)N_NODES * 256;  // bf16 [N,512]
    float* gbuf   = ws + o; o += (size_t)N_NODES * 128;
    short* spAh   = (short*)(ws + o); o += (size_t)N_NODES * 64;   // bf16 [N,128] ping
    short* spAl   = (short*)(ws + o); o += (size_t)N_NODES * 64;
    short* spBh   = (short*)(ws + o); o += (size_t)N_NODES * 64;   // pong
    short* spBl   = (short*)(ws + o); o += (size_t)N_NODES * 64;
    float* als    = ws + o; o += N_NODES * 4;
    float* ald    = ws + o; o += N_NODES * 4;
    float* bnsum  = ws + o; o += 768;      // 3 layers x (128 sum + 128 sumsq)
    short* wt_hi   = (short*)(ws + o); o += 98304;   // 3*512*128 shorts
    short* wint_hi = (short*)(ws + o); o += 24576;   // 3*128*128 shorts
    short* woutt_hi = (short*)(ws + o); o += 24576;
    int* gstart   = (int*)(ws + o); o += 132;
    int* deg      = (int*)(ws + o); o += N_NODES;
    int* rowptr   = (int*)(ws + o); o += N_NODES + 4;
    int* wofs     = (int*)(ws + o); o += N_NODES;
    int* scantmp  = (int*)(ws + o); o += N_NODES;
    int* blksum   = (int*)(ws + o); o += NBLK + 2;
    int* blkoff   = (int*)(ws + o); o += NBLK + 2;
    int* csr_src  = (int*)(ws + o); o += ETOT;

    conv_weights<<<1152, 256, 0, stream>>>(W, sk_Win, sk_Wout, wt_hi, wint_hi, woutt_hi);

    hipMemsetAsync(deg, 0, N_NODES * 4, stream);
    hipMemsetAsync(bnsum, 0, 768 * 4, stream);
    deg_kernel<<<(ETOT + 255) / 256, 256, 0, stream>>>(ei1, deg);
    scan1<<<NBLK, 256, 0, stream>>>(deg, scantmp, blksum);
    scan2<<<1, 128, 0, stream>>>(blksum, blkoff);
    scan3<<<NBLK, 256, 0, stream>>>(scantmp, blkoff, rowptr, wofs);
    scatter_kernel<<<(ETOT + 255) / 256, 256, 0, stream>>>(ei0, ei1, wofs, csr_src);
    bounds_kernel<<<1, 256, 0, stream>>>(batch, gstart);
    split_act<<<1875, 256, 0, stream>>>(x, spAh, spAl);

    short* sih = spAh; short* sil = spAl;
    short* soh = spBh; short* sol = spBl;
    for (int l = 0; l < 3; l++) {
        gemm_conv<<<dim3(469, 4), 256, 0, stream>>>(sih, sil,
                                                    wt_hi + (size_t)l * 65536,
                                                    att_src + l * 512, att_dst + l * 512,
                                                    hfullb, als, ald);
        gat_gather<<<1024, 256, 0, stream>>>(rowptr, csr_src, als, ald, hfullb,
                                             conv_b + l * 128, gbuf,
                                             bnsum + l * 256, bnsum + l * 256 + 128);
        skip_gate<<<dim3(469, 2), 256, 0, stream>>>(sih, sil, gbuf,
                                                    bnsum + l * 256, gamma + l * 128, beta + l * 128,
                                                    wint_hi + (size_t)l * 16384,
                                                    woutt_hi + (size_t)l * 16384,
                                                    sk_bin + l * 128, sk_bout + l * 128,
                                                    soh, sol);
        short* th = sih; short* tl = sil;
        sih = soh; sil = sol;
        soh = th; sol = tl;
    }

    pool_head<<<NGRAPH, 256, 0, stream>>>(sih, sil, gstart, fc1_W, fc1_b, fc3_W, fc3_b, out);
}

// Round 11
// 416.565 us; speedup vs baseline: 1.5512x; 1.0925x over previous
//
#include <hip/hip_runtime.h>
#include <hip/hip_bf16.h>

#define N_NODES 30000
#define N_EDGES 240000
#define ETOT    (N_EDGES + N_NODES)   // 270000 (self loops appended)
#define NGRAPH  128
#define NBLK    118                   // ceil(30000/256)

typedef __attribute__((ext_vector_type(8))) short bf16x8;
typedef __attribute__((ext_vector_type(4))) short bf16x4;
typedef __attribute__((ext_vector_type(4))) float f32x4;

__device__ __forceinline__ unsigned short f2bf(float f) {
    unsigned u = __float_as_uint(f);
    u += 0x7fff + ((u >> 16) & 1);        // round-to-nearest-even
    return (unsigned short)(u >> 16);
}
__device__ __forceinline__ float bf2f(unsigned short h) {
    return __uint_as_float(((unsigned)h) << 16);
}

// ---------- merged prep: weight transpose->bf16, x->bf16, graph bounds ----------
__global__ __launch_bounds__(256) void prep_kernel(const float* __restrict__ W,
                                                   const float* __restrict__ Win,
                                                   const float* __restrict__ Wout,
                                                   const float* __restrict__ x,
                                                   const int* __restrict__ batch,
                                                   short* __restrict__ wt_hi,
                                                   short* __restrict__ wint_hi,
                                                   short* __restrict__ woutt_hi,
                                                   short* __restrict__ xb,
                                                   int* __restrict__ gstart) {
    int i = blockIdx.x * 256 + threadIdx.x;
    if (i < 196608) {                       // 3*512*128
        int l = i >> 16, r = i & 65535;
        int n = r >> 7, k = r & 127;
        wt_hi[i] = (short)f2bf(W[(size_t)l * 65536 + k * 512 + n]);
    } else if (i < 245760) {                // + 3*128*128
        int j = i - 196608;
        int l = j >> 14, r = j & 16383;
        int n = r >> 7, k = r & 127;
        wint_hi[j] = (short)f2bf(Win[(size_t)l * 16384 + k * 128 + n]);
    } else if (i < 294912) {
        int j = i - 245760;
        int l = j >> 14, r = j & 16383;
        int n = r >> 7, k = r & 127;
        woutt_hi[j] = (short)f2bf(Wout[(size_t)l * 16384 + k * 128 + n]);
    } else if (i < 294912 + 480000) {       // x -> bf16, 8 floats per thread
        int j = i - 294912;
        const float4* p = (const float4*)x + (size_t)j * 2;
        float4 v0 = p[0], v1 = p[1];
        bf16x8 hv;
        hv[0] = (short)f2bf(v0.x); hv[1] = (short)f2bf(v0.y);
        hv[2] = (short)f2bf(v0.z); hv[3] = (short)f2bf(v0.w);
        hv[4] = (short)f2bf(v1.x); hv[5] = (short)f2bf(v1.y);
        hv[6] = (short)f2bf(v1.z); hv[7] = (short)f2bf(v1.w);
        *(bf16x8*)(xb + (size_t)j * 8) = hv;
    } else if (i < 294912 + 480000 + 129) { // graph segment bounds
        int t = i - 294912 - 480000;
        int lo = 0, hi = N_NODES;
        while (lo < hi) { int mid = (lo + hi) >> 1; if (batch[mid] < t) lo = mid + 1; else hi = mid; }
        gstart[t] = lo;
    }
}

// ---------- conv GEMM (bf16 x bf16, 1 product) + logits + coalesced store ----
// block: 64 rows x 128 cols (one head)
__global__ __launch_bounds__(256) void gemm_conv(const short* __restrict__ Ab,
                                                 const short* __restrict__ Bth,
                                                 const float* __restrict__ att_s,
                                                 const float* __restrict__ att_d,
                                                 unsigned short* __restrict__ hfullb,
                                                 float* __restrict__ als,
                                                 float* __restrict__ ald) {
    __shared__ short As_h[64 * 136];
    __shared__ float red_s[2][64], red_d[2][64];
    const int bm = blockIdx.x * 64;
    const int hd = blockIdx.y;            // head = column block
    const int bn = hd * 128;
    const int t  = threadIdx.x;
#pragma unroll
    for (int i = 0; i < 4; i++) {
        int idx8 = t + i * 256;              // 1024 ushort8 slots
        int row = idx8 >> 4, c8 = (idx8 & 15) << 3;
        bf16x8 vh = {};
        if (bm + row < N_NODES)
            vh = *(const bf16x8*)(Ab + (size_t)(bm + row) * 128 + c8);
        *(bf16x8*)(As_h + row * 136 + c8) = vh;
    }
    __syncthreads();

    const int w = t >> 6, lane = t & 63;
    const int wr = w >> 1, wc = w & 1;
    const int lr = lane & 15, lg = lane >> 4;
    f32x4 acc[2][4] = {};
    const size_t bofs0 = (size_t)(bn + wc * 64 + lr) * 128 + lg * 8;
#pragma unroll
    for (int kk = 0; kk < 4; kk++) {
        bf16x8 ah[2], bh[4];
#pragma unroll
        for (int ni = 0; ni < 4; ni++) {
            size_t o = bofs0 + (size_t)ni * 16 * 128 + kk * 32;
            bh[ni] = *(const bf16x8*)(Bth + o);
        }
        int ko = kk * 32 + lg * 8;
#pragma unroll
        for (int mi = 0; mi < 2; mi++) {
            int r = wr * 32 + mi * 16 + lr;
            ah[mi] = *(const bf16x8*)(As_h + r * 136 + ko);
        }
#pragma unroll
        for (int mi = 0; mi < 2; mi++)
#pragma unroll
            for (int ni = 0; ni < 4; ni++)
                acc[mi][ni] = __builtin_amdgcn_mfma_f32_16x16x32_bf16(ah[mi], bh[ni], acc[mi][ni], 0, 0, 0);
    }
    // fused attention logits: als[m,hd] = sum_c h[m,c]*att_s[hd,c]  (fp32-exact)
    float as_c[4], ad_c[4];
#pragma unroll
    for (int ni = 0; ni < 4; ni++) {
        int cc = wc * 64 + ni * 16 + lr;
        as_c[ni] = att_s[hd * 128 + cc];
        ad_c[ni] = att_d[hd * 128 + cc];
    }
#pragma unroll
    for (int mi = 0; mi < 2; mi++) {
#pragma unroll
        for (int r = 0; r < 4; r++) {
            float ps = 0.f, pd = 0.f;
#pragma unroll
            for (int ni = 0; ni < 4; ni++) {
                ps = fmaf(acc[mi][ni][r], as_c[ni], ps);
                pd = fmaf(acc[mi][ni][r], ad_c[ni], pd);
            }
#pragma unroll
            for (int off = 1; off < 16; off <<= 1) {
                ps += __shfl_xor(ps, off);
                pd += __shfl_xor(pd, off);
            }
            if (lr == 0) {
                int row = wr * 32 + mi * 16 + lg * 4 + r;
                red_s[wc][row] = ps;
                red_d[wc][row] = pd;
            }
        }
    }
    __syncthreads();            // red complete; As tile dead -> reuse as C staging
#pragma unroll
    for (int mi = 0; mi < 2; mi++)
#pragma unroll
        for (int ni = 0; ni < 4; ni++) {
            int nl = wc * 64 + ni * 16 + lr;
#pragma unroll
            for (int r = 0; r < 4; r++) {
                int row = wr * 32 + mi * 16 + lg * 4 + r;
                As_h[row * 136 + nl] = (short)f2bf(acc[mi][ni][r]);
            }
        }
    if (t < 64) {
        int m = bm + t;
        if (m < N_NODES) als[m * 4 + hd] = red_s[0][t] + red_s[1][t];
    } else if (t < 128) {
        int tt = t - 64;
        int m = bm + tt;
        if (m < N_NODES) ald[m * 4 + hd] = red_d[0][tt] + red_d[1][tt];
    }
    __syncthreads();
    // coalesced bf16x8 store of the 64x128 tile
#pragma unroll
    for (int i2 = 0; i2 < 4; i2++) {
        int idx8 = t + i2 * 256;            // 1024 slots
        int row = idx8 >> 4, c8 = (idx8 & 15) << 3;
        int m = bm + row;
        if (m < N_NODES)
            *(bf16x8*)(hfullb + (size_t)m * 512 + bn + c8) = *(const bf16x8*)(As_h + row * 136 + c8);
    }
}

// ---------- fused skip: P = hin@Win + bn(g)@Wout ; gate+relu -> bf16 h-state ----
__global__ __launch_bounds__(256) void skip_gate(const short* __restrict__ hinb,
                                                 const float* __restrict__ g,
                                                 const float* __restrict__ bnsum,   // [0:128)=sum,[128:256)=sumsq
                                                 const float* __restrict__ gamma,
                                                 const float* __restrict__ beta,
                                                 const short* __restrict__ w1h,
                                                 const short* __restrict__ w2h,
                                                 const float* __restrict__ bin, const float* __restrict__ bout,
                                                 short* __restrict__ houtb) {
    __shared__ short A1h[64 * 136], A2h[64 * 136], A2l[64 * 136];
    __shared__ float bnp_s[256];
    const int bm = blockIdx.x * 64;
    const int bn = blockIdx.y * 64;
    const int t  = threadIdx.x;
    if (t < 128) {
        float inv = 1.f / (float)N_NODES;
        float mu  = bnsum[t] * inv;
        float var = bnsum[128 + t] * inv - mu * mu;
        float rs  = rsqrtf(var + 1e-5f);
        float sc  = gamma[t] * rs;
        bnp_s[t]       = sc;
        bnp_s[128 + t] = beta[t] - mu * sc;
    }
    __syncthreads();
    // A1: bf16 hin tile
#pragma unroll
    for (int i = 0; i < 4; i++) {
        int idx8 = t + i * 256;
        int row = idx8 >> 4, c8 = (idx8 & 15) << 3;
        bf16x8 vh = {};
        if (bm + row < N_NODES)
            vh = *(const bf16x8*)(hinb + (size_t)(bm + row) * 128 + c8);
        *(bf16x8*)(A1h + row * 136 + c8) = vh;
    }
    // A2: bn(g) + hi/lo split (hi feeds MFMA, hi+lo reconstructs gate input)
#pragma unroll
    for (int i = 0; i < 8; i++) {
        int idx4 = t + i * 256;
        int row = idx4 >> 5, c4 = (idx4 & 31) << 2;
        float4 v2 = make_float4(0.f, 0.f, 0.f, 0.f);
        if (bm + row < N_NODES) {
            float4 gv = *(const float4*)(g + (size_t)(bm + row) * 128 + c4);
            v2.x = fmaf(bnp_s[c4 + 0], gv.x, bnp_s[128 + c4 + 0]);
            v2.y = fmaf(bnp_s[c4 + 1], gv.y, bnp_s[128 + c4 + 1]);
            v2.z = fmaf(bnp_s[c4 + 2], gv.z, bnp_s[128 + c4 + 2]);
            v2.w = fmaf(bnp_s[c4 + 3], gv.w, bnp_s[128 + c4 + 3]);
        }
        unsigned short b0 = f2bf(v2.x), b1 = f2bf(v2.y), b2 = f2bf(v2.z), b3 = f2bf(v2.w);
        *(bf16x4*)(A2h + row * 136 + c4) = (bf16x4){(short)b0, (short)b1, (short)b2, (short)b3};
        *(bf16x4*)(A2l + row * 136 + c4) = (bf16x4){(short)f2bf(v2.x - bf2f(b0)), (short)f2bf(v2.y - bf2f(b1)),
                                                    (short)f2bf(v2.z - bf2f(b2)), (short)f2bf(v2.w - bf2f(b3))};
    }
    __syncthreads();

    const int w = t >> 6, lane = t & 63;
    const int wr = w >> 1, wc = w & 1;
    const int lr = lane & 15, lg = lane >> 4;
    f32x4 acc[2][2] = {};
    const size_t bofs0 = (size_t)(bn + wc * 32 + lr) * 128 + lg * 8;
#pragma unroll
    for (int kk = 0; kk < 4; kk++) {
        bf16x8 a1f[2], a2f[2], b1h[2], b2h[2];
#pragma unroll
        for (int ni = 0; ni < 2; ni++) {
            size_t o = bofs0 + (size_t)ni * 16 * 128 + kk * 32;
            b1h[ni] = *(const bf16x8*)(w1h + o);
            b2h[ni] = *(const bf16x8*)(w2h + o);
        }
        int ko = kk * 32 + lg * 8;
#pragma unroll
        for (int mi = 0; mi < 2; mi++) {
            int r = wr * 32 + mi * 16 + lr;
            a1f[mi] = *(const bf16x8*)(A1h + r * 136 + ko);
            a2f[mi] = *(const bf16x8*)(A2h + r * 136 + ko);
        }
#pragma unroll
        for (int mi = 0; mi < 2; mi++)
#pragma unroll
            for (int ni = 0; ni < 2; ni++) {
                acc[mi][ni] = __builtin_amdgcn_mfma_f32_16x16x32_bf16(a1f[mi], b1h[ni], acc[mi][ni], 0, 0, 0);
                acc[mi][ni] = __builtin_amdgcn_mfma_f32_16x16x32_bf16(a2f[mi], b2h[ni], acc[mi][ni], 0, 0, 0);
            }
    }
    // gate+relu into acc (reads A-tiles for reconstruct; hv is exact vs bf16 state)
#pragma unroll
    for (int mi = 0; mi < 2; mi++) {
#pragma unroll
        for (int ni = 0; ni < 2; ni++) {
            int n = bn + wc * 32 + ni * 16 + lr;
            float bsum = bin[n] + bout[n];
#pragma unroll
            for (int r = 0; r < 4; r++) {
                int lrow = wr * 32 + mi * 16 + lg * 4 + r;
                float hbnv = bf2f((unsigned short)A2h[lrow * 136 + n]) + bf2f((unsigned short)A2l[lrow * 136 + n]);
                float hv   = bf2f((unsigned short)A1h[lrow * 136 + n]);
                float gt   = 1.f / (1.f + __expf(-(acc[mi][ni][r] + bsum)));
                acc[mi][ni][r] = fmaxf(gt * hbnv + (1.f - gt) * hv, 0.f);
            }
        }
    }
    __syncthreads();            // A1 tile dead -> reuse as output staging
#pragma unroll
    for (int mi = 0; mi < 2; mi++)
#pragma unroll
        for (int ni = 0; ni < 2; ni++) {
            int n = bn + wc * 32 + ni * 16 + lr;
#pragma unroll
            for (int r = 0; r < 4; r++) {
                int lrow = wr * 32 + mi * 16 + lg * 4 + r;
                A1h[lrow * 136 + n] = (short)f2bf(acc[mi][ni][r]);
            }
        }
    __syncthreads();
    // coalesced store of 64-row x 64-col window
#pragma unroll
    for (int i2 = 0; i2 < 2; i2++) {
        int idx8 = t + i2 * 256;            // 512 slots = 64 rows x 8
        int row = idx8 >> 3, c8 = (idx8 & 7) << 3;
        int m = bm + row;
        if (m < N_NODES)
            *(bf16x8*)(houtb + (size_t)m * 128 + bn + c8) = *(const bf16x8*)(A1h + row * 136 + bn + c8);
    }
}

// ---------------- CSR build ----------------
__global__ __launch_bounds__(256) void deg_kernel(const int* __restrict__ ei1,
                                                  int* __restrict__ deg) {
    int e = blockIdx.x * 256 + threadIdx.x;
    if (e >= ETOT) return;
    int d = (e < N_EDGES) ? ei1[e] : (e - N_EDGES);
    atomicAdd(&deg[d], 1);
}

// hierarchical scan: scan1 (per-block) -> scan2 (block sums) -> scan3 (combine)
__global__ __launch_bounds__(256) void scan1(const int* __restrict__ deg,
                                             int* __restrict__ tmp,
                                             int* __restrict__ blksum) {
    int i = blockIdx.x * 256 + threadIdx.x;
    int v = (i < N_NODES) ? deg[i] : 0;
    __shared__ int sh[256];
    sh[threadIdx.x] = v;
    __syncthreads();
    int acc = v;
    for (int off = 1; off < 256; off <<= 1) {
        int u = (threadIdx.x >= off) ? sh[threadIdx.x - off] : 0;
        __syncthreads();
        acc += u;
        sh[threadIdx.x] = acc;
        __syncthreads();
    }
    if (i < N_NODES) tmp[i] = acc - v;     // exclusive within block
    if (threadIdx.x == 255) blksum[blockIdx.x] = acc;
}

__global__ void scan2(const int* __restrict__ blksum, int* __restrict__ blkoff) {
    int t = threadIdx.x;                   // 128 threads >= NBLK
    int v = (t < NBLK) ? blksum[t] : 0;
    __shared__ int sh[128];
    sh[t] = v;
    __syncthreads();
    int acc = v;
    for (int off = 1; off < 128; off <<= 1) {
        int u = (t >= off) ? sh[t - off] : 0;
        __syncthreads();
        acc += u;
        sh[t] = acc;
        __syncthreads();
    }
    if (t < NBLK) blkoff[t] = acc - v;     // exclusive block offset
}

__global__ __launch_bounds__(256) void scan3(const int* __restrict__ tmp,
                                             const int* __restrict__ blkoff,
                                             int* __restrict__ rowptr,
                                             int* __restrict__ wofs) {
    int i = blockIdx.x * 256 + threadIdx.x;
    if (i == 0) rowptr[N_NODES] = ETOT;    // total is a compile-time constant
    if (i < N_NODES) {
        int r = tmp[i] + blkoff[blockIdx.x];
        rowptr[i] = r;
        wofs[i]   = r;
    }
}

__global__ __launch_bounds__(256) void scatter_kernel(const int* __restrict__ ei0,
                                                      const int* __restrict__ ei1,
                                                      int* __restrict__ wofs,
                                                      int* __restrict__ csr_src) {
    int e = blockIdx.x * 256 + threadIdx.x;
    if (e >= ETOT) return;
    int s = (e < N_EDGES) ? ei0[e] : (e - N_EDGES);
    int d = (e < N_EDGES) ? ei1[e] : (e - N_EDGES);
    int pos = atomicAdd(&wofs[d], 1);
    csr_src[pos] = s;
}

// ---------------- fused gather: single pass, 4-edge load-clustered ----------------
__global__ __launch_bounds__(256) void gat_gather(const int* __restrict__ rowptr,
                                                  const int* __restrict__ csr_src,
                                                  const float* __restrict__ al_s,
                                                  const float* __restrict__ al_d,
                                                  const unsigned short* __restrict__ hfullb,
                                                  const float* __restrict__ conv_b,
                                                  float* __restrict__ g,
                                                  float* __restrict__ bnsum,
                                                  float* __restrict__ bnsum2) {
    const int lane = threadIdx.x & 63;
    const int wib  = threadIdx.x >> 6;
    const int gwid = blockIdx.x * 4 + wib;
    const int nw   = gridDim.x * 4;
    const int h    = lane >> 4;
    const int sub  = lane & 15;
    float s1[8] = {}, s2[8] = {};

    for (int n = gwid; n < N_NODES; n += nw) {
        const int e0 = rowptr[n], e1 = rowptr[n + 1];
        const float ald_h = al_d[n * 4 + h];

        float acc[8] = {};
        float zs = 0.f;
        int i = e0;
        for (; i + 3 < e1; i += 4) {
            int sA = csr_src[i], sB = csr_src[i + 1], sC = csr_src[i + 2], sD = csr_src[i + 3];
            bf16x8 ha = *(const bf16x8*)(hfullb + (size_t)sA * 512 + lane * 8);
            bf16x8 hb = *(const bf16x8*)(hfullb + (size_t)sB * 512 + lane * 8);
            bf16x8 hc = *(const bf16x8*)(hfullb + (size_t)sC * 512 + lane * 8);
            bf16x8 hd = *(const bf16x8*)(hfullb + (size_t)sD * 512 + lane * 8);
            float vA = al_s[sA * 4 + h] + ald_h; vA = (vA > 0.f) ? vA : 0.2f * vA;
            float vB = al_s[sB * 4 + h] + ald_h; vB = (vB > 0.f) ? vB : 0.2f * vB;
            float vC = al_s[sC * 4 + h] + ald_h; vC = (vC > 0.f) ? vC : 0.2f * vC;
            float vD = al_s[sD * 4 + h] + ald_h; vD = (vD > 0.f) ? vD : 0.2f * vD;
            float exA = __expf(vA), exB = __expf(vB), exC = __expf(vC), exD = __expf(vD);
            zs += (exA + exB) + (exC + exD);
#pragma unroll
            for (int j = 0; j < 8; j++) {
                float a = fmaf(exA, bf2f((unsigned short)ha[j]), acc[j]);
                a = fmaf(exB, bf2f((unsigned short)hb[j]), a);
                a = fmaf(exC, bf2f((unsigned short)hc[j]), a);
                acc[j] = fmaf(exD, bf2f((unsigned short)hd[j]), a);
            }
        }
        for (; i < e1; i++) {
            int sA = csr_src[i];
            bf16x8 ha = *(const bf16x8*)(hfullb + (size_t)sA * 512 + lane * 8);
            float vA = al_s[sA * 4 + h] + ald_h; vA = (vA > 0.f) ? vA : 0.2f * vA;
            float exA = __expf(vA);
            zs += exA;
#pragma unroll
            for (int j = 0; j < 8; j++)
                acc[j] = fmaf(exA, bf2f((unsigned short)ha[j]), acc[j]);
        }

        float inv = 0.25f / (zs + 1e-16f);
#pragma unroll
        for (int j = 0; j < 8; j++) {
            float a = acc[j] * inv;
            a += __shfl_xor(a, 16);
            a += __shfl_xor(a, 32);
            acc[j] = a;
        }
        if (lane < 16) {
            float o[8];
#pragma unroll
            for (int j = 0; j < 8; j++) {
                float tv = acc[j] + conv_b[sub * 8 + j];
                o[j] = tv;
                s1[j] += tv;
                s2[j] = fmaf(tv, tv, s2[j]);
            }
            float* gp = g + (size_t)n * 128 + sub * 8;
            *(float4*)gp       = make_float4(o[0], o[1], o[2], o[3]);
            *(float4*)(gp + 4) = make_float4(o[4], o[5], o[6], o[7]);
        }
    }

    __shared__ float redA[4][128], redB[4][128];
    if (lane < 16) {
#pragma unroll
        for (int j = 0; j < 8; j++) {
            redA[wib][sub * 8 + j] = s1[j];
            redB[wib][sub * 8 + j] = s2[j];
        }
    }
    __syncthreads();
    int t = threadIdx.x;
    if (t < 128) {
        atomicAdd(&bnsum[t], redA[0][t] + redA[1][t] + redA[2][t] + redA[3][t]);
    } else {
        int c = t - 128;
        atomicAdd(&bnsum2[c], redB[0][c] + redB[1][c] + redB[2][c] + redB[3][c]);
    }
}

// ---------------- pooling + MLP head fused; sorted batch -> segment sums ----------------
__global__ __launch_bounds__(256) void pool_head(const short* __restrict__ hb,
                                                 const int* __restrict__ gstart,
                                                 const float* __restrict__ fc1W,
                                                 const float* __restrict__ fc1b,
                                                 const float* __restrict__ fc3W,
                                                 const float* __restrict__ fc3b,
                                                 float* __restrict__ out) {
    int gid = blockIdx.x, t = threadIdx.x;
    int lo = gstart[gid], hi = gstart[gid + 1];
    int c = t & 127, half = t >> 7;
    float s = 0.f;
    for (int n = lo + half; n < hi; n += 2)
        s += bf2f((unsigned short)hb[(size_t)n * 128 + c]);
    __shared__ float sh[256];
    __shared__ float hg[128], a1[128];
    sh[t] = s;
    __syncthreads();
    if (half == 0) {
        float cc = fmaxf((float)(hi - lo), 1.f);
        hg[c] = (sh[c] + sh[c + 128]) / cc;
    }
    __syncthreads();
    if (t < 128) {
        float v = fc1b[t];
        for (int c2 = 0; c2 < 128; c2++) v = fmaf(hg[c2], fc1W[c2 * 128 + t], v);
        a1[t] = fmaxf(v, 0.f);
    }
    __syncthreads();
    if (t < 16) {
        float o = fc3b[t];
        for (int j = 0; j < 128; j++) o = fmaf(a1[j], fc3W[j * 16 + t], o);
        out[gid * 16 + t] = o;
    }
}

extern "C" void kernel_launch(void* const* d_in, const int* in_sizes, int n_in,
                              void* d_out, int out_size, void* d_ws, size_t ws_size,
                              hipStream_t stream) {
    const float* x       = (const float*)d_in[0];
    const int*   ei      = (const int*)d_in[1];
    const int*   batch   = (const int*)d_in[2];
    const float* W       = (const float*)d_in[3];
    const float* att_src = (const float*)d_in[4];
    const float* att_dst = (const float*)d_in[5];
    const float* conv_b  = (const float*)d_in[6];
    const float* gamma   = (const float*)d_in[7];
    const float* beta    = (const float*)d_in[8];
    const float* sk_Win  = (const float*)d_in[9];
    const float* sk_bin  = (const float*)d_in[10];
    const float* sk_Wout = (const float*)d_in[11];
    const float* sk_bout = (const float*)d_in[12];
    const float* fc1_W   = (const float*)d_in[13];
    const float* fc1_b   = (const float*)d_in[14];
    const float* fc3_W   = (const float*)d_in[15];
    const float* fc3_b   = (const float*)d_in[16];
    float* out = (float*)d_out;
    const int* ei0 = ei;
    const int* ei1 = ei + N_EDGES;

    float* ws = (float*)d_ws;
    size_t o = 0;
    unsigned short* hfullb = (unsigned short*)(ws + o); o += (size_t)N_NODES * 256;  // bf16 [N,512]
    float* gbuf   = ws + o; o += (size_t)N_NODES * 128;
    short* hbA    = (short*)(ws + o); o += (size_t)N_NODES * 64;   // bf16 [N,128] ping
    short* hbB    = (short*)(ws + o); o += (size_t)N_NODES * 64;   // pong
    float* als    = ws + o; o += N_NODES * 4;
    float* ald    = ws + o; o += N_NODES * 4;
    float* bnsum  = ws + o; o += 768;      // 3 layers x (128 sum + 128 sumsq)
    short* wt_hi   = (short*)(ws + o); o += 98304;   // 3*512*128 shorts
    short* wint_hi = (short*)(ws + o); o += 24576;   // 3*128*128 shorts
    short* woutt_hi = (short*)(ws + o); o += 24576;
    int* gstart   = (int*)(ws + o); o += 132;
    int* deg      = (int*)(ws + o); o += N_NODES;
    int* rowptr   = (int*)(ws + o); o += N_NODES + 4;
    int* wofs     = (int*)(ws + o); o += N_NODES;
    int* scantmp  = (int*)(ws + o); o += N_NODES;
    int* blksum   = (int*)(ws + o); o += NBLK + 2;
    int* blkoff   = (int*)(ws + o); o += NBLK + 2;
    int* csr_src  = (int*)(ws + o); o += ETOT;

    prep_kernel<<<3028, 256, 0, stream>>>(W, sk_Win, sk_Wout, x, batch,
                                          wt_hi, wint_hi, woutt_hi, hbA, gstart);

    hipMemsetAsync(deg, 0, N_NODES * 4, stream);
    hipMemsetAsync(bnsum, 0, 768 * 4, stream);
    deg_kernel<<<(ETOT + 255) / 256, 256, 0, stream>>>(ei1, deg);
    scan1<<<NBLK, 256, 0, stream>>>(deg, scantmp, blksum);
    scan2<<<1, 128, 0, stream>>>(blksum, blkoff);
    scan3<<<NBLK, 256, 0, stream>>>(scantmp, blkoff, rowptr, wofs);
    scatter_kernel<<<(ETOT + 255) / 256, 256, 0, stream>>>(ei0, ei1, wofs, csr_src);

    short* sih = hbA;
    short* soh = hbB;
    for (int l = 0; l < 3; l++) {
        gemm_conv<<<dim3(469, 4), 256, 0, stream>>>(sih,
                                                    wt_hi + (size_t)l * 65536,
                                                    att_src + l * 512, att_dst + l * 512,
                                                    hfullb, als, ald);
        gat_gather<<<1024, 256, 0, stream>>>(rowptr, csr_src, als, ald, hfullb,
                                             conv_b + l * 128, gbuf,
                                             bnsum + l * 256, bnsum + l * 256 + 128);
        skip_gate<<<dim3(469, 2), 256, 0, stream>>>(sih, gbuf,
                                                    bnsum + l * 256, gamma + l * 128, beta + l * 128,
                                                    wint_hi + (size_t)l * 16384,
                                                    woutt_hi + (size_t)l * 16384,
                                                    sk_bin + l * 128, sk_bout + l * 128,
                                                    soh);
        short* th = sih; sih = soh; soh = th;
    }

    pool_head<<<NGRAPH, 256, 0, stream>>>(sih, gstart, fc1_W, fc1_b, fc3_W, fc3_b, out);
}